// Round 4
// baseline (3293.676 us; speedup 1.0000x reference)
//
#include <hip/hip_runtime.h>
#include <math.h>

#define MINN 1e-15f
#define ONE_EPS 0.99999f   // 1 - 1e-5 (artanh clamp)

__device__ __forceinline__ float clampart(float x) {
  return fminf(fmaxf(x, -1.0f + 1e-5f), 1.0f - 1e-5f);
}
__device__ __forceinline__ float redsum(float x) {
  #pragma unroll
  for (int m = 32; m; m >>= 1) x += __shfl_xor(x, m);
  return x;
}
__device__ __forceinline__ float frcp(float x) { return __builtin_amdgcn_rcpf(x); }
__device__ __forceinline__ float fexp2(float x) { return __builtin_amdgcn_exp2f(x); }
__device__ __forceinline__ float flog2(float x) { return __builtin_amdgcn_logf(x); }
// x >= 0
__device__ __forceinline__ float ftanh(float x) {
  float e = fexp2(x * 2.88539008f);          // exp(2x)
  return 1.0f - 2.0f * frcp(e + 1.0f);
}
// 0 <= x < 1
__device__ __forceinline__ float fatanh(float x) {
  return 0.34657359f * flog2((1.0f + x) * frcp(1.0f - x));
}
__device__ __forceinline__ float fsig(float x) {
  return frcp(1.0f + fexp2(-1.44269504f * x));
}
// wave-uniform broadcast of lane j's value (SGPR result)
#define RL(x, j) __uint_as_float(__builtin_amdgcn_readlane(__float_as_uint(x), (j)))
#define DOT4(a, b) ((a).x*(b).x + (a).y*(b).y + (a).z*(b).z + (a).w*(b).w)

// ---------------- Kernel A: per-row stats of sequence (expmap0 scalars) ----
__global__ __launch_bounds__(256) void k_stats(const float* __restrict__ seq,
    float* __restrict__ a_arr, float* __restrict__ xn_arr, float* __restrict__ art_arr) {
  int gw = (blockIdx.x * 256 + threadIdx.x) >> 6;
  int lane = threadIdx.x & 63;
  int nw = (gridDim.x * 256) >> 6;
  for (int r = gw; r < 32768; r += nw) {
    const float* row = seq + (size_t)r * 768;
    float s = 0.f;
    #pragma unroll
    for (int c = 0; c < 3; ++c) {
      float4 v = *reinterpret_cast<const float4*>(row + lane * 4 + c * 256);
      s += v.x*v.x + v.y*v.y + v.z*v.z + v.w*v.w;
    }
    s = redsum(s);
    float un  = sqrtf(s);
    float unc = fmaxf(un, MINN);
    float a   = tanhf(unc) / unc;              // proj = a * seq_row
    float xn  = fmaxf(a * un, MINN);           // ||proj|| clamped
    float art = atanhf(clampart(xn));
    if (lane == 0) { a_arr[r] = a; xn_arr[r] = xn; art_arr[r] = art; }
  }
}

// ---------------- Kernel B0: transpose U matrices into [768][384] ----------
__global__ __launch_bounds__(256) void k_transU(const float* __restrict__ uz,
    const float* __restrict__ ur, const float* __restrict__ uh, float* __restrict__ ut) {
  int idx = blockIdx.x * 256 + threadIdx.x;
  if (idx >= 768 * 384) return;
  int k = idx / 384, n = idx % 384;
  const float* U = (n < 128) ? uz : (n < 256 ? ur : uh);
  int i = n & 127;
  ut[idx] = U[(size_t)i * 768 + k];
}

// ---------------- Kernel B: f32 GEMM  MX = seq[32768x768] @ UT[768x384] ----
#define BM 128
#define BN 128
#define BKK 16
__global__ __launch_bounds__(256) void k_gemm(const float* __restrict__ A,
    const float* __restrict__ Bt, float* __restrict__ C) {
  __shared__ float As[BKK][BM];
  __shared__ float Bs[BKK][BN];
  int t = threadIdx.x;
  int m0 = blockIdx.x * BM;
  int n0 = blockIdx.y * BN;
  int tm = t & 15, tn = t >> 4;
  int arow = t >> 2, acol = (t & 3) * 4;
  int bk = t >> 4, bn = (t & 15) * 8;
  float acc[8][8];
  #pragma unroll
  for (int j = 0; j < 8; ++j)
    #pragma unroll
    for (int jj = 0; jj < 8; ++jj) acc[j][jj] = 0.f;
  for (int k0 = 0; k0 < 768; k0 += BKK) {
    float4 a0 = *reinterpret_cast<const float4*>(A + (size_t)(m0 + arow) * 768 + k0 + acol);
    float4 a1 = *reinterpret_cast<const float4*>(A + (size_t)(m0 + arow + 64) * 768 + k0 + acol);
    float4 b0 = *reinterpret_cast<const float4*>(Bt + (size_t)(k0 + bk) * 384 + n0 + bn);
    float4 b1 = *reinterpret_cast<const float4*>(Bt + (size_t)(k0 + bk) * 384 + n0 + bn + 4);
    __syncthreads();
    As[acol + 0][arow] = a0.x; As[acol + 1][arow] = a0.y;
    As[acol + 2][arow] = a0.z; As[acol + 3][arow] = a0.w;
    As[acol + 0][arow + 64] = a1.x; As[acol + 1][arow + 64] = a1.y;
    As[acol + 2][arow + 64] = a1.z; As[acol + 3][arow + 64] = a1.w;
    *reinterpret_cast<float4*>(&Bs[bk][bn]) = b0;
    *reinterpret_cast<float4*>(&Bs[bk][bn + 4]) = b1;
    __syncthreads();
    #pragma unroll
    for (int k = 0; k < BKK; ++k) {
      float af[8], bf[8];
      #pragma unroll
      for (int j = 0; j < 8; ++j) af[j] = As[k][tm + 16 * j];
      #pragma unroll
      for (int j = 0; j < 8; ++j) bf[j] = Bs[k][tn + 16 * j];
      #pragma unroll
      for (int j = 0; j < 8; ++j)
        #pragma unroll
        for (int jj = 0; jj < 8; ++jj) acc[j][jj] += af[j] * bf[jj];
    }
  }
  #pragma unroll
  for (int j = 0; j < 8; ++j)
    #pragma unroll
    for (int jj = 0; jj < 8; ++jj)
      C[(size_t)(m0 + tm + 16 * j) * 384 + n0 + tn + 16 * jj] = acc[j][jj];
}

// ---------------- Kernel B2: mobius_matvec nonlinearity per (row, gate) ----
__global__ __launch_bounds__(256) void k_mvnl(float* __restrict__ mx,
    const float* __restrict__ a_arr, const float* __restrict__ xn_arr,
    const float* __restrict__ art_arr, float* __restrict__ yn) {
  int gw = (blockIdx.x * 256 + threadIdx.x) >> 6;
  int lane = threadIdx.x & 63;
  int nw = (gridDim.x * 256) >> 6;
  for (int w = gw; w < 32768 * 3; w += nw) {
    int r = w / 3, g = w - r * 3;
    float* p = mx + (size_t)r * 384 + g * 128;
    float2 v = *reinterpret_cast<float2*>(p + lane * 2);
    float a = a_arr[r];
    float x0 = v.x * a, x1 = v.y * a;  // mx = a * raw  (proj @ U.T)
    float s = redsum(x0 * x0 + x1 * x1);
    float mxn = fmaxf(sqrtf(s), MINN);
    float xn = xn_arr[r], art = art_arr[r];
    float tt = tanhf(mxn / xn * art);
    float sc = tt / mxn;
    float2 o; o.x = x0 * sc; o.y = x1 * sc;
    *reinterpret_cast<float2*>(p + lane * 2) = o;
    if (lane == 0) yn[(size_t)r * 4 + g] = tt;   // ||result|| = tt
  }
}

// ---------------- Kernel C: sequential hyperbolic GRU scan, 1 wave per b ---
// wz, wr fully in swizzled LDS (128KB); wh cols 0..63 in swizzled LDS (32KB),
// cols 64..127 in per-lane registers (128 VGPRs). h/p broadcast via
// v_readlane (no LDS staging, no fences in the loop). Zero spill target.
__global__ __launch_bounds__(64, 1) void k_scan(
    const float* __restrict__ ux, const float* __restrict__ yn,
    const float* __restrict__ wz, const float* __restrict__ wr, const float* __restrict__ wh,
    const float* __restrict__ bzp, const float* __restrict__ brp, const float* __restrict__ bhp,
    const float* __restrict__ mask1, const float* __restrict__ mask2,
    float* __restrict__ uarr, float* __restrict__ varr) {
  extern __shared__ __align__(16) float lds[];
  float4* wzs4 = (float4*)lds;            // 4096 float4 = 64KB
  float4* wrs4 = wzs4 + 4096;             // 64KB
  float4* whs4 = wrs4 + 4096;             // 2048 float4 = 32KB (wh cols 0..63)

  int b = blockIdx.x, l = threadIdx.x;
  int sl = l & 31;
  int sl16 = l & 15;

  // ---- stage wz, wr into LDS with 32-slot XOR swizzle (bank-balanced) ----
  const float4* wzg = (const float4*)wz;
  const float4* wrg = (const float4*)wr;
  for (int i = l; i < 4096; i += 64) {
    int r = i >> 5, c = i & 31;
    int d = (r << 5) | (c ^ (r & 31));
    wzs4[d] = wzg[i];
    wrs4[d] = wrg[i];
  }
  // ---- stage wh cols 0..63 (slots 0..15 per row), 16-slot XOR swizzle ----
  const float4* whg = (const float4*)wh;
  for (int i = l; i < 2048; i += 64) {
    int r = i >> 4, c = i & 15;
    int d = (r << 4) | (c ^ (r & 15));
    whs4[d] = whg[r * 32 + c];
  }
  // ---- wh cols 64..127 of rows l and l+64 into registers ----
  float4 whA[16], whB[16];
  #pragma unroll
  for (int j = 0; j < 16; ++j) whA[j] = whg[l * 32 + 16 + j];
  #pragma unroll
  for (int j = 0; j < 16; ++j) whB[j] = whg[(l + 64) * 32 + 16 + j];

  float bz0 = bzp[l], bz1 = bzp[l + 64];
  float br0 = brp[l], br1 = brp[l + 64];
  float bh0 = bhp[l], bh1 = bhp[l + 64];
  float b2z = redsum(bz0 * bz0 + bz1 * bz1);
  float b2r = redsum(br0 * br0 + br1 * br1);
  float b2h = redsum(bh0 * bh0 + bh1 * bh1);

  float h0 = 0.f, h1 = 0.f, hn2 = 0.f;
  float au0 = 0.f, au1 = 0.f, av0 = 0.f, av1 = 0.f;
  const float*  uxb  = ux + (size_t)b * 128 * 384;
  const float4* ynb4 = (const float4*)yn + (size_t)b * 128;
  const float*  m1p  = mask1 + b * 128;
  const float*  m2p  = mask2 + b * 128;

  __syncthreads();   // staging complete (single wave: orders LDS writes)

  #pragma unroll 1
  for (int t = 0; t < 128; ++t) {
    // ---- inputs for this step (issued early; used ~2K cycles later) ----
    const float* uxt = uxb + t * 384;
    float uz0 = uxt[l],       uz1 = uxt[l + 64];
    float ur0 = uxt[128 + l], ur1 = uxt[192 + l];
    float uh0 = uxt[256 + l], uh1 = uxt[320 + l];
    float4 ynt = ynb4[t];
    float m1 = m1p[t], m2 = m2p[t];

    // ---- z/r matvec: LDS weights x readlane-broadcast h ----
    float mz0 = 0.f, mz1 = 0.f, mr0 = 0.f, mr1 = 0.f;
    #pragma unroll
    for (int jc = 0; jc < 32; ++jc) {
      float hx, hy, hz, hw;
      if (jc < 16) {
        hx = RL(h0, 4 * jc + 0); hy = RL(h0, 4 * jc + 1);
        hz = RL(h0, 4 * jc + 2); hw = RL(h0, 4 * jc + 3);
      } else {
        hx = RL(h1, 4 * jc - 64); hy = RL(h1, 4 * jc - 63);
        hz = RL(h1, 4 * jc - 62); hw = RL(h1, 4 * jc - 61);
      }
      int slot = jc ^ sl;
      float4 a0 = wzs4[(l << 5) | slot];
      float4 a1 = wzs4[((l + 64) << 5) | slot];
      float4 c0 = wrs4[(l << 5) | slot];
      float4 c1 = wrs4[((l + 64) << 5) | slot];
      mz0 += a0.x * hx + a0.y * hy + a0.z * hz + a0.w * hw;
      mz1 += a1.x * hx + a1.y * hy + a1.z * hz + a1.w * hw;
      mr0 += c0.x * hx + c0.y * hy + c0.z * hz + c0.w * hw;
      mr1 += c1.x * hx + c1.y * hy + c1.z * hz + c1.w * hw;
    }
    // ---- reduction window A: 8 independent butterflies ----
    float sMz2  = redsum(mz0 * mz0 + mz1 * mz1);
    float sMr2  = redsum(mr0 * mr0 + mr1 * mr1);
    float sMzUz = redsum(mz0 * uz0 + mz1 * uz1);
    float sMrUr = redsum(mr0 * ur0 + mr1 * ur1);
    float sMzBz = redsum(mz0 * bz0 + mz1 * bz1);
    float sMrBr = redsum(mr0 * br0 + mr1 * br1);
    float sUzBz = redsum(uz0 * bz0 + uz1 * bz1);
    float sUrBr = redsum(ur0 * br0 + ur1 * br1);

    float xnh  = fmaxf(sqrtf(hn2), MINN);
    float arth = fatanh(fminf(xnh, ONE_EPS));
    float axr  = arth * frcp(xnh);          // artanh(||h||)/||h||
    float ynz = ynt.x, ynr = ynt.y, ynh = ynt.z;

    // ---- z chain (scalar, analytic norms) ----
    float mzn = fmaxf(sqrtf(sMz2), MINN);
    float tz  = ftanh(mzn * axr);
    float szs = tz * frcp(mzn);
    float xyz = szs * sMzUz;
    float y2z = ynz * ynz, x2z = tz * tz;
    float c1z = 1.f + 2.f * xyz + y2z, c2z = 1.f - x2z;
    float idnz = frcp(fmaxf(1.f + 2.f * xyz + x2z * y2z, MINN));
    float az0 = (c1z * szs * mz0 + c2z * uz0) * idnz;
    float az1 = (c1z * szs * mz1 + c2z * uz1) * idnz;
    float az2 = fmaxf(idnz * idnz * (c1z * c1z * x2z + 2.f * c1z * c2z * xyz + c2z * c2z * y2z), 0.f);
    float azb = idnz * (c1z * szs * sMzBz + c2z * sUzBz);
    float c1zb = 1.f + 2.f * azb + b2z, c2zb = 1.f - az2;
    float idnzb = frcp(fmaxf(1.f + 2.f * azb + az2 * b2z, MINN));
    float cz0 = (c1zb * az0 + c2zb * bz0) * idnzb;
    float cz1 = (c1zb * az1 + c2zb * bz1) * idnzb;
    float cn2z = fmaxf(idnzb * idnzb * (c1zb * c1zb * az2 + 2.f * c1zb * c2zb * azb + c2zb * c2zb * b2z), 0.f);
    float cnz = fmaxf(sqrtf(cn2z), MINN);
    float lsz = fatanh(fminf(cnz, ONE_EPS)) * frcp(cnz);
    float zg0 = fsig(lsz * cz0), zg1 = fsig(lsz * cz1);

    // ---- r chain ----
    float mrn = fmaxf(sqrtf(sMr2), MINN);
    float trr = ftanh(mrn * axr);
    float srs = trr * frcp(mrn);
    float xyr = srs * sMrUr;
    float y2r = ynr * ynr, x2r = trr * trr;
    float c1r = 1.f + 2.f * xyr + y2r, c2r = 1.f - x2r;
    float idnr = frcp(fmaxf(1.f + 2.f * xyr + x2r * y2r, MINN));
    float ar0 = (c1r * srs * mr0 + c2r * ur0) * idnr;
    float ar1 = (c1r * srs * mr1 + c2r * ur1) * idnr;
    float ar2 = fmaxf(idnr * idnr * (c1r * c1r * x2r + 2.f * c1r * c2r * xyr + c2r * c2r * y2r), 0.f);
    float arb = idnr * (c1r * srs * sMrBr + c2r * sUrBr);
    float c1rb = 1.f + 2.f * arb + b2r, c2rb = 1.f - ar2;
    float idnrb = frcp(fmaxf(1.f + 2.f * arb + ar2 * b2r, MINN));
    float cr0 = (c1rb * ar0 + c2rb * br0) * idnrb;
    float cr1 = (c1rb * ar1 + c2rb * br1) * idnrb;
    float cn2r = fmaxf(idnrb * idnrb * (c1rb * c1rb * ar2 + 2.f * c1rb * c2rb * arb + c2rb * c2rb * b2r), 0.f);
    float cnr = fmaxf(sqrtf(cn2r), MINN);
    float lsr = fatanh(fminf(cnr, ONE_EPS)) * frcp(cnr);
    float rg0 = fsig(lsr * cr0), rg1 = fsig(lsr * cr1);

    // ---- rh = mobius_pointwise_mul(h, r): keep p unscaled, fold later ----
    float p0 = h0 * rg0, p1 = h1 * rg1;
    float pn2 = redsum(p0 * p0 + p1 * p1);

    // ---- h matvec: cols 0..63 from LDS, cols 64..127 from registers ----
    float mh0r = 0.f, mh1r = 0.f;          // W_h · p (unscaled)
    #pragma unroll
    for (int jc = 0; jc < 16; ++jc) {
      float px = RL(p0, 4 * jc + 0), py = RL(p0, 4 * jc + 1);
      float pz = RL(p0, 4 * jc + 2), pw = RL(p0, 4 * jc + 3);
      int slot = jc ^ sl16;
      float4 a = whs4[(l << 4) | slot];
      float4 c = whs4[((l + 64) << 4) | slot];
      mh0r += a.x * px + a.y * py + a.z * pz + a.w * pw;
      mh1r += c.x * px + c.y * py + c.z * pz + c.w * pw;
    }
    #pragma unroll
    for (int jc = 0; jc < 16; ++jc) {
      float px = RL(p1, 4 * jc + 0), py = RL(p1, 4 * jc + 1);
      float pz = RL(p1, 4 * jc + 2), pw = RL(p1, 4 * jc + 3);
      mh0r += whA[jc].x * px + whA[jc].y * py + whA[jc].z * pz + whA[jc].w * pw;
      mh1r += whB[jc].x * px + whB[jc].y * py + whB[jc].z * pz + whB[jc].w * pw;
    }
    // ---- reduction window B: 6 independent butterflies (raw sums) ----
    float sMh2r  = redsum(mh0r * mh0r + mh1r * mh1r);
    float sMhUhr = redsum(mh0r * uh0 + mh1r * uh1);
    float sMhBhr = redsum(mh0r * bh0 + mh1r * bh1);
    float sHMhr  = redsum(h0 * mh0r + h1 * mh1r);
    float sUhBh  = redsum(uh0 * bh0 + uh1 * bh1);
    float sHUh   = redsum(h0 * uh0 + h1 * uh1);
    float sHBh   = redsum(h0 * bh0 + h1 * bh1);

    // ---- finish rh scaling scalars ----
    float pn  = fmaxf(sqrtf(pn2), MINN);
    float trh = ftanh(pn * axr);
    float srt = trh * frcp(pn);            // rt = srt * p, ||rt|| = trh

    // ---- h~ chain (fold srt into scalars: mh = srt * mh_raw) ----
    float xnp  = fmaxf(trh, MINN);
    float artp = fatanh(fminf(xnp, ONE_EPS));
    float mhn  = fmaxf(srt * sqrtf(sMh2r), MINN);
    float th   = ftanh(mhn * artp * frcp(xnp));
    float g    = th * frcp(mhn) * srt;     // g*mh_raw = (th/mhn)*mh
    float xyh  = g * sMhUhr;
    float y2h = ynh * ynh, x2h = th * th;
    float c1h = 1.f + 2.f * xyh + y2h, c2h = 1.f - x2h;
    float idnh = frcp(fmaxf(1.f + 2.f * xyh + x2h * y2h, MINN));
    float ah0 = (c1h * g * mh0r + c2h * uh0) * idnh;
    float ah1 = (c1h * g * mh1r + c2h * uh1) * idnh;
    float ah2 = fmaxf(idnh * idnh * (c1h * c1h * x2h + 2.f * c1h * c2h * xyh + c2h * c2h * y2h), 0.f);
    float ahb = idnh * (c1h * g * sMhBhr + c2h * sUhBh);
    float hah = idnh * (c1h * g * sHMhr + c2h * sHUh);    // <h, ah>
    float c1hb = 1.f + 2.f * ahb + b2h, c2hb = 1.f - ah2;
    float idnhb = frcp(fmaxf(1.f + 2.f * ahb + ah2 * b2h, MINN));
    float ct0 = (c1hb * ah0 + c2hb * bh0) * idnhb;
    float ct1 = (c1hb * ah1 + c2hb * bh1) * idnhb;
    float ct2 = fmaxf(idnhb * idnhb * (c1hb * c1hb * ah2 + 2.f * c1hb * c2hb * ahb + c2hb * c2hb * b2h), 0.f);
    float hct = idnhb * (c1hb * hah + c2hb * sHBh);       // <h, h_tilde>

    // ---- delta = mobius_add(-h, h_tilde) ----
    float c1d = 1.f - 2.f * hct + ct2, c2d = 1.f - hn2;
    float idnd = frcp(fmaxf(1.f - 2.f * hct + hn2 * ct2, MINN));
    float dl0 = (c2d * ct0 - c1d * h0) * idnd;
    float dl1 = (c2d * ct1 - c1d * h1) * idnd;
    float dn2 = fmaxf(idnd * idnd * (c1d * c1d * hn2 - 2.f * c1d * c2d * hct + c2d * c2d * ct2), 0.f);
    float w0 = dl0 * zg0, w1 = dl1 * zg1;
    // ---- reduction window C: 2 butterflies ----
    float wn2 = redsum(w0 * w0 + w1 * w1);
    float hw  = redsum(h0 * w0 + h1 * w1);

    float dn = fmaxf(sqrtf(dn2), MINN);
    float wn = fmaxf(sqrtf(wn2), MINN);
    float tdd = ftanh(wn * frcp(dn) * fatanh(fminf(dn, ONE_EPS)));
    float szd = tdd * frcp(wn);
    float zd0 = w0 * szd, zd1 = w1 * szd;
    float hzd = hw * szd;
    float t2 = tdd * tdd;
    float c1f = 1.f + 2.f * hzd + t2, c2f = 1.f - hn2;
    float idnf = frcp(fmaxf(1.f + 2.f * hzd + hn2 * t2, MINN));
    float nh0 = (c1f * h0 + c2f * zd0) * idnf;
    float nh1 = (c1f * h1 + c2f * zd1) * idnf;
    hn2 = fmaxf(idnf * idnf * (c1f * c1f * hn2 + 2.f * c1f * c2f * hzd + c2f * c2f * t2), 0.f);
    h0 = nh0; h1 = nh1;
    au0 += m1 * h0; au1 += m1 * h1;
    av0 += m2 * h0; av1 += m2 * h1;
  }
  uarr[b * 128 + l] = au0; uarr[b * 128 + 64 + l] = au1;
  varr[b * 128 + l] = av0; varr[b * 128 + 64 + l] = av1;
}

// ---------------- Kernel D: dist + mobius FF + hyperbolic MLR, 1 wave/b ----
__global__ __launch_bounds__(64) void k_final(
    const float* __restrict__ uarr, const float* __restrict__ varr,
    const float* __restrict__ wfu, const float* __restrict__ wfv,
    const float* __restrict__ bff, const float* __restrict__ bffd,
    const float* __restrict__ wfc, const float* __restrict__ pmlr,
    const float* __restrict__ amlr, const int* __restrict__ cids,
    const float* __restrict__ csemb, float* __restrict__ out) {
  int b = blockIdx.x;
  int l = threadIdx.x;
  __shared__ float us[128], vs[128], cbuf[64];
  float q0 = uarr[b * 128 + l], q1 = uarr[b * 128 + 64 + l];
  float r0 = varr[b * 128 + l], r1 = varr[b * 128 + 64 + l];
  us[l] = q0; us[l + 64] = q1; vs[l] = r0; vs[l + 64] = r1;
  __syncthreads();
  float u2 = redsum(q0 * q0 + q1 * q1);
  float v2 = redsum(r0 * r0 + r1 * r1);
  float uv = redsum(q0 * r0 + q1 * r1);
  // dist(u,v)
  float dsq;
  { float x2 = u2, y2 = v2, xy = -uv;
    float c1 = 1.f + 2.f * xy + y2, c2 = 1.f - x2;
    float idn = 1.f / fmaxf(1.f + 2.f * xy + x2 * y2, MINN);
    float d0 = (c1 * (-q0) + c2 * r0) * idn, d1 = (c1 * (-q1) + c2 * r1) * idn;
    float dn2 = redsum(d0 * d0 + d1 * d1);
    dsq = 2.f * atanhf(clampart(sqrtf(dn2))); }
  // mobius_matvec(W_ff_u, u) and (W_ff_v, v): out dim 64, lane l = row l
  float mxu = 0.f, mxv = 0.f;
  #pragma unroll 4
  for (int jc = 0; jc < 128; jc += 4) {
    float4 uu = *reinterpret_cast<const float4*>(&us[jc]);
    float4 vv = *reinterpret_cast<const float4*>(&vs[jc]);
    float4 wu4 = *reinterpret_cast<const float4*>(wfu + (size_t)l * 128 + jc);
    float4 wv4 = *reinterpret_cast<const float4*>(wfv + (size_t)l * 128 + jc);
    mxu += DOT4(wu4, uu); mxv += DOT4(wv4, vv);
  }
  float xnu = fmaxf(sqrtf(u2), MINN);
  float xnv = fmaxf(sqrtf(v2), MINN);
  float mun = fmaxf(sqrtf(redsum(mxu * mxu)), MINN);
  float mvn = fmaxf(sqrtf(redsum(mxv * mxv)), MINN);
  float tu = tanhf(mun / xnu * atanhf(clampart(xnu)));
  float tv = tanhf(mvn / xnv * atanhf(clampart(xnv)));
  float fu = mxu * (tu / mun), fv = mxv * (tv / mvn);
  // out = mobius_add(fu, fv)
  float o1;
  { float x2 = tu * tu, y2 = tv * tv, xy = redsum(fu * fv);
    float c1 = 1.f + 2.f * xy + y2, c2 = 1.f - x2;
    float idn = 1.f / fmaxf(1.f + 2.f * xy + x2 * y2, MINN);
    o1 = (c1 * fu + c2 * fv) * idn; }
  // out = mobius_add(out, b_ff)
  float bffl = bff[l];
  float bf2 = redsum(bffl * bffl);
  float o2;
  { float x2 = redsum(o1 * o1), y2 = bf2, xy = redsum(o1 * bffl);
    float c1 = 1.f + 2.f * xy + y2, c2 = 1.f - x2;
    float idn = 1.f / fmaxf(1.f + 2.f * xy + x2 * y2, MINN);
    o2 = (c1 * o1 + c2 * bffl) * idn; }
  // mobius_scalar_mul(dsq, b_ff_d)
  float bdl = bffd[l];
  float bdn = fmaxf(sqrtf(redsum(bdl * bdl)), MINN);
  float tsm = tanhf(dsq * atanhf(clampart(bdn)));
  float sm = bdl * (tsm / bdn);
  float o3;
  { float x2 = redsum(o2 * o2), y2 = tsm * tsm, xy = redsum(o2 * sm);
    float c1 = 1.f + 2.f * xy + y2, c2 = 1.f - x2;
    float idn = 1.f / fmaxf(1.f + 2.f * xy + x2 * y2, MINN);
    o3 = (c1 * o2 + c2 * sm) * idn; }
  // mobius_matvec(W_ff_common, common)
  int cid = cids[b];
  float ce = csemb[(size_t)cid * 64 + l];
  cbuf[l] = ce;
  __syncthreads();
  float ce2 = redsum(ce * ce);
  float mxc = 0.f;
  #pragma unroll 4
  for (int jc = 0; jc < 64; jc += 4) {
    float4 cc = *reinterpret_cast<const float4*>(&cbuf[jc]);
    float4 wc4 = *reinterpret_cast<const float4*>(wfc + (size_t)l * 64 + jc);
    mxc += DOT4(wc4, cc);
  }
  float xnc = fmaxf(sqrtf(ce2), MINN);
  float mcn = fmaxf(sqrtf(redsum(mxc * mxc)), MINN);
  float tc = tanhf(mcn / xnc * atanhf(clampart(xnc)));
  float fc = mxc * (tc / mcn);
  float o4;
  { float x2 = redsum(o3 * o3), y2 = tc * tc, xy = redsum(o3 * fc);
    float c1 = 1.f + 2.f * xy + y2, c2 = 1.f - x2;
    float idn = 1.f / fmaxf(1.f + 2.f * xy + x2 * y2, MINN);
    o4 = (c1 * o3 + c2 * fc) * idn; }
  // logmap0 then expmap0
  float on = fmaxf(sqrtf(redsum(o4 * o4)), MINN);
  float lo = o4 * (atanhf(clampart(on)) / on);
  float un = fmaxf(sqrtf(redsum(lo * lo)), MINN);
  float eo = lo * (tanhf(un) / un);
  float eo2 = redsum(eo * eo);
  // hyperbolic MLR
  for (int c = 0; c < 4; ++c) {
    float pc = pmlr[c * 64 + l];
    float ac = amlr[c * 64 + l];
    float p2 = redsum(pc * pc);
    float pe = redsum(pc * eo);
    float x2 = p2, y2 = eo2, xy = -pe;
    float c1 = 1.f + 2.f * xy + y2, c2 = 1.f - x2;
    float idn = 1.f / fmaxf(1.f + 2.f * xy + x2 * y2, MINN);
    float mp = (c1 * (-pc) + c2 * eo) * idn;
    float mp2 = redsum(mp * mp);
    float lam = 2.f / (1.f - mp2);
    float na = sqrtf(redsum(ac * ac));
    float au = ac / fmaxf(na, 1e-12f);
    float pda = redsum(mp * au);
    if (l == 0) out[b * 4 + c] = 2.f * na * asinhf(pda * lam);
  }
}

extern "C" void kernel_launch(void* const* d_in, const int* in_sizes, int n_in,
                              void* d_out, int out_size, void* d_ws, size_t ws_size,
                              hipStream_t stream) {
  const float* seq   = (const float*)d_in[0];
  const float* mask1 = (const float*)d_in[1];
  const float* mask2 = (const float*)d_in[2];
  const int*   cids  = (const int*)d_in[3];
  const float* csemb = (const float*)d_in[4];
  const float* wz  = (const float*)d_in[5];
  const float* wr  = (const float*)d_in[6];
  const float* wh  = (const float*)d_in[7];
  const float* uz  = (const float*)d_in[8];
  const float* ur  = (const float*)d_in[9];
  const float* uh  = (const float*)d_in[10];
  const float* bz  = (const float*)d_in[11];
  const float* br  = (const float*)d_in[12];
  const float* bh  = (const float*)d_in[13];
  const float* wfu = (const float*)d_in[14];
  const float* wfv = (const float*)d_in[15];
  const float* bff = (const float*)d_in[16];
  const float* bffd= (const float*)d_in[17];
  const float* wfc = (const float*)d_in[18];
  const float* pmlr= (const float*)d_in[19];
  const float* amlr= (const float*)d_in[20];
  float* ws = (float*)d_ws;
  float* mx      = ws;                             // 32768*384
  float* a_arr   = mx + (size_t)32768 * 384;       // 32768
  float* xn_arr  = a_arr + 32768;                  // 32768
  float* art_arr = xn_arr + 32768;                 // 32768
  float* yn      = art_arr + 32768;                // 32768*4
  float* ut      = yn + (size_t)32768 * 4;         // 768*384
  float* uarr    = ut + 768 * 384;                 // 256*128
  float* varr    = uarr + 256 * 128;               // 256*128

  k_stats<<<dim3(2048), dim3(256), 0, stream>>>(seq, a_arr, xn_arr, art_arr);
  k_transU<<<dim3(1152), dim3(256), 0, stream>>>(uz, ur, uh, ut);
  k_gemm<<<dim3(256, 3), dim3(256), 0, stream>>>(seq, ut, mx);
  k_mvnl<<<dim3(4096), dim3(256), 0, stream>>>(mx, a_arr, xn_arr, art_arr, yn);
  k_scan<<<dim3(256), dim3(64), 163840, stream>>>(mx, yn, wz, wr, wh, bz, br, bh,
                                                  mask1, mask2, uarr, varr);
  k_final<<<dim3(256), dim3(64), 0, stream>>>(uarr, varr, wfu, wfv, bff, bffd,
                                              wfc, pmlr, amlr, cids, csemb,
                                              (float*)d_out);
}

// Round 5
// 1083.179 us; speedup vs baseline: 3.0408x; 3.0408x over previous
//
#include <hip/hip_runtime.h>
#include <math.h>

#define MINN 1e-15f
#define ONE_EPS 0.99999f   // 1 - 1e-5 (artanh clamp)

__device__ __forceinline__ float clampart(float x) {
  return fminf(fmaxf(x, -1.0f + 1e-5f), 1.0f - 1e-5f);
}
__device__ __forceinline__ float redsum(float x) {
  #pragma unroll
  for (int m = 32; m; m >>= 1) x += __shfl_xor(x, m);
  return x;
}
__device__ __forceinline__ float frcp(float x) { return __builtin_amdgcn_rcpf(x); }
__device__ __forceinline__ float fexp2(float x) { return __builtin_amdgcn_exp2f(x); }
__device__ __forceinline__ float flog2(float x) { return __builtin_amdgcn_logf(x); }
// x >= 0
__device__ __forceinline__ float ftanh(float x) {
  float e = fexp2(x * 2.88539008f);          // exp(2x)
  return 1.0f - 2.0f * frcp(e + 1.0f);
}
// 0 <= x < 1
__device__ __forceinline__ float fatanh(float x) {
  return 0.34657359f * flog2((1.0f + x) * frcp(1.0f - x));
}
__device__ __forceinline__ float fsig(float x) {
  return frcp(1.0f + fexp2(-1.44269504f * x));
}
#define DOT4(a, b) ((a).x*(b).x + (a).y*(b).y + (a).z*(b).z + (a).w*(b).w)

// ---------------- Kernel A: per-row stats of sequence (expmap0 scalars) ----
__global__ __launch_bounds__(256) void k_stats(const float* __restrict__ seq,
    float* __restrict__ a_arr, float* __restrict__ xn_arr, float* __restrict__ art_arr) {
  int gw = (blockIdx.x * 256 + threadIdx.x) >> 6;
  int lane = threadIdx.x & 63;
  int nw = (gridDim.x * 256) >> 6;
  for (int r = gw; r < 32768; r += nw) {
    const float* row = seq + (size_t)r * 768;
    float s = 0.f;
    #pragma unroll
    for (int c = 0; c < 3; ++c) {
      float4 v = *reinterpret_cast<const float4*>(row + lane * 4 + c * 256);
      s += v.x*v.x + v.y*v.y + v.z*v.z + v.w*v.w;
    }
    s = redsum(s);
    float un  = sqrtf(s);
    float unc = fmaxf(un, MINN);
    float a   = tanhf(unc) / unc;              // proj = a * seq_row
    float xn  = fmaxf(a * un, MINN);           // ||proj|| clamped
    float art = atanhf(clampart(xn));
    if (lane == 0) { a_arr[r] = a; xn_arr[r] = xn; art_arr[r] = art; }
  }
}

// ---------------- Kernel B0: transpose U matrices into [768][384] ----------
__global__ __launch_bounds__(256) void k_transU(const float* __restrict__ uz,
    const float* __restrict__ ur, const float* __restrict__ uh, float* __restrict__ ut) {
  int idx = blockIdx.x * 256 + threadIdx.x;
  if (idx >= 768 * 384) return;
  int k = idx / 384, n = idx % 384;
  const float* U = (n < 128) ? uz : (n < 256 ? ur : uh);
  int i = n & 127;
  ut[idx] = U[(size_t)i * 768 + k];
}

// ---------------- Kernel B: f32 GEMM  MX = seq[32768x768] @ UT[768x384] ----
#define BM 128
#define BN 128
#define BKK 16
__global__ __launch_bounds__(256) void k_gemm(const float* __restrict__ A,
    const float* __restrict__ Bt, float* __restrict__ C) {
  __shared__ float As[BKK][BM];
  __shared__ float Bs[BKK][BN];
  int t = threadIdx.x;
  int m0 = blockIdx.x * BM;
  int n0 = blockIdx.y * BN;
  int tm = t & 15, tn = t >> 4;
  int arow = t >> 2, acol = (t & 3) * 4;
  int bk = t >> 4, bn = (t & 15) * 8;
  float acc[8][8];
  #pragma unroll
  for (int j = 0; j < 8; ++j)
    #pragma unroll
    for (int jj = 0; jj < 8; ++jj) acc[j][jj] = 0.f;
  for (int k0 = 0; k0 < 768; k0 += BKK) {
    float4 a0 = *reinterpret_cast<const float4*>(A + (size_t)(m0 + arow) * 768 + k0 + acol);
    float4 a1 = *reinterpret_cast<const float4*>(A + (size_t)(m0 + arow + 64) * 768 + k0 + acol);
    float4 b0 = *reinterpret_cast<const float4*>(Bt + (size_t)(k0 + bk) * 384 + n0 + bn);
    float4 b1 = *reinterpret_cast<const float4*>(Bt + (size_t)(k0 + bk) * 384 + n0 + bn + 4);
    __syncthreads();
    As[acol + 0][arow] = a0.x; As[acol + 1][arow] = a0.y;
    As[acol + 2][arow] = a0.z; As[acol + 3][arow] = a0.w;
    As[acol + 0][arow + 64] = a1.x; As[acol + 1][arow + 64] = a1.y;
    As[acol + 2][arow + 64] = a1.z; As[acol + 3][arow + 64] = a1.w;
    *reinterpret_cast<float4*>(&Bs[bk][bn]) = b0;
    *reinterpret_cast<float4*>(&Bs[bk][bn + 4]) = b1;
    __syncthreads();
    #pragma unroll
    for (int k = 0; k < BKK; ++k) {
      float af[8], bf[8];
      #pragma unroll
      for (int j = 0; j < 8; ++j) af[j] = As[k][tm + 16 * j];
      #pragma unroll
      for (int j = 0; j < 8; ++j) bf[j] = Bs[k][tn + 16 * j];
      #pragma unroll
      for (int j = 0; j < 8; ++j)
        #pragma unroll
        for (int jj = 0; jj < 8; ++jj) acc[j][jj] += af[j] * bf[jj];
    }
  }
  #pragma unroll
  for (int j = 0; j < 8; ++j)
    #pragma unroll
    for (int jj = 0; jj < 8; ++jj)
      C[(size_t)(m0 + tm + 16 * j) * 384 + n0 + tn + 16 * jj] = acc[j][jj];
}

// -------- Kernel B2: mobius_matvec nonlinearity + <U,b> precompute --------
__global__ __launch_bounds__(256) void k_mvnl(float* __restrict__ mx,
    const float* __restrict__ a_arr, const float* __restrict__ xn_arr,
    const float* __restrict__ art_arr, float* __restrict__ yn, float* __restrict__ ub,
    const float* __restrict__ bzp, const float* __restrict__ brp,
    const float* __restrict__ bhp) {
  int gw = (blockIdx.x * 256 + threadIdx.x) >> 6;
  int lane = threadIdx.x & 63;
  int nw = (gridDim.x * 256) >> 6;
  for (int w = gw; w < 32768 * 3; w += nw) {
    int r = w / 3, g = w - r * 3;
    float* p = mx + (size_t)r * 384 + g * 128;
    float2 v = *reinterpret_cast<float2*>(p + lane * 2);
    const float* bp = (g == 0) ? bzp : (g == 1 ? brp : bhp);
    float2 b2 = reinterpret_cast<const float2*>(bp)[lane];
    float a = a_arr[r];
    float x0 = v.x * a, x1 = v.y * a;  // mx = a * raw  (proj @ U.T)
    float s = redsum(x0 * x0 + x1 * x1);
    float mxn = fmaxf(sqrtf(s), MINN);
    float xn = xn_arr[r], art = art_arr[r];
    float tt = tanhf(mxn / xn * art);
    float sc = tt / mxn;
    float o0 = x0 * sc, o1 = x1 * sc;
    float2 o; o.x = o0; o.y = o1;
    *reinterpret_cast<float2*>(p + lane * 2) = o;
    float dot = redsum(o0 * b2.x + o1 * b2.y);
    if (lane == 0) { yn[(size_t)r * 4 + g] = tt; ub[(size_t)r * 4 + g] = dot; }
  }
}

// ---------------- Kernel C: hyperbolic GRU scan, 4 waves per chain --------
// Lane (w,l) owns output o = 32w + (l&31) over k-half (l>>5). wz/wr in
// swizzled LDS (128KB, each element read once/step); wh slice in 64 VGPRs.
// Partial dots combined with one shfl_xor(32); reductions = per-wave
// butterfly (x2 from duplication) + 4-entry LDS combine. 5 barriers/step.
__global__ __launch_bounds__(256, 1) void k_scan(
    const float* __restrict__ ux, const float* __restrict__ yn,
    const float* __restrict__ ub,
    const float* __restrict__ wz, const float* __restrict__ wr, const float* __restrict__ wh,
    const float* __restrict__ bzp, const float* __restrict__ brp, const float* __restrict__ bhp,
    const float* __restrict__ mask1, const float* __restrict__ mask2,
    float* __restrict__ uarr, float* __restrict__ varr) {
  extern __shared__ __align__(16) float lds[];
  float4* wzs4 = (float4*)lds;            // 4096 f4 = 64KB
  float4* wrs4 = wzs4 + 4096;             // 64KB
  float*  hs   = (float*)(wrs4 + 4096);   // 128 f32
  float*  ps   = hs + 128;                // 128 f32
  float*  part = ps + 128;                // 18 reductions x 4 waves = 72 f32
  float4* hs4   = (float4*)hs;
  float4* ps4   = (float4*)ps;
  float4* part4 = (float4*)part;

  int b = blockIdx.x;
  int tid = threadIdx.x;
  int w = tid >> 6;          // wave 0..3
  int l = tid & 63;          // lane
  int l31 = l & 31;
  int kh = l >> 5;           // k-half 0/1
  int o = w * 32 + l31;      // owned output/elem index

  // ---- stage wz, wr into LDS with 32-slot XOR swizzle ----
  const float4* wzg = (const float4*)wz;
  const float4* wrg = (const float4*)wr;
  for (int i = tid; i < 4096; i += 256) {
    int r = i >> 5, s = i & 31;
    int d = (r << 5) | (s ^ (r & 31));
    wzs4[d] = wzg[i];
    wrs4[d] = wrg[i];
  }
  // ---- wh[o][64*kh .. 64*kh+63] into 16 float4 regs ----
  const float4* whg = (const float4*)wh;
  float4 whr[16];
  #pragma unroll
  for (int i = 0; i < 16; ++i) whr[i] = whg[o * 32 + kh * 16 + i];

  float bzv = bzp[o], brv = brp[o], bhv = bhp[o];
  // bias norm^2 via window machinery (init region 15..17)
  {
    float v0 = redsum(bzv * bzv);
    float v1 = redsum(brv * brv);
    float v2 = redsum(bhv * bhv);
    if (l == 0) { part[15*4 + w] = v0; part[16*4 + w] = v1; part[17*4 + w] = v2; }
  }
  __syncthreads();  // staging + init writes complete
  float b2z, b2r, b2h;
  { float4 q;
    q = part4[15]; b2z = (q.x + q.y + q.z + q.w) * 0.5f;
    q = part4[16]; b2r = (q.x + q.y + q.z + q.w) * 0.5f;
    q = part4[17]; b2h = (q.x + q.y + q.z + q.w) * 0.5f; }

  float h = 0.f, hn2 = 0.f, au = 0.f, av = 0.f;
  const float*  uxb  = ux + (size_t)b * 128 * 384;
  const float4* ynb4 = (const float4*)yn + (size_t)b * 128;
  const float4* ubb4 = (const float4*)ub + (size_t)b * 128;
  const float*  m1p  = mask1 + b * 128;
  const float*  m2p  = mask2 + b * 128;

  #pragma unroll 1
  for (int t = 0; t < 128; ++t) {
    if (l < 32) hs[o] = h;
    __syncthreads();                      // (1) h visible
    const float* uxt = uxb + t * 384;
    float uz = uxt[o], ur = uxt[128 + o], uh = uxt[256 + o];
    float4 ynt = ynb4[t];
    float4 ubt = ubb4[t];
    float m1 = m1p[t], m2 = m2p[t];

    // ---- z/r matvec: partial dot over own k-half ----
    float mzp = 0.f, mrp = 0.f;
    #pragma unroll 4
    for (int i = 0; i < 16; ++i) {
      float4 hv = hs4[kh * 16 + i];                    // uniform-per-half broadcast
      int slot = (kh * 16 + i) ^ l31;
      float4 a = wzs4[(o << 5) | slot];
      float4 c = wrs4[(o << 5) | slot];
      mzp += DOT4(a, hv);
      mrp += DOT4(c, hv);
    }
    float mz = mzp + __shfl_xor(mzp, 32);
    float mr = mrp + __shfl_xor(mrp, 32);

    // ---- window A: 6 reductions ----
    {
      float pA0 = redsum(mz * mz);
      float pA1 = redsum(mr * mr);
      float pA2 = redsum(mz * uz);
      float pA3 = redsum(mr * ur);
      float pA4 = redsum(mz * bzv);
      float pA5 = redsum(mr * brv);
      if (l == 0) {
        part[0*4 + w] = pA0; part[1*4 + w] = pA1; part[2*4 + w] = pA2;
        part[3*4 + w] = pA3; part[4*4 + w] = pA4; part[5*4 + w] = pA5;
      }
    }
    __syncthreads();                      // (2) window A partials
    float sMz2, sMr2, sMzUz, sMrUr, sMzBz, sMrBr;
    { float4 q;
      q = part4[0]; sMz2  = (q.x + q.y + q.z + q.w) * 0.5f;
      q = part4[1]; sMr2  = (q.x + q.y + q.z + q.w) * 0.5f;
      q = part4[2]; sMzUz = (q.x + q.y + q.z + q.w) * 0.5f;
      q = part4[3]; sMrUr = (q.x + q.y + q.z + q.w) * 0.5f;
      q = part4[4]; sMzBz = (q.x + q.y + q.z + q.w) * 0.5f;
      q = part4[5]; sMrBr = (q.x + q.y + q.z + q.w) * 0.5f; }

    float xnh  = fmaxf(sqrtf(hn2), MINN);
    float arth = fatanh(fminf(xnh, ONE_EPS));
    float axr  = arth * frcp(xnh);
    float ynz = ynt.x, ynr = ynt.y, ynh = ynt.z;
    float ubz = ubt.x, ubr = ubt.y, ubh = ubt.z;   // <U_t, b_gate> precomputed

    // ---- z chain ----
    float mzn = fmaxf(sqrtf(sMz2), MINN);
    float tz  = ftanh(mzn * axr);
    float szs = tz * frcp(mzn);
    float xyz = szs * sMzUz;
    float y2z = ynz * ynz, x2z = tz * tz;
    float c1z = 1.f + 2.f * xyz + y2z, c2z = 1.f - x2z;
    float idnz = frcp(fmaxf(1.f + 2.f * xyz + x2z * y2z, MINN));
    float az  = (c1z * szs * mz + c2z * uz) * idnz;
    float az2 = fmaxf(idnz * idnz * (c1z * c1z * x2z + 2.f * c1z * c2z * xyz + c2z * c2z * y2z), 0.f);
    float azb = idnz * (c1z * szs * sMzBz + c2z * ubz);
    float c1zb = 1.f + 2.f * azb + b2z, c2zb = 1.f - az2;
    float idnzb = frcp(fmaxf(1.f + 2.f * azb + az2 * b2z, MINN));
    float cz = (c1zb * az + c2zb * bzv) * idnzb;
    float cn2z = fmaxf(idnzb * idnzb * (c1zb * c1zb * az2 + 2.f * c1zb * c2zb * azb + c2zb * c2zb * b2z), 0.f);
    float cnz = fmaxf(sqrtf(cn2z), MINN);
    float lsz = fatanh(fminf(cnz, ONE_EPS)) * frcp(cnz);
    float zg = fsig(lsz * cz);

    // ---- r chain ----
    float mrn = fmaxf(sqrtf(sMr2), MINN);
    float trr = ftanh(mrn * axr);
    float srs = trr * frcp(mrn);
    float xyr = srs * sMrUr;
    float y2r = ynr * ynr, x2r = trr * trr;
    float c1r = 1.f + 2.f * xyr + y2r, c2r = 1.f - x2r;
    float idnr = frcp(fmaxf(1.f + 2.f * xyr + x2r * y2r, MINN));
    float ar  = (c1r * srs * mr + c2r * ur) * idnr;
    float ar2 = fmaxf(idnr * idnr * (c1r * c1r * x2r + 2.f * c1r * c2r * xyr + c2r * c2r * y2r), 0.f);
    float arb = idnr * (c1r * srs * sMrBr + c2r * ubr);
    float c1rb = 1.f + 2.f * arb + b2r, c2rb = 1.f - ar2;
    float idnrb = frcp(fmaxf(1.f + 2.f * arb + ar2 * b2r, MINN));
    float cr = (c1rb * ar + c2rb * brv) * idnrb;
    float cn2r = fmaxf(idnrb * idnrb * (c1rb * c1rb * ar2 + 2.f * c1rb * c2rb * arb + c2rb * c2rb * b2r), 0.f);
    float cnr = fmaxf(sqrtf(cn2r), MINN);
    float lsr = fatanh(fminf(cnr, ONE_EPS)) * frcp(cnr);
    float rg = fsig(lsr * cr);

    // ---- rh = h o r (unscaled p; scaling folded into scalars) ----
    float p = h * rg;
    if (l < 32) ps[o] = p;
    __syncthreads();                      // (3) p visible

    // ---- h matvec from regs x ps broadcast ----
    float mhp = 0.f;
    #pragma unroll 4
    for (int i = 0; i < 16; ++i) {
      float4 pv = ps4[kh * 16 + i];
      mhp += DOT4(whr[i], pv);
    }
    float mh = mhp + __shfl_xor(mhp, 32);

    // ---- window B: 7 reductions ----
    {
      float pB0 = redsum(p * p);
      float pB1 = redsum(mh * mh);
      float pB2 = redsum(mh * uh);
      float pB3 = redsum(mh * bhv);
      float pB4 = redsum(h * mh);
      float pB5 = redsum(h * uh);
      float pB6 = redsum(h * bhv);
      if (l == 0) {
        part[6*4 + w] = pB0; part[7*4 + w] = pB1; part[8*4 + w] = pB2;
        part[9*4 + w] = pB3; part[10*4 + w] = pB4; part[11*4 + w] = pB5;
        part[12*4 + w] = pB6;
      }
    }
    __syncthreads();                      // (4) window B partials
    float pn2, sMh2r, sMhUhr, sMhBhr, sHMhr, sHUh, sHBh;
    { float4 q;
      q = part4[6];  pn2    = (q.x + q.y + q.z + q.w) * 0.5f;
      q = part4[7];  sMh2r  = (q.x + q.y + q.z + q.w) * 0.5f;
      q = part4[8];  sMhUhr = (q.x + q.y + q.z + q.w) * 0.5f;
      q = part4[9];  sMhBhr = (q.x + q.y + q.z + q.w) * 0.5f;
      q = part4[10]; sHMhr  = (q.x + q.y + q.z + q.w) * 0.5f;
      q = part4[11]; sHUh   = (q.x + q.y + q.z + q.w) * 0.5f;
      q = part4[12]; sHBh   = (q.x + q.y + q.z + q.w) * 0.5f; }

    // ---- rh scaling + h~ chain (srt folded) ----
    float pn  = fmaxf(sqrtf(pn2), MINN);
    float trh = ftanh(pn * axr);
    float srt = trh * frcp(pn);
    float xnp  = fmaxf(trh, MINN);
    float artp = fatanh(fminf(xnp, ONE_EPS));
    float mhn  = fmaxf(srt * sqrtf(sMh2r), MINN);
    float th   = ftanh(mhn * artp * frcp(xnp));
    float g    = th * frcp(mhn) * srt;
    float xyh  = g * sMhUhr;
    float y2h = ynh * ynh, x2h = th * th;
    float c1h = 1.f + 2.f * xyh + y2h, c2h = 1.f - x2h;
    float idnh = frcp(fmaxf(1.f + 2.f * xyh + x2h * y2h, MINN));
    float ah  = (c1h * g * mh + c2h * uh) * idnh;
    float ah2 = fmaxf(idnh * idnh * (c1h * c1h * x2h + 2.f * c1h * c2h * xyh + c2h * c2h * y2h), 0.f);
    float ahb = idnh * (c1h * g * sMhBhr + c2h * ubh);
    float hah = idnh * (c1h * g * sHMhr + c2h * sHUh);
    float c1hb = 1.f + 2.f * ahb + b2h, c2hb = 1.f - ah2;
    float idnhb = frcp(fmaxf(1.f + 2.f * ahb + ah2 * b2h, MINN));
    float ct  = (c1hb * ah + c2hb * bhv) * idnhb;
    float ct2 = fmaxf(idnhb * idnhb * (c1hb * c1hb * ah2 + 2.f * c1hb * c2hb * ahb + c2hb * c2hb * b2h), 0.f);
    float hct = idnhb * (c1hb * hah + c2hb * sHBh);

    // ---- delta = mobius_add(-h, h_tilde) ----
    float c1d = 1.f - 2.f * hct + ct2, c2d = 1.f - hn2;
    float idnd = frcp(fmaxf(1.f - 2.f * hct + hn2 * ct2, MINN));
    float dl = (c2d * ct - c1d * h) * idnd;
    float dn2 = fmaxf(idnd * idnd * (c1d * c1d * hn2 - 2.f * c1d * c2d * hct + c2d * c2d * ct2), 0.f);
    float wv = dl * zg;

    // ---- window C: 2 reductions ----
    {
      float pC0 = redsum(wv * wv);
      float pC1 = redsum(h * wv);
      if (l == 0) { part[13*4 + w] = pC0; part[14*4 + w] = pC1; }
    }
    __syncthreads();                      // (5) window C partials
    float wn2, hw;
    { float4 q;
      q = part4[13]; wn2 = (q.x + q.y + q.z + q.w) * 0.5f;
      q = part4[14]; hw  = (q.x + q.y + q.z + q.w) * 0.5f; }

    float dnv = fmaxf(sqrtf(dn2), MINN);
    float wnv = fmaxf(sqrtf(wn2), MINN);
    float tdd = ftanh(wnv * frcp(dnv) * fatanh(fminf(dnv, ONE_EPS)));
    float szd = tdd * frcp(wnv);
    float zd = wv * szd;
    float hzd = hw * szd;
    float t2v = tdd * tdd;
    float c1f = 1.f + 2.f * hzd + t2v, c2f = 1.f - hn2;
    float idnf = frcp(fmaxf(1.f + 2.f * hzd + hn2 * t2v, MINN));
    float nh = (c1f * h + c2f * zd) * idnf;
    hn2 = fmaxf(idnf * idnf * (c1f * c1f * hn2 + 2.f * c1f * c2f * hzd + c2f * c2f * t2v), 0.f);
    h = nh;
    au += m1 * h; av += m2 * h;
  }
  if (l < 32) {
    uarr[b * 128 + o] = au;
    varr[b * 128 + o] = av;
  }
}

// ---------------- Kernel D: dist + mobius FF + hyperbolic MLR, 1 wave/b ----
__global__ __launch_bounds__(64) void k_final(
    const float* __restrict__ uarr, const float* __restrict__ varr,
    const float* __restrict__ wfu, const float* __restrict__ wfv,
    const float* __restrict__ bff, const float* __restrict__ bffd,
    const float* __restrict__ wfc, const float* __restrict__ pmlr,
    const float* __restrict__ amlr, const int* __restrict__ cids,
    const float* __restrict__ csemb, float* __restrict__ out) {
  int b = blockIdx.x;
  int l = threadIdx.x;
  __shared__ float us[128], vs[128], cbuf[64];
  float q0 = uarr[b * 128 + l], q1 = uarr[b * 128 + 64 + l];
  float r0 = varr[b * 128 + l], r1 = varr[b * 128 + 64 + l];
  us[l] = q0; us[l + 64] = q1; vs[l] = r0; vs[l + 64] = r1;
  __syncthreads();
  float u2 = redsum(q0 * q0 + q1 * q1);
  float v2 = redsum(r0 * r0 + r1 * r1);
  float uv = redsum(q0 * r0 + q1 * r1);
  // dist(u,v)
  float dsq;
  { float x2 = u2, y2 = v2, xy = -uv;
    float c1 = 1.f + 2.f * xy + y2, c2 = 1.f - x2;
    float idn = 1.f / fmaxf(1.f + 2.f * xy + x2 * y2, MINN);
    float d0 = (c1 * (-q0) + c2 * r0) * idn, d1 = (c1 * (-q1) + c2 * r1) * idn;
    float dn2 = redsum(d0 * d0 + d1 * d1);
    dsq = 2.f * atanhf(clampart(sqrtf(dn2))); }
  // mobius_matvec(W_ff_u, u) and (W_ff_v, v): out dim 64, lane l = row l
  float mxu = 0.f, mxv = 0.f;
  #pragma unroll 4
  for (int jc = 0; jc < 128; jc += 4) {
    float4 uu = *reinterpret_cast<const float4*>(&us[jc]);
    float4 vv = *reinterpret_cast<const float4*>(&vs[jc]);
    float4 wu4 = *reinterpret_cast<const float4*>(wfu + (size_t)l * 128 + jc);
    float4 wv4 = *reinterpret_cast<const float4*>(wfv + (size_t)l * 128 + jc);
    mxu += DOT4(wu4, uu); mxv += DOT4(wv4, vv);
  }
  float xnu = fmaxf(sqrtf(u2), MINN);
  float xnv = fmaxf(sqrtf(v2), MINN);
  float mun = fmaxf(sqrtf(redsum(mxu * mxu)), MINN);
  float mvn = fmaxf(sqrtf(redsum(mxv * mxv)), MINN);
  float tu = tanhf(mun / xnu * atanhf(clampart(xnu)));
  float tv = tanhf(mvn / xnv * atanhf(clampart(xnv)));
  float fu = mxu * (tu / mun), fv = mxv * (tv / mvn);
  // out = mobius_add(fu, fv)
  float o1;
  { float x2 = tu * tu, y2 = tv * tv, xy = redsum(fu * fv);
    float c1 = 1.f + 2.f * xy + y2, c2 = 1.f - x2;
    float idn = 1.f / fmaxf(1.f + 2.f * xy + x2 * y2, MINN);
    o1 = (c1 * fu + c2 * fv) * idn; }
  // out = mobius_add(out, b_ff)
  float bffl = bff[l];
  float bf2 = redsum(bffl * bffl);
  float o2;
  { float x2 = redsum(o1 * o1), y2 = bf2, xy = redsum(o1 * bffl);
    float c1 = 1.f + 2.f * xy + y2, c2 = 1.f - x2;
    float idn = 1.f / fmaxf(1.f + 2.f * xy + x2 * y2, MINN);
    o2 = (c1 * o1 + c2 * bffl) * idn; }
  // mobius_scalar_mul(dsq, b_ff_d)
  float bdl = bffd[l];
  float bdn = fmaxf(sqrtf(redsum(bdl * bdl)), MINN);
  float tsm = tanhf(dsq * atanhf(clampart(bdn)));
  float sm = bdl * (tsm / bdn);
  float o3;
  { float x2 = redsum(o2 * o2), y2 = tsm * tsm, xy = redsum(o2 * sm);
    float c1 = 1.f + 2.f * xy + y2, c2 = 1.f - x2;
    float idn = 1.f / fmaxf(1.f + 2.f * xy + x2 * y2, MINN);
    o3 = (c1 * o2 + c2 * sm) * idn; }
  // mobius_matvec(W_ff_common, common)
  int cid = cids[b];
  float ce = csemb[(size_t)cid * 64 + l];
  cbuf[l] = ce;
  __syncthreads();
  float ce2 = redsum(ce * ce);
  float mxc = 0.f;
  #pragma unroll 4
  for (int jc = 0; jc < 64; jc += 4) {
    float4 cc = *reinterpret_cast<const float4*>(&cbuf[jc]);
    float4 wc4 = *reinterpret_cast<const float4*>(wfc + (size_t)l * 64 + jc);
    mxc += DOT4(wc4, cc);
  }
  float xnc = fmaxf(sqrtf(ce2), MINN);
  float mcn = fmaxf(sqrtf(redsum(mxc * mxc)), MINN);
  float tc = tanhf(mcn / xnc * atanhf(clampart(xnc)));
  float fc = mxc * (tc / mcn);
  float o4;
  { float x2 = redsum(o3 * o3), y2 = tc * tc, xy = redsum(o3 * fc);
    float c1 = 1.f + 2.f * xy + y2, c2 = 1.f - x2;
    float idn = 1.f / fmaxf(1.f + 2.f * xy + x2 * y2, MINN);
    o4 = (c1 * o3 + c2 * fc) * idn; }
  // logmap0 then expmap0
  float on = fmaxf(sqrtf(redsum(o4 * o4)), MINN);
  float lo = o4 * (atanhf(clampart(on)) / on);
  float un = fmaxf(sqrtf(redsum(lo * lo)), MINN);
  float eo = lo * (tanhf(un) / un);
  float eo2 = redsum(eo * eo);
  // hyperbolic MLR
  for (int c = 0; c < 4; ++c) {
    float pc = pmlr[c * 64 + l];
    float ac = amlr[c * 64 + l];
    float p2 = redsum(pc * pc);
    float pe = redsum(pc * eo);
    float x2 = p2, y2 = eo2, xy = -pe;
    float c1 = 1.f + 2.f * xy + y2, c2 = 1.f - x2;
    float idn = 1.f / fmaxf(1.f + 2.f * xy + x2 * y2, MINN);
    float mp = (c1 * (-pc) + c2 * eo) * idn;
    float mp2 = redsum(mp * mp);
    float lam = 2.f / (1.f - mp2);
    float na = sqrtf(redsum(ac * ac));
    float au = ac / fmaxf(na, 1e-12f);
    float pda = redsum(mp * au);
    if (l == 0) out[b * 4 + c] = 2.f * na * asinhf(pda * lam);
  }
}

extern "C" void kernel_launch(void* const* d_in, const int* in_sizes, int n_in,
                              void* d_out, int out_size, void* d_ws, size_t ws_size,
                              hipStream_t stream) {
  const float* seq   = (const float*)d_in[0];
  const float* mask1 = (const float*)d_in[1];
  const float* mask2 = (const float*)d_in[2];
  const int*   cids  = (const int*)d_in[3];
  const float* csemb = (const float*)d_in[4];
  const float* wz  = (const float*)d_in[5];
  const float* wr  = (const float*)d_in[6];
  const float* wh  = (const float*)d_in[7];
  const float* uz  = (const float*)d_in[8];
  const float* ur  = (const float*)d_in[9];
  const float* uh  = (const float*)d_in[10];
  const float* bz  = (const float*)d_in[11];
  const float* br  = (const float*)d_in[12];
  const float* bh  = (const float*)d_in[13];
  const float* wfu = (const float*)d_in[14];
  const float* wfv = (const float*)d_in[15];
  const float* bff = (const float*)d_in[16];
  const float* bffd= (const float*)d_in[17];
  const float* wfc = (const float*)d_in[18];
  const float* pmlr= (const float*)d_in[19];
  const float* amlr= (const float*)d_in[20];
  float* ws = (float*)d_ws;
  float* mx      = ws;                             // 32768*384
  float* a_arr   = mx + (size_t)32768 * 384;       // 32768
  float* xn_arr  = a_arr + 32768;                  // 32768
  float* art_arr = xn_arr + 32768;                 // 32768
  float* yn      = art_arr + 32768;                // 32768*4
  float* ubp     = yn + (size_t)32768 * 4;         // 32768*4
  float* ut      = ubp + (size_t)32768 * 4;        // 768*384
  float* uarr    = ut + 768 * 384;                 // 256*128
  float* varr    = uarr + 256 * 128;               // 256*128

  k_stats<<<dim3(2048), dim3(256), 0, stream>>>(seq, a_arr, xn_arr, art_arr);
  k_transU<<<dim3(1152), dim3(256), 0, stream>>>(uz, ur, uh, ut);
  k_gemm<<<dim3(256, 3), dim3(256), 0, stream>>>(seq, ut, mx);
  k_mvnl<<<dim3(4096), dim3(256), 0, stream>>>(mx, a_arr, xn_arr, art_arr, yn,
                                               ubp, bz, br, bh);
  // LDS: 128KB weights + 256 f32 (hs/ps) + 72 f32 partials = 132384 B
  k_scan<<<dim3(256), dim3(256), 132384, stream>>>(mx, yn, ubp, wz, wr, wh,
                                                   bz, br, bh, mask1, mask2,
                                                   uarr, varr);
  k_final<<<dim3(256), dim3(64), 0, stream>>>(uarr, varr, wfu, wfv, bff, bffd,
                                              wfc, pmlr, amlr, cids, csemb,
                                              (float*)d_out);
}

// Round 6
// 880.449 us; speedup vs baseline: 3.7409x; 1.2303x over previous
//
#include <hip/hip_runtime.h>
#include <math.h>

#define MINN 1e-15f
#define ONE_EPS 0.99999f   // 1 - 1e-5 (artanh clamp)

__device__ __forceinline__ float clampart(float x) {
  return fminf(fmaxf(x, -1.0f + 1e-5f), 1.0f - 1e-5f);
}
__device__ __forceinline__ float redsum(float x) {
  #pragma unroll
  for (int m = 32; m; m >>= 1) x += __shfl_xor(x, m);
  return x;
}
__device__ __forceinline__ float frcp(float x) { return __builtin_amdgcn_rcpf(x); }
__device__ __forceinline__ float fexp2(float x) { return __builtin_amdgcn_exp2f(x); }
__device__ __forceinline__ float flog2(float x) { return __builtin_amdgcn_logf(x); }
// x >= 0
__device__ __forceinline__ float ftanh(float x) {
  float e = fexp2(x * 2.88539008f);          // exp(2x)
  return 1.0f - 2.0f * frcp(e + 1.0f);
}
// 0 <= x < 1
__device__ __forceinline__ float fatanh(float x) {
  return 0.34657359f * flog2((1.0f + x) * frcp(1.0f - x));
}
__device__ __forceinline__ float fsig(float x) {
  return frcp(1.0f + fexp2(-1.44269504f * x));
}
#define DOT4(a, b) ((a).x*(b).x + (a).y*(b).y + (a).z*(b).z + (a).w*(b).w)

// ---------------- Kernel A: per-row stats of sequence (expmap0 scalars) ----
__global__ __launch_bounds__(256) void k_stats(const float* __restrict__ seq,
    float* __restrict__ a_arr, float* __restrict__ xn_arr, float* __restrict__ art_arr) {
  int gw = (blockIdx.x * 256 + threadIdx.x) >> 6;
  int lane = threadIdx.x & 63;
  int nw = (gridDim.x * 256) >> 6;
  for (int r = gw; r < 32768; r += nw) {
    const float* row = seq + (size_t)r * 768;
    float s = 0.f;
    #pragma unroll
    for (int c = 0; c < 3; ++c) {
      float4 v = *reinterpret_cast<const float4*>(row + lane * 4 + c * 256);
      s += v.x*v.x + v.y*v.y + v.z*v.z + v.w*v.w;
    }
    s = redsum(s);
    float un  = sqrtf(s);
    float unc = fmaxf(un, MINN);
    float a   = tanhf(unc) / unc;              // proj = a * seq_row
    float xn  = fmaxf(a * un, MINN);           // ||proj|| clamped
    float art = atanhf(clampart(xn));
    if (lane == 0) { a_arr[r] = a; xn_arr[r] = xn; art_arr[r] = art; }
  }
}

// ---------------- Kernel B0: transpose U matrices into [768][384] ----------
__global__ __launch_bounds__(256) void k_transU(const float* __restrict__ uz,
    const float* __restrict__ ur, const float* __restrict__ uh, float* __restrict__ ut) {
  int idx = blockIdx.x * 256 + threadIdx.x;
  if (idx >= 768 * 384) return;
  int k = idx / 384, n = idx % 384;
  const float* U = (n < 128) ? uz : (n < 256 ? ur : uh);
  int i = n & 127;
  ut[idx] = U[(size_t)i * 768 + k];
}

// ---------------- Kernel B: f32 GEMM  MX = seq[32768x768] @ UT[768x384] ----
#define BM 128
#define BN 128
#define BKK 16
__global__ __launch_bounds__(256) void k_gemm(const float* __restrict__ A,
    const float* __restrict__ Bt, float* __restrict__ C) {
  __shared__ float As[BKK][BM];
  __shared__ float Bs[BKK][BN];
  int t = threadIdx.x;
  int m0 = blockIdx.x * BM;
  int n0 = blockIdx.y * BN;
  int tm = t & 15, tn = t >> 4;
  int arow = t >> 2, acol = (t & 3) * 4;
  int bk = t >> 4, bn = (t & 15) * 8;
  float acc[8][8];
  #pragma unroll
  for (int j = 0; j < 8; ++j)
    #pragma unroll
    for (int jj = 0; jj < 8; ++jj) acc[j][jj] = 0.f;
  for (int k0 = 0; k0 < 768; k0 += BKK) {
    float4 a0 = *reinterpret_cast<const float4*>(A + (size_t)(m0 + arow) * 768 + k0 + acol);
    float4 a1 = *reinterpret_cast<const float4*>(A + (size_t)(m0 + arow + 64) * 768 + k0 + acol);
    float4 b0 = *reinterpret_cast<const float4*>(Bt + (size_t)(k0 + bk) * 384 + n0 + bn);
    float4 b1 = *reinterpret_cast<const float4*>(Bt + (size_t)(k0 + bk) * 384 + n0 + bn + 4);
    __syncthreads();
    As[acol + 0][arow] = a0.x; As[acol + 1][arow] = a0.y;
    As[acol + 2][arow] = a0.z; As[acol + 3][arow] = a0.w;
    As[acol + 0][arow + 64] = a1.x; As[acol + 1][arow + 64] = a1.y;
    As[acol + 2][arow + 64] = a1.z; As[acol + 3][arow + 64] = a1.w;
    *reinterpret_cast<float4*>(&Bs[bk][bn]) = b0;
    *reinterpret_cast<float4*>(&Bs[bk][bn + 4]) = b1;
    __syncthreads();
    #pragma unroll
    for (int k = 0; k < BKK; ++k) {
      float af[8], bf[8];
      #pragma unroll
      for (int j = 0; j < 8; ++j) af[j] = As[k][tm + 16 * j];
      #pragma unroll
      for (int j = 0; j < 8; ++j) bf[j] = Bs[k][tn + 16 * j];
      #pragma unroll
      for (int j = 0; j < 8; ++j)
        #pragma unroll
        for (int jj = 0; jj < 8; ++jj) acc[j][jj] += af[j] * bf[jj];
    }
  }
  #pragma unroll
  for (int j = 0; j < 8; ++j)
    #pragma unroll
    for (int jj = 0; jj < 8; ++jj)
      C[(size_t)(m0 + tm + 16 * j) * 384 + n0 + tn + 16 * jj] = acc[j][jj];
}

// -------- Kernel B2: mobius_matvec nonlinearity + <U,b> precompute --------
__global__ __launch_bounds__(256) void k_mvnl(float* __restrict__ mx,
    const float* __restrict__ a_arr, const float* __restrict__ xn_arr,
    const float* __restrict__ art_arr, float* __restrict__ yn, float* __restrict__ ub,
    const float* __restrict__ bzp, const float* __restrict__ brp,
    const float* __restrict__ bhp) {
  int gw = (blockIdx.x * 256 + threadIdx.x) >> 6;
  int lane = threadIdx.x & 63;
  int nw = (gridDim.x * 256) >> 6;
  for (int w = gw; w < 32768 * 3; w += nw) {
    int r = w / 3, g = w - r * 3;
    float* p = mx + (size_t)r * 384 + g * 128;
    float2 v = *reinterpret_cast<float2*>(p + lane * 2);
    const float* bp = (g == 0) ? bzp : (g == 1 ? brp : bhp);
    float2 b2 = reinterpret_cast<const float2*>(bp)[lane];
    float a = a_arr[r];
    float x0 = v.x * a, x1 = v.y * a;  // mx = a * raw  (proj @ U.T)
    float s = redsum(x0 * x0 + x1 * x1);
    float mxn = fmaxf(sqrtf(s), MINN);
    float xn = xn_arr[r], art = art_arr[r];
    float tt = tanhf(mxn / xn * art);
    float sc = tt / mxn;
    float o0 = x0 * sc, o1 = x1 * sc;
    float2 o; o.x = o0; o.y = o1;
    *reinterpret_cast<float2*>(p + lane * 2) = o;
    float dot = redsum(o0 * b2.x + o1 * b2.y);
    if (lane == 0) { yn[(size_t)r * 4 + g] = tt; ub[(size_t)r * 4 + g] = dot; }
  }
}

// ---------------- Kernel C: hyperbolic GRU scan, 4 waves per chain --------
// Lane (w,l) owns output o = 32w + (l&31) over k-half (l>>5). wz/wr in
// swizzled LDS (128KB); wh slice in 64 VGPRs (loops FULLY unrolled so all
// whr[] indices are compile-time constants -> stays in registers, no scratch).
__global__ __launch_bounds__(256, 1) void k_scan(
    const float* __restrict__ ux, const float* __restrict__ yn,
    const float* __restrict__ ub,
    const float* __restrict__ wz, const float* __restrict__ wr, const float* __restrict__ wh,
    const float* __restrict__ bzp, const float* __restrict__ brp, const float* __restrict__ bhp,
    const float* __restrict__ mask1, const float* __restrict__ mask2,
    float* __restrict__ uarr, float* __restrict__ varr) {
  extern __shared__ __align__(16) float lds[];
  float4* wzs4 = (float4*)lds;            // 4096 f4 = 64KB
  float4* wrs4 = wzs4 + 4096;             // 64KB
  float*  hs   = (float*)(wrs4 + 4096);   // 128 f32
  float*  ps   = hs + 128;                // 128 f32
  float*  part = ps + 128;                // 18 reductions x 4 waves = 72 f32
  float4* hs4   = (float4*)hs;
  float4* ps4   = (float4*)ps;
  float4* part4 = (float4*)part;

  int b = blockIdx.x;
  int tid = threadIdx.x;
  int w = tid >> 6;          // wave 0..3
  int l = tid & 63;          // lane
  int l31 = l & 31;
  int kh = l >> 5;           // k-half 0/1
  int o = w * 32 + l31;      // owned output/elem index

  // ---- stage wz, wr into LDS with 32-slot XOR swizzle ----
  const float4* wzg = (const float4*)wz;
  const float4* wrg = (const float4*)wr;
  for (int i = tid; i < 4096; i += 256) {
    int r = i >> 5, s = i & 31;
    int d = (r << 5) | (s ^ (r & 31));
    wzs4[d] = wzg[i];
    wrs4[d] = wrg[i];
  }
  // ---- wh[o][64*kh .. 64*kh+63] into 16 float4 regs (static indices) ----
  const float4* whg = (const float4*)wh;
  float4 whr[16];
  #pragma unroll
  for (int i = 0; i < 16; ++i) whr[i] = whg[o * 32 + kh * 16 + i];

  float bzv = bzp[o], brv = brp[o], bhv = bhp[o];
  // bias norm^2 via window machinery (init region 15..17)
  {
    float v0 = redsum(bzv * bzv);
    float v1 = redsum(brv * brv);
    float v2 = redsum(bhv * bhv);
    if (l == 0) { part[15*4 + w] = v0; part[16*4 + w] = v1; part[17*4 + w] = v2; }
  }
  __syncthreads();  // staging + init writes complete
  float b2z, b2r, b2h;
  { float4 q;
    q = part4[15]; b2z = (q.x + q.y + q.z + q.w) * 0.5f;
    q = part4[16]; b2r = (q.x + q.y + q.z + q.w) * 0.5f;
    q = part4[17]; b2h = (q.x + q.y + q.z + q.w) * 0.5f; }

  float h = 0.f, hn2 = 0.f, au = 0.f, av = 0.f;
  const float*  uxb  = ux + (size_t)b * 128 * 384;
  const float4* ynb4 = (const float4*)yn + (size_t)b * 128;
  const float4* ubb4 = (const float4*)ub + (size_t)b * 128;
  const float*  m1p  = mask1 + b * 128;
  const float*  m2p  = mask2 + b * 128;

  #pragma unroll 1
  for (int t = 0; t < 128; ++t) {
    if (l < 32) hs[o] = h;
    __syncthreads();                      // (1) h visible
    const float* uxt = uxb + t * 384;
    float uz = uxt[o], ur = uxt[128 + o], uh = uxt[256 + o];
    float4 ynt = ynb4[t];
    float4 ubt = ubb4[t];
    float m1 = m1p[t], m2 = m2p[t];

    // ---- z/r matvec: partial dot over own k-half (fully unrolled) ----
    float mzp = 0.f, mrp = 0.f;
    #pragma unroll
    for (int i = 0; i < 16; ++i) {
      float4 hv = hs4[kh * 16 + i];                    // uniform-per-half broadcast
      int slot = (kh * 16 + i) ^ l31;
      float4 a = wzs4[(o << 5) | slot];
      float4 c = wrs4[(o << 5) | slot];
      mzp += DOT4(a, hv);
      mrp += DOT4(c, hv);
    }
    float mz = mzp + __shfl_xor(mzp, 32);
    float mr = mrp + __shfl_xor(mrp, 32);

    // ---- window A: 6 reductions ----
    {
      float pA0 = redsum(mz * mz);
      float pA1 = redsum(mr * mr);
      float pA2 = redsum(mz * uz);
      float pA3 = redsum(mr * ur);
      float pA4 = redsum(mz * bzv);
      float pA5 = redsum(mr * brv);
      if (l == 0) {
        part[0*4 + w] = pA0; part[1*4 + w] = pA1; part[2*4 + w] = pA2;
        part[3*4 + w] = pA3; part[4*4 + w] = pA4; part[5*4 + w] = pA5;
      }
    }
    __syncthreads();                      // (2) window A partials
    float sMz2, sMr2, sMzUz, sMrUr, sMzBz, sMrBr;
    { float4 q;
      q = part4[0]; sMz2  = (q.x + q.y + q.z + q.w) * 0.5f;
      q = part4[1]; sMr2  = (q.x + q.y + q.z + q.w) * 0.5f;
      q = part4[2]; sMzUz = (q.x + q.y + q.z + q.w) * 0.5f;
      q = part4[3]; sMrUr = (q.x + q.y + q.z + q.w) * 0.5f;
      q = part4[4]; sMzBz = (q.x + q.y + q.z + q.w) * 0.5f;
      q = part4[5]; sMrBr = (q.x + q.y + q.z + q.w) * 0.5f; }

    float xnh  = fmaxf(sqrtf(hn2), MINN);
    float arth = fatanh(fminf(xnh, ONE_EPS));
    float axr  = arth * frcp(xnh);
    float ynz = ynt.x, ynr = ynt.y, ynh = ynt.z;
    float ubz = ubt.x, ubr = ubt.y, ubh = ubt.z;   // <U_t, b_gate> precomputed

    // ---- z chain ----
    float mzn = fmaxf(sqrtf(sMz2), MINN);
    float tz  = ftanh(mzn * axr);
    float szs = tz * frcp(mzn);
    float xyz = szs * sMzUz;
    float y2z = ynz * ynz, x2z = tz * tz;
    float c1z = 1.f + 2.f * xyz + y2z, c2z = 1.f - x2z;
    float idnz = frcp(fmaxf(1.f + 2.f * xyz + x2z * y2z, MINN));
    float az  = (c1z * szs * mz + c2z * uz) * idnz;
    float az2 = fmaxf(idnz * idnz * (c1z * c1z * x2z + 2.f * c1z * c2z * xyz + c2z * c2z * y2z), 0.f);
    float azb = idnz * (c1z * szs * sMzBz + c2z * ubz);
    float c1zb = 1.f + 2.f * azb + b2z, c2zb = 1.f - az2;
    float idnzb = frcp(fmaxf(1.f + 2.f * azb + az2 * b2z, MINN));
    float cz = (c1zb * az + c2zb * bzv) * idnzb;
    float cn2z = fmaxf(idnzb * idnzb * (c1zb * c1zb * az2 + 2.f * c1zb * c2zb * azb + c2zb * c2zb * b2z), 0.f);
    float cnz = fmaxf(sqrtf(cn2z), MINN);
    float lsz = fatanh(fminf(cnz, ONE_EPS)) * frcp(cnz);
    float zg = fsig(lsz * cz);

    // ---- r chain ----
    float mrn = fmaxf(sqrtf(sMr2), MINN);
    float trr = ftanh(mrn * axr);
    float srs = trr * frcp(mrn);
    float xyr = srs * sMrUr;
    float y2r = ynr * ynr, x2r = trr * trr;
    float c1r = 1.f + 2.f * xyr + y2r, c2r = 1.f - x2r;
    float idnr = frcp(fmaxf(1.f + 2.f * xyr + x2r * y2r, MINN));
    float ar  = (c1r * srs * mr + c2r * ur) * idnr;
    float ar2 = fmaxf(idnr * idnr * (c1r * c1r * x2r + 2.f * c1r * c2r * xyr + c2r * c2r * y2r), 0.f);
    float arb = idnr * (c1r * srs * sMrBr + c2r * ubr);
    float c1rb = 1.f + 2.f * arb + b2r, c2rb = 1.f - ar2;
    float idnrb = frcp(fmaxf(1.f + 2.f * arb + ar2 * b2r, MINN));
    float cr = (c1rb * ar + c2rb * brv) * idnrb;
    float cn2r = fmaxf(idnrb * idnrb * (c1rb * c1rb * ar2 + 2.f * c1rb * c2rb * arb + c2rb * c2rb * b2r), 0.f);
    float cnr = fmaxf(sqrtf(cn2r), MINN);
    float lsr = fatanh(fminf(cnr, ONE_EPS)) * frcp(cnr);
    float rg = fsig(lsr * cr);

    // ---- rh = h o r (unscaled p; scaling folded into scalars) ----
    float p = h * rg;
    if (l < 32) ps[o] = p;
    __syncthreads();                      // (3) p visible

    // ---- h matvec from regs x ps broadcast (fully unrolled: whr static) ----
    float mhp = 0.f;
    #pragma unroll
    for (int i = 0; i < 16; ++i) {
      float4 pv = ps4[kh * 16 + i];
      mhp += DOT4(whr[i], pv);
    }
    float mh = mhp + __shfl_xor(mhp, 32);

    // ---- window B: 7 reductions ----
    {
      float pB0 = redsum(p * p);
      float pB1 = redsum(mh * mh);
      float pB2 = redsum(mh * uh);
      float pB3 = redsum(mh * bhv);
      float pB4 = redsum(h * mh);
      float pB5 = redsum(h * uh);
      float pB6 = redsum(h * bhv);
      if (l == 0) {
        part[6*4 + w] = pB0; part[7*4 + w] = pB1; part[8*4 + w] = pB2;
        part[9*4 + w] = pB3; part[10*4 + w] = pB4; part[11*4 + w] = pB5;
        part[12*4 + w] = pB6;
      }
    }
    __syncthreads();                      // (4) window B partials
    float pn2, sMh2r, sMhUhr, sMhBhr, sHMhr, sHUh, sHBh;
    { float4 q;
      q = part4[6];  pn2    = (q.x + q.y + q.z + q.w) * 0.5f;
      q = part4[7];  sMh2r  = (q.x + q.y + q.z + q.w) * 0.5f;
      q = part4[8];  sMhUhr = (q.x + q.y + q.z + q.w) * 0.5f;
      q = part4[9];  sMhBhr = (q.x + q.y + q.z + q.w) * 0.5f;
      q = part4[10]; sHMhr  = (q.x + q.y + q.z + q.w) * 0.5f;
      q = part4[11]; sHUh   = (q.x + q.y + q.z + q.w) * 0.5f;
      q = part4[12]; sHBh   = (q.x + q.y + q.z + q.w) * 0.5f; }

    // ---- rh scaling + h~ chain (srt folded) ----
    float pn  = fmaxf(sqrtf(pn2), MINN);
    float trh = ftanh(pn * axr);
    float srt = trh * frcp(pn);
    float xnp  = fmaxf(trh, MINN);
    float artp = fatanh(fminf(xnp, ONE_EPS));
    float mhn  = fmaxf(srt * sqrtf(sMh2r), MINN);
    float th   = ftanh(mhn * artp * frcp(xnp));
    float g    = th * frcp(mhn) * srt;
    float xyh  = g * sMhUhr;
    float y2h = ynh * ynh, x2h = th * th;
    float c1h = 1.f + 2.f * xyh + y2h, c2h = 1.f - x2h;
    float idnh = frcp(fmaxf(1.f + 2.f * xyh + x2h * y2h, MINN));
    float ah  = (c1h * g * mh + c2h * uh) * idnh;
    float ah2 = fmaxf(idnh * idnh * (c1h * c1h * x2h + 2.f * c1h * c2h * xyh + c2h * c2h * y2h), 0.f);
    float ahb = idnh * (c1h * g * sMhBhr + c2h * ubh);
    float hah = idnh * (c1h * g * sHMhr + c2h * sHUh);
    float c1hb = 1.f + 2.f * ahb + b2h, c2hb = 1.f - ah2;
    float idnhb = frcp(fmaxf(1.f + 2.f * ahb + ah2 * b2h, MINN));
    float ct  = (c1hb * ah + c2hb * bhv) * idnhb;
    float ct2 = fmaxf(idnhb * idnhb * (c1hb * c1hb * ah2 + 2.f * c1hb * c2hb * ahb + c2hb * c2hb * b2h), 0.f);
    float hct = idnhb * (c1hb * hah + c2hb * sHBh);

    // ---- delta = mobius_add(-h, h_tilde) ----
    float c1d = 1.f - 2.f * hct + ct2, c2d = 1.f - hn2;
    float idnd = frcp(fmaxf(1.f - 2.f * hct + hn2 * ct2, MINN));
    float dl = (c2d * ct - c1d * h) * idnd;
    float dn2 = fmaxf(idnd * idnd * (c1d * c1d * hn2 - 2.f * c1d * c2d * hct + c2d * c2d * ct2), 0.f);
    float wv = dl * zg;

    // ---- window C: 2 reductions ----
    {
      float pC0 = redsum(wv * wv);
      float pC1 = redsum(h * wv);
      if (l == 0) { part[13*4 + w] = pC0; part[14*4 + w] = pC1; }
    }
    __syncthreads();                      // (5) window C partials
    float wn2, hw;
    { float4 q;
      q = part4[13]; wn2 = (q.x + q.y + q.z + q.w) * 0.5f;
      q = part4[14]; hw  = (q.x + q.y + q.z + q.w) * 0.5f; }

    float dnv = fmaxf(sqrtf(dn2), MINN);
    float wnv = fmaxf(sqrtf(wn2), MINN);
    float tdd = ftanh(wnv * frcp(dnv) * fatanh(fminf(dnv, ONE_EPS)));
    float szd = tdd * frcp(wnv);
    float zd = wv * szd;
    float hzd = hw * szd;
    float t2v = tdd * tdd;
    float c1f = 1.f + 2.f * hzd + t2v, c2f = 1.f - hn2;
    float idnf = frcp(fmaxf(1.f + 2.f * hzd + hn2 * t2v, MINN));
    float nh = (c1f * h + c2f * zd) * idnf;
    hn2 = fmaxf(idnf * idnf * (c1f * c1f * hn2 + 2.f * c1f * c2f * hzd + c2f * c2f * t2v), 0.f);
    h = nh;
    au += m1 * h; av += m2 * h;
  }
  if (l < 32) {
    uarr[b * 128 + o] = au;
    varr[b * 128 + o] = av;
  }
}

// ---------------- Kernel D: dist + mobius FF + hyperbolic MLR, 1 wave/b ----
__global__ __launch_bounds__(64) void k_final(
    const float* __restrict__ uarr, const float* __restrict__ varr,
    const float* __restrict__ wfu, const float* __restrict__ wfv,
    const float* __restrict__ bff, const float* __restrict__ bffd,
    const float* __restrict__ wfc, const float* __restrict__ pmlr,
    const float* __restrict__ amlr, const int* __restrict__ cids,
    const float* __restrict__ csemb, float* __restrict__ out) {
  int b = blockIdx.x;
  int l = threadIdx.x;
  __shared__ float us[128], vs[128], cbuf[64];
  float q0 = uarr[b * 128 + l], q1 = uarr[b * 128 + 64 + l];
  float r0 = varr[b * 128 + l], r1 = varr[b * 128 + 64 + l];
  us[l] = q0; us[l + 64] = q1; vs[l] = r0; vs[l + 64] = r1;
  __syncthreads();
  float u2 = redsum(q0 * q0 + q1 * q1);
  float v2 = redsum(r0 * r0 + r1 * r1);
  float uv = redsum(q0 * r0 + q1 * r1);
  // dist(u,v)
  float dsq;
  { float x2 = u2, y2 = v2, xy = -uv;
    float c1 = 1.f + 2.f * xy + y2, c2 = 1.f - x2;
    float idn = 1.f / fmaxf(1.f + 2.f * xy + x2 * y2, MINN);
    float d0 = (c1 * (-q0) + c2 * r0) * idn, d1 = (c1 * (-q1) + c2 * r1) * idn;
    float dn2 = redsum(d0 * d0 + d1 * d1);
    dsq = 2.f * atanhf(clampart(sqrtf(dn2))); }
  // mobius_matvec(W_ff_u, u) and (W_ff_v, v): out dim 64, lane l = row l
  float mxu = 0.f, mxv = 0.f;
  #pragma unroll 4
  for (int jc = 0; jc < 128; jc += 4) {
    float4 uu = *reinterpret_cast<const float4*>(&us[jc]);
    float4 vv = *reinterpret_cast<const float4*>(&vs[jc]);
    float4 wu4 = *reinterpret_cast<const float4*>(wfu + (size_t)l * 128 + jc);
    float4 wv4 = *reinterpret_cast<const float4*>(wfv + (size_t)l * 128 + jc);
    mxu += DOT4(wu4, uu); mxv += DOT4(wv4, vv);
  }
  float xnu = fmaxf(sqrtf(u2), MINN);
  float xnv = fmaxf(sqrtf(v2), MINN);
  float mun = fmaxf(sqrtf(redsum(mxu * mxu)), MINN);
  float mvn = fmaxf(sqrtf(redsum(mxv * mxv)), MINN);
  float tu = tanhf(mun / xnu * atanhf(clampart(xnu)));
  float tv = tanhf(mvn / xnv * atanhf(clampart(xnv)));
  float fu = mxu * (tu / mun), fv = mxv * (tv / mvn);
  // out = mobius_add(fu, fv)
  float o1;
  { float x2 = tu * tu, y2 = tv * tv, xy = redsum(fu * fv);
    float c1 = 1.f + 2.f * xy + y2, c2 = 1.f - x2;
    float idn = 1.f / fmaxf(1.f + 2.f * xy + x2 * y2, MINN);
    o1 = (c1 * fu + c2 * fv) * idn; }
  // out = mobius_add(out, b_ff)
  float bffl = bff[l];
  float bf2 = redsum(bffl * bffl);
  float o2;
  { float x2 = redsum(o1 * o1), y2 = bf2, xy = redsum(o1 * bffl);
    float c1 = 1.f + 2.f * xy + y2, c2 = 1.f - x2;
    float idn = 1.f / fmaxf(1.f + 2.f * xy + x2 * y2, MINN);
    o2 = (c1 * o1 + c2 * bffl) * idn; }
  // mobius_scalar_mul(dsq, b_ff_d)
  float bdl = bffd[l];
  float bdn = fmaxf(sqrtf(redsum(bdl * bdl)), MINN);
  float tsm = tanhf(dsq * atanhf(clampart(bdn)));
  float sm = bdl * (tsm / bdn);
  float o3;
  { float x2 = redsum(o2 * o2), y2 = tsm * tsm, xy = redsum(o2 * sm);
    float c1 = 1.f + 2.f * xy + y2, c2 = 1.f - x2;
    float idn = 1.f / fmaxf(1.f + 2.f * xy + x2 * y2, MINN);
    o3 = (c1 * o2 + c2 * sm) * idn; }
  // mobius_matvec(W_ff_common, common)
  int cid = cids[b];
  float ce = csemb[(size_t)cid * 64 + l];
  cbuf[l] = ce;
  __syncthreads();
  float ce2 = redsum(ce * ce);
  float mxc = 0.f;
  #pragma unroll 4
  for (int jc = 0; jc < 64; jc += 4) {
    float4 cc = *reinterpret_cast<const float4*>(&cbuf[jc]);
    float4 wc4 = *reinterpret_cast<const float4*>(wfc + (size_t)l * 64 + jc);
    mxc += DOT4(wc4, cc);
  }
  float xnc = fmaxf(sqrtf(ce2), MINN);
  float mcn = fmaxf(sqrtf(redsum(mxc * mxc)), MINN);
  float tc = tanhf(mcn / xnc * atanhf(clampart(xnc)));
  float fc = mxc * (tc / mcn);
  float o4;
  { float x2 = redsum(o3 * o3), y2 = tc * tc, xy = redsum(o3 * fc);
    float c1 = 1.f + 2.f * xy + y2, c2 = 1.f - x2;
    float idn = 1.f / fmaxf(1.f + 2.f * xy + x2 * y2, MINN);
    o4 = (c1 * o3 + c2 * fc) * idn; }
  // logmap0 then expmap0
  float on = fmaxf(sqrtf(redsum(o4 * o4)), MINN);
  float lo = o4 * (atanhf(clampart(on)) / on);
  float un = fmaxf(sqrtf(redsum(lo * lo)), MINN);
  float eo = lo * (tanhf(un) / un);
  float eo2 = redsum(eo * eo);
  // hyperbolic MLR
  for (int c = 0; c < 4; ++c) {
    float pc = pmlr[c * 64 + l];
    float ac = amlr[c * 64 + l];
    float p2 = redsum(pc * pc);
    float pe = redsum(pc * eo);
    float x2 = p2, y2 = eo2, xy = -pe;
    float c1 = 1.f + 2.f * xy + y2, c2 = 1.f - x2;
    float idn = 1.f / fmaxf(1.f + 2.f * xy + x2 * y2, MINN);
    float mp = (c1 * (-pc) + c2 * eo) * idn;
    float mp2 = redsum(mp * mp);
    float lam = 2.f / (1.f - mp2);
    float na = sqrtf(redsum(ac * ac));
    float au = ac / fmaxf(na, 1e-12f);
    float pda = redsum(mp * au);
    if (l == 0) out[b * 4 + c] = 2.f * na * asinhf(pda * lam);
  }
}

extern "C" void kernel_launch(void* const* d_in, const int* in_sizes, int n_in,
                              void* d_out, int out_size, void* d_ws, size_t ws_size,
                              hipStream_t stream) {
  const float* seq   = (const float*)d_in[0];
  const float* mask1 = (const float*)d_in[1];
  const float* mask2 = (const float*)d_in[2];
  const int*   cids  = (const int*)d_in[3];
  const float* csemb = (const float*)d_in[4];
  const float* wz  = (const float*)d_in[5];
  const float* wr  = (const float*)d_in[6];
  const float* wh  = (const float*)d_in[7];
  const float* uz  = (const float*)d_in[8];
  const float* ur  = (const float*)d_in[9];
  const float* uh  = (const float*)d_in[10];
  const float* bz  = (const float*)d_in[11];
  const float* br  = (const float*)d_in[12];
  const float* bh  = (const float*)d_in[13];
  const float* wfu = (const float*)d_in[14];
  const float* wfv = (const float*)d_in[15];
  const float* bff = (const float*)d_in[16];
  const float* bffd= (const float*)d_in[17];
  const float* wfc = (const float*)d_in[18];
  const float* pmlr= (const float*)d_in[19];
  const float* amlr= (const float*)d_in[20];
  float* ws = (float*)d_ws;
  float* mx      = ws;                             // 32768*384
  float* a_arr   = mx + (size_t)32768 * 384;       // 32768
  float* xn_arr  = a_arr + 32768;                  // 32768
  float* art_arr = xn_arr + 32768;                 // 32768
  float* yn      = art_arr + 32768;                // 32768*4
  float* ubp     = yn + (size_t)32768 * 4;         // 32768*4
  float* ut      = ubp + (size_t)32768 * 4;        // 768*384
  float* uarr    = ut + 768 * 384;                 // 256*128
  float* varr    = uarr + 256 * 128;               // 256*128

  k_stats<<<dim3(2048), dim3(256), 0, stream>>>(seq, a_arr, xn_arr, art_arr);
  k_transU<<<dim3(1152), dim3(256), 0, stream>>>(uz, ur, uh, ut);
  k_gemm<<<dim3(256, 3), dim3(256), 0, stream>>>(seq, ut, mx);
  k_mvnl<<<dim3(4096), dim3(256), 0, stream>>>(mx, a_arr, xn_arr, art_arr, yn,
                                               ubp, bz, br, bh);
  // LDS: 128KB weights + 256 f32 (hs/ps) + 72 f32 partials = 132384 B
  k_scan<<<dim3(256), dim3(256), 132384, stream>>>(mx, yn, ubp, wz, wr, wh,
                                                   bz, br, bh, mask1, mask2,
                                                   uarr, varr);
  k_final<<<dim3(256), dim3(64), 0, stream>>>(uarr, varr, wfu, wfv, bff, bffd,
                                              wfc, pmlr, amlr, cids, csemb,
                                              (float*)d_out);
}

// Round 7
// 781.913 us; speedup vs baseline: 4.2123x; 1.1260x over previous
//
#include <hip/hip_runtime.h>
#include <math.h>

#define MINN 1e-15f
#define ONE_EPS 0.99999f   // 1 - 1e-5 (artanh clamp)

__device__ __forceinline__ float clampart(float x) {
  return fminf(fmaxf(x, -1.0f + 1e-5f), 1.0f - 1e-5f);
}
__device__ __forceinline__ float redsum(float x) {
  #pragma unroll
  for (int m = 32; m; m >>= 1) x += __shfl_xor(x, m);
  return x;
}
// 5-level butterfly within each 32-lane half. Valid when values are
// duplicated across halves (lane l == lane l+32): both halves then hold
// the full sum over the 32 distinct values.
__device__ __forceinline__ float redsum32(float x) {
  #pragma unroll
  for (int m = 16; m; m >>= 1) x += __shfl_xor(x, m);
  return x;
}
__device__ __forceinline__ float frcp(float x) { return __builtin_amdgcn_rcpf(x); }
__device__ __forceinline__ float fexp2(float x) { return __builtin_amdgcn_exp2f(x); }
__device__ __forceinline__ float flog2(float x) { return __builtin_amdgcn_logf(x); }
// x >= 0
__device__ __forceinline__ float ftanh(float x) {
  float e = fexp2(x * 2.88539008f);          // exp(2x)
  return 1.0f - 2.0f * frcp(e + 1.0f);
}
// 0 <= x < 1
__device__ __forceinline__ float fatanh(float x) {
  return 0.34657359f * flog2((1.0f + x) * frcp(1.0f - x));
}
__device__ __forceinline__ float fsig(float x) {
  return frcp(1.0f + fexp2(-1.44269504f * x));
}
#define DOT4(a, b) ((a).x*(b).x + (a).y*(b).y + (a).z*(b).z + (a).w*(b).w)

// ---- bf16 split helpers (x = hi + lo, each bf16; rel err ~2^-18) ----------
__device__ __forceinline__ unsigned bfh(float x) {
  unsigned u = __float_as_uint(x);
  return (u + 0x7FFFu + ((u >> 16) & 1u)) >> 16;    // RNE to bf16 bits
}
__device__ __forceinline__ void splitpack(float4 q0, float4 q1,
                                          uint4& hi, uint4& lo) {
  unsigned h0=bfh(q0.x),h1=bfh(q0.y),h2=bfh(q0.z),h3=bfh(q0.w);
  unsigned h4=bfh(q1.x),h5=bfh(q1.y),h6=bfh(q1.z),h7=bfh(q1.w);
  float r0=q0.x-__uint_as_float(h0<<16), r1=q0.y-__uint_as_float(h1<<16);
  float r2=q0.z-__uint_as_float(h2<<16), r3=q0.w-__uint_as_float(h3<<16);
  float r4=q1.x-__uint_as_float(h4<<16), r5=q1.y-__uint_as_float(h5<<16);
  float r6=q1.z-__uint_as_float(h6<<16), r7=q1.w-__uint_as_float(h7<<16);
  hi = make_uint4(h0|(h1<<16), h2|(h3<<16), h4|(h5<<16), h6|(h7<<16));
  lo = make_uint4(bfh(r0)|(bfh(r1)<<16), bfh(r2)|(bfh(r3)<<16),
                  bfh(r4)|(bfh(r5)<<16), bfh(r6)|(bfh(r7)<<16));
}
typedef __attribute__((ext_vector_type(8))) short bf16x8;
typedef __attribute__((ext_vector_type(4))) float f32x4;
__device__ __forceinline__ bf16x8 asfrag(uint4 u) {
  union { uint4 u; bf16x8 f; } c; c.u = u; return c.f;
}

// ---------------- Kernel A: per-row stats of sequence (expmap0 scalars) ----
__global__ __launch_bounds__(256) void k_stats(const float* __restrict__ seq,
    float* __restrict__ a_arr, float* __restrict__ xn_arr, float* __restrict__ art_arr) {
  int gw = (blockIdx.x * 256 + threadIdx.x) >> 6;
  int lane = threadIdx.x & 63;
  int nw = (gridDim.x * 256) >> 6;
  for (int r = gw; r < 32768; r += nw) {
    const float* row = seq + (size_t)r * 768;
    float s = 0.f;
    #pragma unroll
    for (int c = 0; c < 3; ++c) {
      float4 v = *reinterpret_cast<const float4*>(row + lane * 4 + c * 256);
      s += v.x*v.x + v.y*v.y + v.z*v.z + v.w*v.w;
    }
    s = redsum(s);
    float un  = sqrtf(s);
    float unc = fmaxf(un, MINN);
    float a   = tanhf(unc) / unc;              // proj = a * seq_row
    float xn  = fmaxf(a * un, MINN);           // ||proj|| clamped
    float art = atanhf(clampart(xn));
    if (lane == 0) { a_arr[r] = a; xn_arr[r] = xn; art_arr[r] = art; }
  }
}

// -------- Kernel B0: U matrices -> bf16 hi/lo fragment-linear layout -------
// B[k][n] = U_g[n&127][k], subtile (kt,nt) = 32k x 16n. Lane l holds
// B[kt*32 + (l>>4)*8 + j][nt*16 + (l&15)], j=0..7, stored as one uint4.
__global__ __launch_bounds__(256) void k_convB(const float* __restrict__ uz,
    const float* __restrict__ ur, const float* __restrict__ uh,
    uint4* __restrict__ Bh, uint4* __restrict__ Bl) {
  int tid = threadIdx.x;
  int l = tid & 63;
  int s = blockIdx.x * 4 + (tid >> 6);     // 0..575
  int kt = s / 24, nt = s % 24;
  int n = nt * 16 + (l & 15);
  const float* U = (n < 128) ? uz : (n < 256 ? ur : uh);
  int i = n & 127;
  int k = kt * 32 + (l >> 4) * 8;
  float4 q0 = *reinterpret_cast<const float4*>(U + (size_t)i * 768 + k);
  float4 q1 = *reinterpret_cast<const float4*>(U + (size_t)i * 768 + k + 4);
  uint4 hi, lo;
  splitpack(q0, q1, hi, lo);
  Bh[(size_t)(kt * 24 + nt) * 64 + l] = hi;
  Bl[(size_t)(kt * 24 + nt) * 64 + l] = lo;
}

// ---------------- Kernel B: MFMA GEMM  MX = seq[32768x768] @ B[768x384] ----
// bf16x4 split (hi/lo both operands, all 4 products -> ~f32 accuracy).
// A converted from f32 on the fly (the 8 consecutive k-floats per lane ARE
// the 16x16x32 A fragment: m=lane&15, k=(lane>>4)*8+j). Per wave: 2 M-tiles
// x 24 N-tiles; 1024 waves total = 1 wave/SIMD.
__global__ __launch_bounds__(256, 1) void k_gemm_mfma(
    const float* __restrict__ A, const uint4* __restrict__ Bh,
    const uint4* __restrict__ Bl, float* __restrict__ C) {
  int tid = threadIdx.x;
  int l = tid & 63;
  int wid = blockIdx.x * 4 + (tid >> 6);   // 0..1023
  int mt0 = wid * 2;
  int mrow = l & 15;
  int koff = (l >> 4) * 8;
  f32x4 acc[2][24];
  #pragma unroll
  for (int m = 0; m < 2; ++m)
    #pragma unroll
    for (int n = 0; n < 24; ++n) acc[m][n] = (f32x4){0.f, 0.f, 0.f, 0.f};
  #pragma unroll 1
  for (int kt = 0; kt < 24; ++kt) {
    const float* a0p = A + (size_t)(mt0 * 16 + mrow) * 768 + kt * 32 + koff;
    const float* a1p = a0p + 16 * 768;
    float4 q0 = *reinterpret_cast<const float4*>(a0p);
    float4 q1 = *reinterpret_cast<const float4*>(a0p + 4);
    float4 q2 = *reinterpret_cast<const float4*>(a1p);
    float4 q3 = *reinterpret_cast<const float4*>(a1p + 4);
    uint4 ah0u, al0u, ah1u, al1u;
    splitpack(q0, q1, ah0u, al0u);
    splitpack(q2, q3, ah1u, al1u);
    bf16x8 ah0 = asfrag(ah0u), al0 = asfrag(al0u);
    bf16x8 ah1 = asfrag(ah1u), al1 = asfrag(al1u);
    const uint4* bhp = Bh + (size_t)(kt * 24) * 64 + l;
    const uint4* blp = Bl + (size_t)(kt * 24) * 64 + l;
    #pragma unroll
    for (int nt = 0; nt < 24; ++nt) {
      bf16x8 bh = asfrag(bhp[nt * 64]);
      bf16x8 bl = asfrag(blp[nt * 64]);
      acc[0][nt] = __builtin_amdgcn_mfma_f32_16x16x32_bf16(ah0, bh, acc[0][nt], 0, 0, 0);
      acc[0][nt] = __builtin_amdgcn_mfma_f32_16x16x32_bf16(ah0, bl, acc[0][nt], 0, 0, 0);
      acc[0][nt] = __builtin_amdgcn_mfma_f32_16x16x32_bf16(al0, bh, acc[0][nt], 0, 0, 0);
      acc[0][nt] = __builtin_amdgcn_mfma_f32_16x16x32_bf16(al0, bl, acc[0][nt], 0, 0, 0);
      acc[1][nt] = __builtin_amdgcn_mfma_f32_16x16x32_bf16(ah1, bh, acc[1][nt], 0, 0, 0);
      acc[1][nt] = __builtin_amdgcn_mfma_f32_16x16x32_bf16(ah1, bl, acc[1][nt], 0, 0, 0);
      acc[1][nt] = __builtin_amdgcn_mfma_f32_16x16x32_bf16(al1, bh, acc[1][nt], 0, 0, 0);
      acc[1][nt] = __builtin_amdgcn_mfma_f32_16x16x32_bf16(al1, bl, acc[1][nt], 0, 0, 0);
    }
  }
  // epilogue: C/D layout col = lane&15, row = (lane>>4)*4 + j  [m89-verified]
  int r0 = (l >> 4) * 4;
  #pragma unroll
  for (int m = 0; m < 2; ++m) {
    size_t rbase = (size_t)(mt0 + m) * 16;
    #pragma unroll
    for (int nt = 0; nt < 24; ++nt) {
      int col = nt * 16 + mrow;
      #pragma unroll
      for (int j = 0; j < 4; ++j)
        C[(rbase + r0 + j) * 384 + col] = acc[m][nt][j];
    }
  }
}

// -------- Kernel B2: mobius_matvec nonlinearity + <U,b> precompute --------
__global__ __launch_bounds__(256) void k_mvnl(float* __restrict__ mx,
    const float* __restrict__ a_arr, const float* __restrict__ xn_arr,
    const float* __restrict__ art_arr, float* __restrict__ yn, float* __restrict__ ub,
    const float* __restrict__ bzp, const float* __restrict__ brp,
    const float* __restrict__ bhp) {
  int gw = (blockIdx.x * 256 + threadIdx.x) >> 6;
  int lane = threadIdx.x & 63;
  int nw = (gridDim.x * 256) >> 6;
  for (int w = gw; w < 32768 * 3; w += nw) {
    int r = w / 3, g = w - r * 3;
    float* p = mx + (size_t)r * 384 + g * 128;
    float2 v = *reinterpret_cast<float2*>(p + lane * 2);
    const float* bp = (g == 0) ? bzp : (g == 1 ? brp : bhp);
    float2 b2 = reinterpret_cast<const float2*>(bp)[lane];
    float a = a_arr[r];
    float x0 = v.x * a, x1 = v.y * a;  // mx = a * raw  (proj @ U.T)
    float s = redsum(x0 * x0 + x1 * x1);
    float mxn = fmaxf(sqrtf(s), MINN);
    float xn = xn_arr[r], art = art_arr[r];
    float tt = tanhf(mxn / xn * art);
    float sc = tt / mxn;
    float o0 = x0 * sc, o1 = x1 * sc;
    float2 o; o.x = o0; o.y = o1;
    *reinterpret_cast<float2*>(p + lane * 2) = o;
    float dot = redsum(o0 * b2.x + o1 * b2.y);
    if (lane == 0) { yn[(size_t)r * 4 + g] = tt; ub[(size_t)r * 4 + g] = dot; }
  }
}

// ---------------- Kernel C: hyperbolic GRU scan, 4 waves per chain --------
__global__ __launch_bounds__(256, 1) void k_scan(
    const float* __restrict__ ux, const float* __restrict__ yn,
    const float* __restrict__ ub,
    const float* __restrict__ wz, const float* __restrict__ wr, const float* __restrict__ wh,
    const float* __restrict__ bzp, const float* __restrict__ brp, const float* __restrict__ bhp,
    const float* __restrict__ mask1, const float* __restrict__ mask2,
    float* __restrict__ uarr, float* __restrict__ varr) {
  extern __shared__ __align__(16) float lds[];
  float4* wzs4 = (float4*)lds;            // 4096 f4 = 64KB
  float4* wrs4 = wzs4 + 4096;             // 64KB
  float*  hs   = (float*)(wrs4 + 4096);   // 128 f32
  float*  ps   = hs + 128;                // 128 f32
  float*  part = ps + 128;                // 18 reductions x 4 waves = 72 f32
  float4* hs4   = (float4*)hs;
  float4* ps4   = (float4*)ps;
  float4* part4 = (float4*)part;

  int b = blockIdx.x;
  int tid = threadIdx.x;
  int w = tid >> 6;          // wave 0..3
  int l = tid & 63;          // lane
  int l31 = l & 31;
  int kh = l >> 5;           // k-half 0/1
  int o = w * 32 + l31;      // owned output/elem index

  // ---- stage wz, wr into LDS with 32-slot XOR swizzle ----
  const float4* wzg = (const float4*)wz;
  const float4* wrg = (const float4*)wr;
  for (int i = tid; i < 4096; i += 256) {
    int r = i >> 5, s = i & 31;
    int d = (r << 5) | (s ^ (r & 31));
    wzs4[d] = wzg[i];
    wrs4[d] = wrg[i];
  }
  // ---- wh[o][64*kh .. 64*kh+63] into 16 float4 regs (static indices) ----
  const float4* whg = (const float4*)wh;
  float4 whr[16];
  #pragma unroll
  for (int i = 0; i < 16; ++i) whr[i] = whg[o * 32 + kh * 16 + i];

  float bzv = bzp[o], brv = brp[o], bhv = bhp[o];
  {
    float v0 = redsum32(bzv * bzv);
    float v1 = redsum32(brv * brv);
    float v2 = redsum32(bhv * bhv);
    if (l == 0) { part[15*4 + w] = v0; part[16*4 + w] = v1; part[17*4 + w] = v2; }
  }
  __syncthreads();  // staging + init writes complete
  float b2z, b2r, b2h;
  { float4 q;
    q = part4[15]; b2z = q.x + q.y + q.z + q.w;
    q = part4[16]; b2r = q.x + q.y + q.z + q.w;
    q = part4[17]; b2h = q.x + q.y + q.z + q.w; }

  float h = 0.f, hn2 = 0.f, au = 0.f, av = 0.f;
  const float*  uxb  = ux + (size_t)b * 128 * 384;
  const float4* ynb4 = (const float4*)yn + (size_t)b * 128;
  const float4* ubb4 = (const float4*)ub + (size_t)b * 128;
  const float*  m1p  = mask1 + b * 128;
  const float*  m2p  = mask2 + b * 128;

  #pragma unroll 1
  for (int t = 0; t < 128; ++t) {
    if (l < 32) hs[o] = h;
    __syncthreads();                      // (1) h visible
    const float* uxt = uxb + t * 384;
    float uz = uxt[o], ur = uxt[128 + o], uh = uxt[256 + o];
    float4 ynt = ynb4[t];
    float4 ubt = ubb4[t];
    float m1 = m1p[t], m2 = m2p[t];

    // ---- z/r matvec: partial dot over own k-half (fully unrolled) ----
    float mzp = 0.f, mrp = 0.f;
    #pragma unroll
    for (int i = 0; i < 16; ++i) {
      float4 hv = hs4[kh * 16 + i];
      int slot = (kh * 16 + i) ^ l31;
      float4 a = wzs4[(o << 5) | slot];
      float4 c = wrs4[(o << 5) | slot];
      mzp += DOT4(a, hv);
      mrp += DOT4(c, hv);
    }
    float mz = mzp + __shfl_xor(mzp, 32);
    float mr = mrp + __shfl_xor(mrp, 32);

    // ---- window A: 6 reductions (5-level, duplicated halves) ----
    {
      float pA0 = redsum32(mz * mz);
      float pA1 = redsum32(mr * mr);
      float pA2 = redsum32(mz * uz);
      float pA3 = redsum32(mr * ur);
      float pA4 = redsum32(mz * bzv);
      float pA5 = redsum32(mr * brv);
      if (l == 0) {
        part[0*4 + w] = pA0; part[1*4 + w] = pA1; part[2*4 + w] = pA2;
        part[3*4 + w] = pA3; part[4*4 + w] = pA4; part[5*4 + w] = pA5;
      }
    }
    __syncthreads();                      // (2) window A partials
    float sMz2, sMr2, sMzUz, sMrUr, sMzBz, sMrBr;
    { float4 q;
      q = part4[0]; sMz2  = q.x + q.y + q.z + q.w;
      q = part4[1]; sMr2  = q.x + q.y + q.z + q.w;
      q = part4[2]; sMzUz = q.x + q.y + q.z + q.w;
      q = part4[3]; sMrUr = q.x + q.y + q.z + q.w;
      q = part4[4]; sMzBz = q.x + q.y + q.z + q.w;
      q = part4[5]; sMrBr = q.x + q.y + q.z + q.w; }

    float xnh  = fmaxf(sqrtf(hn2), MINN);
    float arth = fatanh(fminf(xnh, ONE_EPS));
    float axr  = arth * frcp(xnh);
    float ynz = ynt.x, ynr = ynt.y, ynh = ynt.z;
    float ubz = ubt.x, ubr = ubt.y, ubh = ubt.z;

    // ---- z chain ----
    float mzn = fmaxf(sqrtf(sMz2), MINN);
    float tz  = ftanh(mzn * axr);
    float szs = tz * frcp(mzn);
    float xyz = szs * sMzUz;
    float y2z = ynz * ynz, x2z = tz * tz;
    float c1z = 1.f + 2.f * xyz + y2z, c2z = 1.f - x2z;
    float idnz = frcp(fmaxf(1.f + 2.f * xyz + x2z * y2z, MINN));
    float az  = (c1z * szs * mz + c2z * uz) * idnz;
    float az2 = fmaxf(idnz * idnz * (c1z * c1z * x2z + 2.f * c1z * c2z * xyz + c2z * c2z * y2z), 0.f);
    float azb = idnz * (c1z * szs * sMzBz + c2z * ubz);
    float c1zb = 1.f + 2.f * azb + b2z, c2zb = 1.f - az2;
    float idnzb = frcp(fmaxf(1.f + 2.f * azb + az2 * b2z, MINN));
    float cz = (c1zb * az + c2zb * bzv) * idnzb;
    float cn2z = fmaxf(idnzb * idnzb * (c1zb * c1zb * az2 + 2.f * c1zb * c2zb * azb + c2zb * c2zb * b2z), 0.f);
    float cnz = fmaxf(sqrtf(cn2z), MINN);
    float lsz = fatanh(fminf(cnz, ONE_EPS)) * frcp(cnz);
    float zg = fsig(lsz * cz);

    // ---- r chain ----
    float mrn = fmaxf(sqrtf(sMr2), MINN);
    float trr = ftanh(mrn * axr);
    float srs = trr * frcp(mrn);
    float xyr = srs * sMrUr;
    float y2r = ynr * ynr, x2r = trr * trr;
    float c1r = 1.f + 2.f * xyr + y2r, c2r = 1.f - x2r;
    float idnr = frcp(fmaxf(1.f + 2.f * xyr + x2r * y2r, MINN));
    float ar  = (c1r * srs * mr + c2r * ur) * idnr;
    float ar2 = fmaxf(idnr * idnr * (c1r * c1r * x2r + 2.f * c1r * c2r * xyr + c2r * c2r * y2r), 0.f);
    float arb = idnr * (c1r * srs * sMrBr + c2r * ubr);
    float c1rb = 1.f + 2.f * arb + b2r, c2rb = 1.f - ar2;
    float idnrb = frcp(fmaxf(1.f + 2.f * arb + ar2 * b2r, MINN));
    float cr = (c1rb * ar + c2rb * brv) * idnrb;
    float cn2r = fmaxf(idnrb * idnrb * (c1rb * c1rb * ar2 + 2.f * c1rb * c2rb * arb + c2rb * c2rb * b2r), 0.f);
    float cnr = fmaxf(sqrtf(cn2r), MINN);
    float lsr = fatanh(fminf(cnr, ONE_EPS)) * frcp(cnr);
    float rg = fsig(lsr * cr);

    // ---- rh = h o r (unscaled p; scaling folded into scalars) ----
    float p = h * rg;
    if (l < 32) ps[o] = p;
    __syncthreads();                      // (3) p visible

    // ---- h matvec from regs x ps broadcast ----
    float mhp = 0.f;
    #pragma unroll
    for (int i = 0; i < 16; ++i) {
      float4 pv = ps4[kh * 16 + i];
      mhp += DOT4(whr[i], pv);
    }
    float mh = mhp + __shfl_xor(mhp, 32);

    // ---- window B: 7 reductions ----
    {
      float pB0 = redsum32(p * p);
      float pB1 = redsum32(mh * mh);
      float pB2 = redsum32(mh * uh);
      float pB3 = redsum32(mh * bhv);
      float pB4 = redsum32(h * mh);
      float pB5 = redsum32(h * uh);
      float pB6 = redsum32(h * bhv);
      if (l == 0) {
        part[6*4 + w] = pB0; part[7*4 + w] = pB1; part[8*4 + w] = pB2;
        part[9*4 + w] = pB3; part[10*4 + w] = pB4; part[11*4 + w] = pB5;
        part[12*4 + w] = pB6;
      }
    }
    __syncthreads();                      // (4) window B partials
    float pn2, sMh2r, sMhUhr, sMhBhr, sHMhr, sHUh, sHBh;
    { float4 q;
      q = part4[6];  pn2    = q.x + q.y + q.z + q.w;
      q = part4[7];  sMh2r  = q.x + q.y + q.z + q.w;
      q = part4[8];  sMhUhr = q.x + q.y + q.z + q.w;
      q = part4[9];  sMhBhr = q.x + q.y + q.z + q.w;
      q = part4[10]; sHMhr  = q.x + q.y + q.z + q.w;
      q = part4[11]; sHUh   = q.x + q.y + q.z + q.w;
      q = part4[12]; sHBh   = q.x + q.y + q.z + q.w; }

    // ---- rh scaling + h~ chain (srt folded) ----
    float pn  = fmaxf(sqrtf(pn2), MINN);
    float trh = ftanh(pn * axr);
    float srt = trh * frcp(pn);
    float xnp  = fmaxf(trh, MINN);
    float artp = fatanh(fminf(xnp, ONE_EPS));
    float mhn  = fmaxf(srt * sqrtf(sMh2r), MINN);
    float th   = ftanh(mhn * artp * frcp(xnp));
    float g    = th * frcp(mhn) * srt;
    float xyh  = g * sMhUhr;
    float y2h = ynh * ynh, x2h = th * th;
    float c1h = 1.f + 2.f * xyh + y2h, c2h = 1.f - x2h;
    float idnh = frcp(fmaxf(1.f + 2.f * xyh + x2h * y2h, MINN));
    float ah  = (c1h * g * mh + c2h * uh) * idnh;
    float ah2 = fmaxf(idnh * idnh * (c1h * c1h * x2h + 2.f * c1h * c2h * xyh + c2h * c2h * y2h), 0.f);
    float ahb = idnh * (c1h * g * sMhBhr + c2h * ubh);
    float hah = idnh * (c1h * g * sHMhr + c2h * sHUh);
    float c1hb = 1.f + 2.f * ahb + b2h, c2hb = 1.f - ah2;
    float idnhb = frcp(fmaxf(1.f + 2.f * ahb + ah2 * b2h, MINN));
    float ct  = (c1hb * ah + c2hb * bhv) * idnhb;
    float ct2 = fmaxf(idnhb * idnhb * (c1hb * c1hb * ah2 + 2.f * c1hb * c2hb * ahb + c2hb * c2hb * b2h), 0.f);
    float hct = idnhb * (c1hb * hah + c2hb * sHBh);

    // ---- delta = mobius_add(-h, h_tilde) ----
    float c1d = 1.f - 2.f * hct + ct2, c2d = 1.f - hn2;
    float idnd = frcp(fmaxf(1.f - 2.f * hct + hn2 * ct2, MINN));
    float dl = (c2d * ct - c1d * h) * idnd;
    float dn2 = fmaxf(idnd * idnd * (c1d * c1d * hn2 - 2.f * c1d * c2d * hct + c2d * c2d * ct2), 0.f);
    float wv = dl * zg;

    // ---- window C: 2 reductions ----
    {
      float pC0 = redsum32(wv * wv);
      float pC1 = redsum32(h * wv);
      if (l == 0) { part[13*4 + w] = pC0; part[14*4 + w] = pC1; }
    }
    __syncthreads();                      // (5) window C partials
    float wn2, hw;
    { float4 q;
      q = part4[13]; wn2 = q.x + q.y + q.z + q.w;
      q = part4[14]; hw  = q.x + q.y + q.z + q.w; }

    float dnv = fmaxf(sqrtf(dn2), MINN);
    float wnv = fmaxf(sqrtf(wn2), MINN);
    float tdd = ftanh(wnv * frcp(dnv) * fatanh(fminf(dnv, ONE_EPS)));
    float szd = tdd * frcp(wnv);
    float zd = wv * szd;
    float hzd = hw * szd;
    float t2v = tdd * tdd;
    float c1f = 1.f + 2.f * hzd + t2v, c2f = 1.f - hn2;
    float idnf = frcp(fmaxf(1.f + 2.f * hzd + hn2 * t2v, MINN));
    float nh = (c1f * h + c2f * zd) * idnf;
    hn2 = fmaxf(idnf * idnf * (c1f * c1f * hn2 + 2.f * c1f * c2f * hzd + c2f * c2f * t2v), 0.f);
    h = nh;
    au += m1 * h; av += m2 * h;
  }
  if (l < 32) {
    uarr[b * 128 + o] = au;
    varr[b * 128 + o] = av;
  }
}

// ---------------- Kernel D: dist + mobius FF + hyperbolic MLR, 1 wave/b ----
__global__ __launch_bounds__(64) void k_final(
    const float* __restrict__ uarr, const float* __restrict__ varr,
    const float* __restrict__ wfu, const float* __restrict__ wfv,
    const float* __restrict__ bff, const float* __restrict__ bffd,
    const float* __restrict__ wfc, const float* __restrict__ pmlr,
    const float* __restrict__ amlr, const int* __restrict__ cids,
    const float* __restrict__ csemb, float* __restrict__ out) {
  int b = blockIdx.x;
  int l = threadIdx.x;
  __shared__ float us[128], vs[128], cbuf[64];
  float q0 = uarr[b * 128 + l], q1 = uarr[b * 128 + 64 + l];
  float r0 = varr[b * 128 + l], r1 = varr[b * 128 + 64 + l];
  us[l] = q0; us[l + 64] = q1; vs[l] = r0; vs[l + 64] = r1;
  __syncthreads();
  float u2 = redsum(q0 * q0 + q1 * q1);
  float v2 = redsum(r0 * r0 + r1 * r1);
  float uv = redsum(q0 * r0 + q1 * r1);
  float dsq;
  { float x2 = u2, y2 = v2, xy = -uv;
    float c1 = 1.f + 2.f * xy + y2, c2 = 1.f - x2;
    float idn = 1.f / fmaxf(1.f + 2.f * xy + x2 * y2, MINN);
    float d0 = (c1 * (-q0) + c2 * r0) * idn, d1 = (c1 * (-q1) + c2 * r1) * idn;
    float dn2 = redsum(d0 * d0 + d1 * d1);
    dsq = 2.f * atanhf(clampart(sqrtf(dn2))); }
  float mxu = 0.f, mxv = 0.f;
  #pragma unroll 4
  for (int jc = 0; jc < 128; jc += 4) {
    float4 uu = *reinterpret_cast<const float4*>(&us[jc]);
    float4 vv = *reinterpret_cast<const float4*>(&vs[jc]);
    float4 wu4 = *reinterpret_cast<const float4*>(wfu + (size_t)l * 128 + jc);
    float4 wv4 = *reinterpret_cast<const float4*>(wfv + (size_t)l * 128 + jc);
    mxu += DOT4(wu4, uu); mxv += DOT4(wv4, vv);
  }
  float xnu = fmaxf(sqrtf(u2), MINN);
  float xnv = fmaxf(sqrtf(v2), MINN);
  float mun = fmaxf(sqrtf(redsum(mxu * mxu)), MINN);
  float mvn = fmaxf(sqrtf(redsum(mxv * mxv)), MINN);
  float tu = tanhf(mun / xnu * atanhf(clampart(xnu)));
  float tv = tanhf(mvn / xnv * atanhf(clampart(xnv)));
  float fu = mxu * (tu / mun), fv = mxv * (tv / mvn);
  float o1;
  { float x2 = tu * tu, y2 = tv * tv, xy = redsum(fu * fv);
    float c1 = 1.f + 2.f * xy + y2, c2 = 1.f - x2;
    float idn = 1.f / fmaxf(1.f + 2.f * xy + x2 * y2, MINN);
    o1 = (c1 * fu + c2 * fv) * idn; }
  float bffl = bff[l];
  float bf2 = redsum(bffl * bffl);
  float o2;
  { float x2 = redsum(o1 * o1), y2 = bf2, xy = redsum(o1 * bffl);
    float c1 = 1.f + 2.f * xy + y2, c2 = 1.f - x2;
    float idn = 1.f / fmaxf(1.f + 2.f * xy + x2 * y2, MINN);
    o2 = (c1 * o1 + c2 * bffl) * idn; }
  float bdl = bffd[l];
  float bdn = fmaxf(sqrtf(redsum(bdl * bdl)), MINN);
  float tsm = tanhf(dsq * atanhf(clampart(bdn)));
  float sm = bdl * (tsm / bdn);
  float o3;
  { float x2 = redsum(o2 * o2), y2 = tsm * tsm, xy = redsum(o2 * sm);
    float c1 = 1.f + 2.f * xy + y2, c2 = 1.f - x2;
    float idn = 1.f / fmaxf(1.f + 2.f * xy + x2 * y2, MINN);
    o3 = (c1 * o2 + c2 * sm) * idn; }
  int cid = cids[b];
  float ce = csemb[(size_t)cid * 64 + l];
  cbuf[l] = ce;
  __syncthreads();
  float ce2 = redsum(ce * ce);
  float mxc = 0.f;
  #pragma unroll 4
  for (int jc = 0; jc < 64; jc += 4) {
    float4 cc = *reinterpret_cast<const float4*>(&cbuf[jc]);
    float4 wc4 = *reinterpret_cast<const float4*>(wfc + (size_t)l * 64 + jc);
    mxc += DOT4(wc4, cc);
  }
  float xnc = fmaxf(sqrtf(ce2), MINN);
  float mcn = fmaxf(sqrtf(redsum(mxc * mxc)), MINN);
  float tc = tanhf(mcn / xnc * atanhf(clampart(xnc)));
  float fc = mxc * (tc / mcn);
  float o4;
  { float x2 = redsum(o3 * o3), y2 = tc * tc, xy = redsum(o3 * fc);
    float c1 = 1.f + 2.f * xy + y2, c2 = 1.f - x2;
    float idn = 1.f / fmaxf(1.f + 2.f * xy + x2 * y2, MINN);
    o4 = (c1 * o3 + c2 * fc) * idn; }
  float on = fmaxf(sqrtf(redsum(o4 * o4)), MINN);
  float lo = o4 * (atanhf(clampart(on)) / on);
  float un = fmaxf(sqrtf(redsum(lo * lo)), MINN);
  float eo = lo * (tanhf(un) / un);
  float eo2 = redsum(eo * eo);
  for (int c = 0; c < 4; ++c) {
    float pc = pmlr[c * 64 + l];
    float ac = amlr[c * 64 + l];
    float p2 = redsum(pc * pc);
    float pe = redsum(pc * eo);
    float x2 = p2, y2 = eo2, xy = -pe;
    float c1 = 1.f + 2.f * xy + y2, c2 = 1.f - x2;
    float idn = 1.f / fmaxf(1.f + 2.f * xy + x2 * y2, MINN);
    float mp = (c1 * (-pc) + c2 * eo) * idn;
    float mp2 = redsum(mp * mp);
    float lam = 2.f / (1.f - mp2);
    float na = sqrtf(redsum(ac * ac));
    float au = ac / fmaxf(na, 1e-12f);
    float pda = redsum(mp * au);
    if (l == 0) out[b * 4 + c] = 2.f * na * asinhf(pda * lam);
  }
}

extern "C" void kernel_launch(void* const* d_in, const int* in_sizes, int n_in,
                              void* d_out, int out_size, void* d_ws, size_t ws_size,
                              hipStream_t stream) {
  const float* seq   = (const float*)d_in[0];
  const float* mask1 = (const float*)d_in[1];
  const float* mask2 = (const float*)d_in[2];
  const int*   cids  = (const int*)d_in[3];
  const float* csemb = (const float*)d_in[4];
  const float* wz  = (const float*)d_in[5];
  const float* wr  = (const float*)d_in[6];
  const float* wh  = (const float*)d_in[7];
  const float* uz  = (const float*)d_in[8];
  const float* ur  = (const float*)d_in[9];
  const float* uh  = (const float*)d_in[10];
  const float* bz  = (const float*)d_in[11];
  const float* br  = (const float*)d_in[12];
  const float* bh  = (const float*)d_in[13];
  const float* wfu = (const float*)d_in[14];
  const float* wfv = (const float*)d_in[15];
  const float* bff = (const float*)d_in[16];
  const float* bffd= (const float*)d_in[17];
  const float* wfc = (const float*)d_in[18];
  const float* pmlr= (const float*)d_in[19];
  const float* amlr= (const float*)d_in[20];
  float* ws = (float*)d_ws;
  float* mx      = ws;                             // 32768*384
  float* a_arr   = mx + (size_t)32768 * 384;       // 32768
  float* xn_arr  = a_arr + 32768;                  // 32768
  float* art_arr = xn_arr + 32768;                 // 32768
  float* yn      = art_arr + 32768;                // 32768*4
  float* ubp     = yn + (size_t)32768 * 4;         // 32768*4
  float* bhi_f   = ubp + (size_t)32768 * 4;        // 36864 uint4 = 147456 f32
  float* blo_f   = bhi_f + 147456;                 // 147456 f32
  float* uarr    = blo_f + 147456;                 // 256*128
  float* varr    = uarr + 256 * 128;               // 256*128
  uint4* Bh = (uint4*)bhi_f;
  uint4* Bl = (uint4*)blo_f;

  k_stats<<<dim3(2048), dim3(256), 0, stream>>>(seq, a_arr, xn_arr, art_arr);
  k_convB<<<dim3(144), dim3(256), 0, stream>>>(uz, ur, uh, Bh, Bl);
  k_gemm_mfma<<<dim3(256), dim3(256), 0, stream>>>(seq, Bh, Bl, mx);
  k_mvnl<<<dim3(4096), dim3(256), 0, stream>>>(mx, a_arr, xn_arr, art_arr, yn,
                                               ubp, bz, br, bh);
  // LDS: 128KB weights + 256 f32 (hs/ps) + 72 f32 partials = 132384 B
  k_scan<<<dim3(256), dim3(256), 132384, stream>>>(mx, yn, ubp, wz, wr, wh,
                                                   bz, br, bh, mask1, mask2,
                                                   uarr, varr);
  k_final<<<dim3(256), dim3(64), 0, stream>>>(uarr, varr, wfu, wfv, bff, bffd,
                                              wfc, pmlr, amlr, cids, csemb,
                                              (float*)d_out);
}

// Round 8
// 586.043 us; speedup vs baseline: 5.6202x; 1.3342x over previous
//
#include <hip/hip_runtime.h>
#include <math.h>

#define MINN 1e-15f
#define ONE_EPS 0.99999f   // 1 - 1e-5 (artanh clamp)

__device__ __forceinline__ float clampart(float x) {
  return fminf(fmaxf(x, -1.0f + 1e-5f), 1.0f - 1e-5f);
}
__device__ __forceinline__ float redsum(float x) {
  #pragma unroll
  for (int m = 32; m; m >>= 1) x += __shfl_xor(x, m);
  return x;
}
// 5-level butterfly within each 32-lane half (valid for half-duplicated values)
__device__ __forceinline__ float redsum32(float x) {
  #pragma unroll
  for (int m = 16; m; m >>= 1) x += __shfl_xor(x, m);
  return x;
}
__device__ __forceinline__ float frcp(float x) { return __builtin_amdgcn_rcpf(x); }
__device__ __forceinline__ float fexp2(float x) { return __builtin_amdgcn_exp2f(x); }
__device__ __forceinline__ float flog2(float x) { return __builtin_amdgcn_logf(x); }
__device__ __forceinline__ float ftanh(float x) {
  float e = fexp2(x * 2.88539008f);
  return 1.0f - 2.0f * frcp(e + 1.0f);
}
__device__ __forceinline__ float fatanh(float x) {
  return 0.34657359f * flog2((1.0f + x) * frcp(1.0f - x));
}
__device__ __forceinline__ float fsig(float x) {
  return frcp(1.0f + fexp2(-1.44269504f * x));
}
#define DOT4(a, b) ((a).x*(b).x + (a).y*(b).y + (a).z*(b).z + (a).w*(b).w)

// ---- bf16 split helpers (x = hi + lo, each bf16; rel err ~2^-18) ----------
__device__ __forceinline__ unsigned bfh(float x) {
  unsigned u = __float_as_uint(x);
  return (u + 0x7FFFu + ((u >> 16) & 1u)) >> 16;    // RNE to bf16 bits
}
__device__ __forceinline__ void splitpack(float4 q0, float4 q1,
                                          uint4& hi, uint4& lo) {
  unsigned h0=bfh(q0.x),h1=bfh(q0.y),h2=bfh(q0.z),h3=bfh(q0.w);
  unsigned h4=bfh(q1.x),h5=bfh(q1.y),h6=bfh(q1.z),h7=bfh(q1.w);
  float r0=q0.x-__uint_as_float(h0<<16), r1=q0.y-__uint_as_float(h1<<16);
  float r2=q0.z-__uint_as_float(h2<<16), r3=q0.w-__uint_as_float(h3<<16);
  float r4=q1.x-__uint_as_float(h4<<16), r5=q1.y-__uint_as_float(h5<<16);
  float r6=q1.z-__uint_as_float(h6<<16), r7=q1.w-__uint_as_float(h7<<16);
  hi = make_uint4(h0|(h1<<16), h2|(h3<<16), h4|(h5<<16), h6|(h7<<16));
  lo = make_uint4(bfh(r0)|(bfh(r1)<<16), bfh(r2)|(bfh(r3)<<16),
                  bfh(r4)|(bfh(r5)<<16), bfh(r6)|(bfh(r7)<<16));
}
typedef __attribute__((ext_vector_type(8))) short bf16x8;
typedef __attribute__((ext_vector_type(4))) float f32x4;
__device__ __forceinline__ bf16x8 asfrag(uint4 u) {
  union { uint4 u; bf16x8 f; } c; c.u = u; return c.f;
}

// -------- Kernel B0: U matrices -> bf16 hi/lo fragment-linear layout -------
__global__ __launch_bounds__(256) void k_convB(const float* __restrict__ uz,
    const float* __restrict__ ur, const float* __restrict__ uh,
    uint4* __restrict__ Bh, uint4* __restrict__ Bl) {
  int tid = threadIdx.x;
  int l = tid & 63;
  int s = blockIdx.x * 4 + (tid >> 6);     // 0..575
  int kt = s / 24, nt = s % 24;
  int n = nt * 16 + (l & 15);
  const float* U = (n < 128) ? uz : (n < 256 ? ur : uh);
  int i = n & 127;
  int k = kt * 32 + (l >> 4) * 8;
  float4 q0 = *reinterpret_cast<const float4*>(U + (size_t)i * 768 + k);
  float4 q1 = *reinterpret_cast<const float4*>(U + (size_t)i * 768 + k + 4);
  uint4 hi, lo;
  splitpack(q0, q1, hi, lo);
  Bh[(size_t)(kt * 24 + nt) * 64 + l] = hi;
  Bl[(size_t)(kt * 24 + nt) * 64 + l] = lo;
}

// -------- Kernel B: fused MFMA GEMM + expmap0 stats + mobius_matvec NL -----
// Per wave: 2 M-tiles x all 24 N-tiles -> owns 32 full output rows AND reads
// those rows' full seq slices. Fuses: seq row norms (expmap0 scalars),
// GEMM (bf16 hi/lo x4), per-row-per-gate output norms + tanh scaling, yn/ub.
__global__ __launch_bounds__(256, 1) void k_gemm_fused(
    const float* __restrict__ A, const uint4* __restrict__ Bh,
    const uint4* __restrict__ Bl,
    const float* __restrict__ bzp, const float* __restrict__ brp,
    const float* __restrict__ bhp,
    float* __restrict__ mx, float* __restrict__ yn, float* __restrict__ ub) {
  int tid = threadIdx.x;
  int l = tid & 63;
  int wid = blockIdx.x * 4 + (tid >> 6);   // 0..1023
  int mt0 = wid * 2;
  int mrow = l & 15;
  int koff = (l >> 4) * 8;
  f32x4 acc[2][24];
  #pragma unroll
  for (int m = 0; m < 2; ++m)
    #pragma unroll
    for (int n = 0; n < 24; ++n) acc[m][n] = (f32x4){0.f, 0.f, 0.f, 0.f};
  float ssA0 = 0.f, ssA1 = 0.f;
  #pragma unroll 1
  for (int kt = 0; kt < 24; ++kt) {
    const float* a0p = A + (size_t)(mt0 * 16 + mrow) * 768 + kt * 32 + koff;
    const float* a1p = a0p + 16 * 768;
    float4 q0 = *reinterpret_cast<const float4*>(a0p);
    float4 q1 = *reinterpret_cast<const float4*>(a0p + 4);
    float4 q2 = *reinterpret_cast<const float4*>(a1p);
    float4 q3 = *reinterpret_cast<const float4*>(a1p + 4);
    ssA0 += DOT4(q0, q0) + DOT4(q1, q1);
    ssA1 += DOT4(q2, q2) + DOT4(q3, q3);
    uint4 ah0u, al0u, ah1u, al1u;
    splitpack(q0, q1, ah0u, al0u);
    splitpack(q2, q3, ah1u, al1u);
    bf16x8 ah0 = asfrag(ah0u), al0 = asfrag(al0u);
    bf16x8 ah1 = asfrag(ah1u), al1 = asfrag(al1u);
    const uint4* bhp4 = Bh + (size_t)(kt * 24) * 64 + l;
    const uint4* blp4 = Bl + (size_t)(kt * 24) * 64 + l;
    #pragma unroll
    for (int nt = 0; nt < 24; ++nt) {
      bf16x8 bh = asfrag(bhp4[nt * 64]);
      bf16x8 bl = asfrag(blp4[nt * 64]);
      acc[0][nt] = __builtin_amdgcn_mfma_f32_16x16x32_bf16(ah0, bh, acc[0][nt], 0, 0, 0);
      acc[0][nt] = __builtin_amdgcn_mfma_f32_16x16x32_bf16(ah0, bl, acc[0][nt], 0, 0, 0);
      acc[0][nt] = __builtin_amdgcn_mfma_f32_16x16x32_bf16(al0, bh, acc[0][nt], 0, 0, 0);
      acc[0][nt] = __builtin_amdgcn_mfma_f32_16x16x32_bf16(al0, bl, acc[0][nt], 0, 0, 0);
      acc[1][nt] = __builtin_amdgcn_mfma_f32_16x16x32_bf16(ah1, bh, acc[1][nt], 0, 0, 0);
      acc[1][nt] = __builtin_amdgcn_mfma_f32_16x16x32_bf16(ah1, bl, acc[1][nt], 0, 0, 0);
      acc[1][nt] = __builtin_amdgcn_mfma_f32_16x16x32_bf16(al1, bh, acc[1][nt], 0, 0, 0);
      acc[1][nt] = __builtin_amdgcn_mfma_f32_16x16x32_bf16(al1, bl, acc[1][nt], 0, 0, 0);
    }
  }
  // ---- seq row stats (A layout: lane covers koff-quarter of row mrow) ----
  ssA0 += __shfl_xor(ssA0, 16); ssA0 += __shfl_xor(ssA0, 32);
  ssA1 += __shfl_xor(ssA1, 16); ssA1 += __shfl_xor(ssA1, 32);
  float aA[2], rxA[2];
  {
    float un0 = sqrtf(ssA0), unc0 = fmaxf(un0, MINN);
    float a0 = tanhf(unc0) / unc0;
    float xn0 = fmaxf(a0 * un0, MINN);
    aA[0] = a0; rxA[0] = atanhf(clampart(xn0)) / xn0;
    float un1 = sqrtf(ssA1), unc1 = fmaxf(un1, MINN);
    float a1 = tanhf(unc1) / unc1;
    float xn1 = fmaxf(a1 * un1, MINN);
    aA[1] = a1; rxA[1] = atanhf(clampart(xn1)) / xn1;
  }
  // ---- remap stats to C-layout rows (row = r0 + j) ----
  int r0 = (l >> 4) * 4;
  float aC[2][4], rxC[2][4];
  #pragma unroll
  for (int m = 0; m < 2; ++m)
    #pragma unroll
    for (int j = 0; j < 4; ++j) {
      aC[m][j]  = __shfl(aA[m],  r0 + j);
      rxC[m][j] = __shfl(rxA[m], r0 + j);
    }
  // ---- bias values for ub dots: b_g[col], col = nt*16 + mrow ----
  float bv0[8], bv1[8], bv2[8];
  #pragma unroll
  for (int i = 0; i < 8; ++i) {
    bv0[i] = bzp[i * 16 + mrow];
    bv1[i] = brp[i * 16 + mrow];
    bv2[i] = bhp[i * 16 + mrow];
  }
  // ---- per (m, gate): row norms over 128 cols, scale, store ----
#define GATE_EPI(m, g, bvarr)                                                 \
  {                                                                           \
    float ss0=0.f,ss1=0.f,ss2=0.f,ss3=0.f,sb0=0.f,sb1=0.f,sb2=0.f,sb3=0.f;    \
    _Pragma("unroll")                                                         \
    for (int ntg = 0; ntg < 8; ++ntg) {                                       \
      f32x4 v = acc[m][(g)*8 + ntg];                                          \
      float bb = bvarr[ntg];                                                  \
      ss0 += v[0]*v[0]; sb0 += v[0]*bb;                                       \
      ss1 += v[1]*v[1]; sb1 += v[1]*bb;                                       \
      ss2 += v[2]*v[2]; sb2 += v[2]*bb;                                       \
      ss3 += v[3]*v[3]; sb3 += v[3]*bb;                                       \
    }                                                                         \
    _Pragma("unroll")                                                         \
    for (int mk = 1; mk <= 8; mk <<= 1) {                                     \
      ss0 += __shfl_xor(ss0, mk); sb0 += __shfl_xor(sb0, mk);                 \
      ss1 += __shfl_xor(ss1, mk); sb1 += __shfl_xor(sb1, mk);                 \
      ss2 += __shfl_xor(ss2, mk); sb2 += __shfl_xor(sb2, mk);                 \
      ss3 += __shfl_xor(ss3, mk); sb3 += __shfl_xor(sb3, mk);                 \
    }                                                                         \
    float ssv[4] = {ss0, ss1, ss2, ss3};                                      \
    float sbv[4] = {sb0, sb1, sb2, sb3};                                      \
    float scale[4];                                                           \
    _Pragma("unroll")                                                         \
    for (int j = 0; j < 4; ++j) {                                             \
      float mxn = fmaxf(aC[m][j] * sqrtf(ssv[j]), MINN);                      \
      float tt = tanhf(mxn * rxC[m][j]);                                      \
      float sc = tt / mxn;                                                    \
      scale[j] = aC[m][j] * sc;                                               \
      if (mrow == 0) {                                                        \
        size_t row = (size_t)(mt0 + (m)) * 16 + r0 + j;                       \
        yn[row * 4 + (g)] = tt;                                               \
        ub[row * 4 + (g)] = scale[j] * sbv[j];                                \
      }                                                                       \
    }                                                                         \
    _Pragma("unroll")                                                         \
    for (int ntg = 0; ntg < 8; ++ntg) {                                       \
      int col = ((g)*8 + ntg) * 16 + mrow;                                    \
      f32x4 v = acc[m][(g)*8 + ntg];                                          \
      size_t rbase = (size_t)(mt0 + (m)) * 16 + r0;                           \
      _Pragma("unroll")                                                       \
      for (int j = 0; j < 4; ++j)                                             \
        mx[(rbase + j) * 384 + col] = v[j] * scale[j];                        \
    }                                                                         \
  }
  GATE_EPI(0, 0, bv0) GATE_EPI(0, 1, bv1) GATE_EPI(0, 2, bv2)
  GATE_EPI(1, 0, bv0) GATE_EPI(1, 1, bv1) GATE_EPI(1, 2, bv2)
#undef GATE_EPI
}

// ---------------- Kernel C: hyperbolic GRU scan, 4 waves per chain --------
// ALL weights (wz, wr, wh k-half rows) in per-lane VGPRs: 48 float4 = 192
// regs, statically indexed. LDS only for h/p broadcast + 18x4 partials.
// Next-step ux loads prefetched one iteration ahead.
__global__ __launch_bounds__(256, 1) void k_scan(
    const float* __restrict__ ux, const float* __restrict__ yn,
    const float* __restrict__ ub,
    const float* __restrict__ wz, const float* __restrict__ wr, const float* __restrict__ wh,
    const float* __restrict__ bzp, const float* __restrict__ brp, const float* __restrict__ bhp,
    const float* __restrict__ mask1, const float* __restrict__ mask2,
    float* __restrict__ uarr, float* __restrict__ varr) {
  __shared__ __align__(16) float hs[128];
  __shared__ __align__(16) float ps[128];
  __shared__ __align__(16) float part[72];
  float4* hs4   = (float4*)hs;
  float4* ps4   = (float4*)ps;
  float4* part4 = (float4*)part;

  int b = blockIdx.x;
  int tid = threadIdx.x;
  int w = tid >> 6;          // wave 0..3
  int l = tid & 63;          // lane
  int l31 = l & 31;
  int kh = l >> 5;           // k-half 0/1
  int o = w * 32 + l31;      // owned output/elem index

  // ---- weight rows into registers (static indices) ----
  const float4* wzg = (const float4*)wz;
  const float4* wrg = (const float4*)wr;
  const float4* whg = (const float4*)wh;
  float4 wzr[16], wrr[16], whr[16];
  #pragma unroll
  for (int i = 0; i < 16; ++i) {
    wzr[i] = wzg[o * 32 + kh * 16 + i];
    wrr[i] = wrg[o * 32 + kh * 16 + i];
    whr[i] = whg[o * 32 + kh * 16 + i];
  }

  float bzv = bzp[o], brv = brp[o], bhv = bhp[o];
  {
    float v0 = redsum32(bzv * bzv);
    float v1 = redsum32(brv * brv);
    float v2 = redsum32(bhv * bhv);
    if (l == 0) { part[15*4 + w] = v0; part[16*4 + w] = v1; part[17*4 + w] = v2; }
  }
  __syncthreads();
  float b2z, b2r, b2h;
  { float4 q;
    q = part4[15]; b2z = q.x + q.y + q.z + q.w;
    q = part4[16]; b2r = q.x + q.y + q.z + q.w;
    q = part4[17]; b2h = q.x + q.y + q.z + q.w; }

  float h = 0.f, hn2 = 0.f, au = 0.f, av = 0.f;
  const float*  uxb  = ux + (size_t)b * 128 * 384;
  const float4* ynb4 = (const float4*)yn + (size_t)b * 128;
  const float4* ubb4 = (const float4*)ub + (size_t)b * 128;
  const float*  m1p  = mask1 + b * 128;
  const float*  m2p  = mask2 + b * 128;

  // prefetch t=0 ux values
  float cuz = uxb[o], cur = uxb[128 + o], cuh = uxb[256 + o];

  #pragma unroll 1
  for (int t = 0; t < 128; ++t) {
    if (l < 32) hs[o] = h;
    __syncthreads();                      // (1) h visible
    // issue t+1 ux prefetch (hidden under this step's compute)
    int tn = (t + 1 < 128) ? t + 1 : 127;
    const float* uxn = uxb + tn * 384;
    float nuz = uxn[o], nur = uxn[128 + o], nuh = uxn[256 + o];
    float uz = cuz, ur = cur, uh = cuh;
    float4 ynt = ynb4[t];
    float4 ubt = ubb4[t];
    float m1 = m1p[t], m2 = m2p[t];

    // ---- z/r matvec: register weights x LDS-broadcast h ----
    float mzp = 0.f, mrp = 0.f;
    #pragma unroll
    for (int i = 0; i < 16; ++i) {
      float4 hv = hs4[kh * 16 + i];
      mzp += DOT4(wzr[i], hv);
      mrp += DOT4(wrr[i], hv);
    }
    float mz = mzp + __shfl_xor(mzp, 32);
    float mr = mrp + __shfl_xor(mrp, 32);

    // ---- window A: 6 reductions ----
    {
      float pA0 = redsum32(mz * mz);
      float pA1 = redsum32(mr * mr);
      float pA2 = redsum32(mz * uz);
      float pA3 = redsum32(mr * ur);
      float pA4 = redsum32(mz * bzv);
      float pA5 = redsum32(mr * brv);
      if (l == 0) {
        part[0*4 + w] = pA0; part[1*4 + w] = pA1; part[2*4 + w] = pA2;
        part[3*4 + w] = pA3; part[4*4 + w] = pA4; part[5*4 + w] = pA5;
      }
    }
    __syncthreads();                      // (2) window A partials
    float sMz2, sMr2, sMzUz, sMrUr, sMzBz, sMrBr;
    { float4 q;
      q = part4[0]; sMz2  = q.x + q.y + q.z + q.w;
      q = part4[1]; sMr2  = q.x + q.y + q.z + q.w;
      q = part4[2]; sMzUz = q.x + q.y + q.z + q.w;
      q = part4[3]; sMrUr = q.x + q.y + q.z + q.w;
      q = part4[4]; sMzBz = q.x + q.y + q.z + q.w;
      q = part4[5]; sMrBr = q.x + q.y + q.z + q.w; }

    float xnh  = fmaxf(sqrtf(hn2), MINN);
    float arth = fatanh(fminf(xnh, ONE_EPS));
    float axr  = arth * frcp(xnh);
    float ynz = ynt.x, ynr = ynt.y, ynh = ynt.z;
    float ubz = ubt.x, ubr = ubt.y, ubh = ubt.z;

    // ---- z chain ----
    float mzn = fmaxf(sqrtf(sMz2), MINN);
    float tz  = ftanh(mzn * axr);
    float szs = tz * frcp(mzn);
    float xyz = szs * sMzUz;
    float y2z = ynz * ynz, x2z = tz * tz;
    float c1z = 1.f + 2.f * xyz + y2z, c2z = 1.f - x2z;
    float idnz = frcp(fmaxf(1.f + 2.f * xyz + x2z * y2z, MINN));
    float az  = (c1z * szs * mz + c2z * uz) * idnz;
    float az2 = fmaxf(idnz * idnz * (c1z * c1z * x2z + 2.f * c1z * c2z * xyz + c2z * c2z * y2z), 0.f);
    float azb = idnz * (c1z * szs * sMzBz + c2z * ubz);
    float c1zb = 1.f + 2.f * azb + b2z, c2zb = 1.f - az2;
    float idnzb = frcp(fmaxf(1.f + 2.f * azb + az2 * b2z, MINN));
    float cz = (c1zb * az + c2zb * bzv) * idnzb;
    float cn2z = fmaxf(idnzb * idnzb * (c1zb * c1zb * az2 + 2.f * c1zb * c2zb * azb + c2zb * c2zb * b2z), 0.f);
    float cnz = fmaxf(sqrtf(cn2z), MINN);
    float lsz = fatanh(fminf(cnz, ONE_EPS)) * frcp(cnz);
    float zg = fsig(lsz * cz);

    // ---- r chain ----
    float mrn = fmaxf(sqrtf(sMr2), MINN);
    float trr = ftanh(mrn * axr);
    float srs = trr * frcp(mrn);
    float xyr = srs * sMrUr;
    float y2r = ynr * ynr, x2r = trr * trr;
    float c1r = 1.f + 2.f * xyr + y2r, c2r = 1.f - x2r;
    float idnr = frcp(fmaxf(1.f + 2.f * xyr + x2r * y2r, MINN));
    float ar  = (c1r * srs * mr + c2r * ur) * idnr;
    float ar2 = fmaxf(idnr * idnr * (c1r * c1r * x2r + 2.f * c1r * c2r * xyr + c2r * c2r * y2r), 0.f);
    float arb = idnr * (c1r * srs * sMrBr + c2r * ubr);
    float c1rb = 1.f + 2.f * arb + b2r, c2rb = 1.f - ar2;
    float idnrb = frcp(fmaxf(1.f + 2.f * arb + ar2 * b2r, MINN));
    float cr = (c1rb * ar + c2rb * brv) * idnrb;
    float cn2r = fmaxf(idnrb * idnrb * (c1rb * c1rb * ar2 + 2.f * c1rb * c2rb * arb + c2rb * c2rb * b2r), 0.f);
    float cnr = fmaxf(sqrtf(cn2r), MINN);
    float lsr = fatanh(fminf(cnr, ONE_EPS)) * frcp(cnr);
    float rg = fsig(lsr * cr);

    // ---- rh = h o r (unscaled p) ----
    float p = h * rg;
    if (l < 32) ps[o] = p;
    __syncthreads();                      // (3) p visible

    // ---- h matvec from regs x ps broadcast ----
    float mhp = 0.f;
    #pragma unroll
    for (int i = 0; i < 16; ++i) {
      float4 pv = ps4[kh * 16 + i];
      mhp += DOT4(whr[i], pv);
    }
    float mh = mhp + __shfl_xor(mhp, 32);

    // ---- window B: 7 reductions ----
    {
      float pB0 = redsum32(p * p);
      float pB1 = redsum32(mh * mh);
      float pB2 = redsum32(mh * uh);
      float pB3 = redsum32(mh * bhv);
      float pB4 = redsum32(h * mh);
      float pB5 = redsum32(h * uh);
      float pB6 = redsum32(h * bhv);
      if (l == 0) {
        part[6*4 + w] = pB0; part[7*4 + w] = pB1; part[8*4 + w] = pB2;
        part[9*4 + w] = pB3; part[10*4 + w] = pB4; part[11*4 + w] = pB5;
        part[12*4 + w] = pB6;
      }
    }
    __syncthreads();                      // (4) window B partials
    float pn2, sMh2r, sMhUhr, sMhBhr, sHMhr, sHUh, sHBh;
    { float4 q;
      q = part4[6];  pn2    = q.x + q.y + q.z + q.w;
      q = part4[7];  sMh2r  = q.x + q.y + q.z + q.w;
      q = part4[8];  sMhUhr = q.x + q.y + q.z + q.w;
      q = part4[9];  sMhBhr = q.x + q.y + q.z + q.w;
      q = part4[10]; sHMhr  = q.x + q.y + q.z + q.w;
      q = part4[11]; sHUh   = q.x + q.y + q.z + q.w;
      q = part4[12]; sHBh   = q.x + q.y + q.z + q.w; }

    // ---- rh scaling + h~ chain (srt folded) ----
    float pn  = fmaxf(sqrtf(pn2), MINN);
    float trh = ftanh(pn * axr);
    float srt = trh * frcp(pn);
    float xnp  = fmaxf(trh, MINN);
    float artp = fatanh(fminf(xnp, ONE_EPS));
    float mhn  = fmaxf(srt * sqrtf(sMh2r), MINN);
    float th   = ftanh(mhn * artp * frcp(xnp));
    float g    = th * frcp(mhn) * srt;
    float xyh  = g * sMhUhr;
    float y2h = ynh * ynh, x2h = th * th;
    float c1h = 1.f + 2.f * xyh + y2h, c2h = 1.f - x2h;
    float idnh = frcp(fmaxf(1.f + 2.f * xyh + x2h * y2h, MINN));
    float ah  = (c1h * g * mh + c2h * uh) * idnh;
    float ah2 = fmaxf(idnh * idnh * (c1h * c1h * x2h + 2.f * c1h * c2h * xyh + c2h * c2h * y2h), 0.f);
    float ahb = idnh * (c1h * g * sMhBhr + c2h * ubh);
    float hah = idnh * (c1h * g * sHMhr + c2h * sHUh);
    float c1hb = 1.f + 2.f * ahb + b2h, c2hb = 1.f - ah2;
    float idnhb = frcp(fmaxf(1.f + 2.f * ahb + ah2 * b2h, MINN));
    float ct  = (c1hb * ah + c2hb * bhv) * idnhb;
    float ct2 = fmaxf(idnhb * idnhb * (c1hb * c1hb * ah2 + 2.f * c1hb * c2hb * ahb + c2hb * c2hb * b2h), 0.f);
    float hct = idnhb * (c1hb * hah + c2hb * sHBh);

    // ---- delta = mobius_add(-h, h_tilde) ----
    float c1d = 1.f - 2.f * hct + ct2, c2d = 1.f - hn2;
    float idnd = frcp(fmaxf(1.f - 2.f * hct + hn2 * ct2, MINN));
    float dl = (c2d * ct - c1d * h) * idnd;
    float dn2 = fmaxf(idnd * idnd * (c1d * c1d * hn2 - 2.f * c1d * c2d * hct + c2d * c2d * ct2), 0.f);
    float wv = dl * zg;

    // ---- window C: 2 reductions ----
    {
      float pC0 = redsum32(wv * wv);
      float pC1 = redsum32(h * wv);
      if (l == 0) { part[13*4 + w] = pC0; part[14*4 + w] = pC1; }
    }
    __syncthreads();                      // (5) window C partials
    float wn2, hw;
    { float4 q;
      q = part4[13]; wn2 = q.x + q.y + q.z + q.w;
      q = part4[14]; hw  = q.x + q.y + q.z + q.w; }

    float dnv = fmaxf(sqrtf(dn2), MINN);
    float wnv = fmaxf(sqrtf(wn2), MINN);
    float tdd = ftanh(wnv * frcp(dnv) * fatanh(fminf(dnv, ONE_EPS)));
    float szd = tdd * frcp(wnv);
    float zd = wv * szd;
    float hzd = hw * szd;
    float t2v = tdd * tdd;
    float c1f = 1.f + 2.f * hzd + t2v, c2f = 1.f - hn2;
    float idnf = frcp(fmaxf(1.f + 2.f * hzd + hn2 * t2v, MINN));
    float nh = (c1f * h + c2f * zd) * idnf;
    hn2 = fmaxf(idnf * idnf * (c1f * c1f * hn2 + 2.f * c1f * c2f * hzd + c2f * c2f * t2v), 0.f);
    h = nh;
    au += m1 * h; av += m2 * h;
    cuz = nuz; cur = nur; cuh = nuh;
  }
  if (l < 32) {
    uarr[b * 128 + o] = au;
    varr[b * 128 + o] = av;
  }
}

// ---------------- Kernel D: dist + mobius FF + hyperbolic MLR, 1 wave/b ----
__global__ __launch_bounds__(64) void k_final(
    const float* __restrict__ uarr, const float* __restrict__ varr,
    const float* __restrict__ wfu, const float* __restrict__ wfv,
    const float* __restrict__ bff, const float* __restrict__ bffd,
    const float* __restrict__ wfc, const float* __restrict__ pmlr,
    const float* __restrict__ amlr, const int* __restrict__ cids,
    const float* __restrict__ csemb, float* __restrict__ out) {
  int b = blockIdx.x;
  int l = threadIdx.x;
  __shared__ float us[128], vs[128], cbuf[64];
  float q0 = uarr[b * 128 + l], q1 = uarr[b * 128 + 64 + l];
  float r0 = varr[b * 128 + l], r1 = varr[b * 128 + 64 + l];
  us[l] = q0; us[l + 64] = q1; vs[l] = r0; vs[l + 64] = r1;
  __syncthreads();
  float u2 = redsum(q0 * q0 + q1 * q1);
  float v2 = redsum(r0 * r0 + r1 * r1);
  float uv = redsum(q0 * r0 + q1 * r1);
  float dsq;
  { float x2 = u2, y2 = v2, xy = -uv;
    float c1 = 1.f + 2.f * xy + y2, c2 = 1.f - x2;
    float idn = 1.f / fmaxf(1.f + 2.f * xy + x2 * y2, MINN);
    float d0 = (c1 * (-q0) + c2 * r0) * idn, d1 = (c1 * (-q1) + c2 * r1) * idn;
    float dn2 = redsum(d0 * d0 + d1 * d1);
    dsq = 2.f * atanhf(clampart(sqrtf(dn2))); }
  float mxu = 0.f, mxv = 0.f;
  #pragma unroll 4
  for (int jc = 0; jc < 128; jc += 4) {
    float4 uu = *reinterpret_cast<const float4*>(&us[jc]);
    float4 vv = *reinterpret_cast<const float4*>(&vs[jc]);
    float4 wu4 = *reinterpret_cast<const float4*>(wfu + (size_t)l * 128 + jc);
    float4 wv4 = *reinterpret_cast<const float4*>(wfv + (size_t)l * 128 + jc);
    mxu += DOT4(wu4, uu); mxv += DOT4(wv4, vv);
  }
  float xnu = fmaxf(sqrtf(u2), MINN);
  float xnv = fmaxf(sqrtf(v2), MINN);
  float mun = fmaxf(sqrtf(redsum(mxu * mxu)), MINN);
  float mvn = fmaxf(sqrtf(redsum(mxv * mxv)), MINN);
  float tu = tanhf(mun / xnu * atanhf(clampart(xnu)));
  float tv = tanhf(mvn / xnv * atanhf(clampart(xnv)));
  float fu = mxu * (tu / mun), fv = mxv * (tv / mvn);
  float o1;
  { float x2 = tu * tu, y2 = tv * tv, xy = redsum(fu * fv);
    float c1 = 1.f + 2.f * xy + y2, c2 = 1.f - x2;
    float idn = 1.f / fmaxf(1.f + 2.f * xy + x2 * y2, MINN);
    o1 = (c1 * fu + c2 * fv) * idn; }
  float bffl = bff[l];
  float bf2 = redsum(bffl * bffl);
  float o2;
  { float x2 = redsum(o1 * o1), y2 = bf2, xy = redsum(o1 * bffl);
    float c1 = 1.f + 2.f * xy + y2, c2 = 1.f - x2;
    float idn = 1.f / fmaxf(1.f + 2.f * xy + x2 * y2, MINN);
    o2 = (c1 * o1 + c2 * bffl) * idn; }
  float bdl = bffd[l];
  float bdn = fmaxf(sqrtf(redsum(bdl * bdl)), MINN);
  float tsm = tanhf(dsq * atanhf(clampart(bdn)));
  float sm = bdl * (tsm / bdn);
  float o3;
  { float x2 = redsum(o2 * o2), y2 = tsm * tsm, xy = redsum(o2 * sm);
    float c1 = 1.f + 2.f * xy + y2, c2 = 1.f - x2;
    float idn = 1.f / fmaxf(1.f + 2.f * xy + x2 * y2, MINN);
    o3 = (c1 * o2 + c2 * sm) * idn; }
  int cid = cids[b];
  float ce = csemb[(size_t)cid * 64 + l];
  cbuf[l] = ce;
  __syncthreads();
  float ce2 = redsum(ce * ce);
  float mxc = 0.f;
  #pragma unroll 4
  for (int jc = 0; jc < 64; jc += 4) {
    float4 cc = *reinterpret_cast<const float4*>(&cbuf[jc]);
    float4 wc4 = *reinterpret_cast<const float4*>(wfc + (size_t)l * 64 + jc);
    mxc += DOT4(wc4, cc);
  }
  float xnc = fmaxf(sqrtf(ce2), MINN);
  float mcn = fmaxf(sqrtf(redsum(mxc * mxc)), MINN);
  float tc = tanhf(mcn / xnc * atanhf(clampart(xnc)));
  float fc = mxc * (tc / mcn);
  float o4;
  { float x2 = redsum(o3 * o3), y2 = tc * tc, xy = redsum(o3 * fc);
    float c1 = 1.f + 2.f * xy + y2, c2 = 1.f - x2;
    float idn = 1.f / fmaxf(1.f + 2.f * xy + x2 * y2, MINN);
    o4 = (c1 * o3 + c2 * fc) * idn; }
  float on = fmaxf(sqrtf(redsum(o4 * o4)), MINN);
  float lo = o4 * (atanhf(clampart(on)) / on);
  float un = fmaxf(sqrtf(redsum(lo * lo)), MINN);
  float eo = lo * (tanhf(un) / un);
  float eo2 = redsum(eo * eo);
  for (int c = 0; c < 4; ++c) {
    float pc = pmlr[c * 64 + l];
    float ac = amlr[c * 64 + l];
    float p2 = redsum(pc * pc);
    float pe = redsum(pc * eo);
    float x2 = p2, y2 = eo2, xy = -pe;
    float c1 = 1.f + 2.f * xy + y2, c2 = 1.f - x2;
    float idn = 1.f / fmaxf(1.f + 2.f * xy + x2 * y2, MINN);
    float mp = (c1 * (-pc) + c2 * eo) * idn;
    float mp2 = redsum(mp * mp);
    float lam = 2.f / (1.f - mp2);
    float na = sqrtf(redsum(ac * ac));
    float au = ac / fmaxf(na, 1e-12f);
    float pda = redsum(mp * au);
    if (l == 0) out[b * 4 + c] = 2.f * na * asinhf(pda * lam);
  }
}

extern "C" void kernel_launch(void* const* d_in, const int* in_sizes, int n_in,
                              void* d_out, int out_size, void* d_ws, size_t ws_size,
                              hipStream_t stream) {
  const float* seq   = (const float*)d_in[0];
  const float* mask1 = (const float*)d_in[1];
  const float* mask2 = (const float*)d_in[2];
  const int*   cids  = (const int*)d_in[3];
  const float* csemb = (const float*)d_in[4];
  const float* wz  = (const float*)d_in[5];
  const float* wr  = (const float*)d_in[6];
  const float* wh  = (const float*)d_in[7];
  const float* uz  = (const float*)d_in[8];
  const float* ur  = (const float*)d_in[9];
  const float* uh  = (const float*)d_in[10];
  const float* bz  = (const float*)d_in[11];
  const float* br  = (const float*)d_in[12];
  const float* bh  = (const float*)d_in[13];
  const float* wfu = (const float*)d_in[14];
  const float* wfv = (const float*)d_in[15];
  const float* bff = (const float*)d_in[16];
  const float* bffd= (const float*)d_in[17];
  const float* wfc = (const float*)d_in[18];
  const float* pmlr= (const float*)d_in[19];
  const float* amlr= (const float*)d_in[20];
  float* ws = (float*)d_ws;
  float* mx      = ws;                             // 32768*384
  float* yn      = mx + (size_t)32768 * 384;       // 32768*4
  float* ubp     = yn + (size_t)32768 * 4;         // 32768*4
  float* bhi_f   = ubp + (size_t)32768 * 4;        // 147456 f32
  float* blo_f   = bhi_f + 147456;                 // 147456 f32
  float* uarr    = blo_f + 147456;                 // 256*128
  float* varr    = uarr + 256 * 128;               // 256*128
  uint4* Bh = (uint4*)bhi_f;
  uint4* Bl = (uint4*)blo_f;

  k_convB<<<dim3(144), dim3(256), 0, stream>>>(uz, ur, uh, Bh, Bl);
  k_gemm_fused<<<dim3(256), dim3(256), 0, stream>>>(seq, Bh, Bl, bz, br, bh,
                                                    mx, yn, ubp);
  k_scan<<<dim3(256), dim3(256), 0, stream>>>(mx, yn, ubp, wz, wr, wh,
                                              bz, br, bh, mask1, mask2,
                                              uarr, varr);
  k_final<<<dim3(256), dim3(64), 0, stream>>>(uarr, varr, wfu, wfv, bff, bffd,
                                              wfc, pmlr, amlr, cids, csemb,
                                              (float*)d_out);
}

// Round 9
// 532.426 us; speedup vs baseline: 6.1862x; 1.1007x over previous
//
#include <hip/hip_runtime.h>
#include <math.h>

#define MINN 1e-15f
#define ONE_EPS 0.99999f   // 1 - 1e-5 (artanh clamp)

__device__ __forceinline__ float clampart(float x) {
  return fminf(fmaxf(x, -1.0f + 1e-5f), 1.0f - 1e-5f);
}
__device__ __forceinline__ float redsum(float x) {
  #pragma unroll
  for (int m = 32; m; m >>= 1) x += __shfl_xor(x, m);
  return x;
}
// 5-level butterfly within each 32-lane half (valid for half-duplicated values)
__device__ __forceinline__ float redsum32(float x) {
  #pragma unroll
  for (int m = 16; m; m >>= 1) x += __shfl_xor(x, m);
  return x;
}
__device__ __forceinline__ float frcp(float x) { return __builtin_amdgcn_rcpf(x); }
__device__ __forceinline__ float frsq(float x) { return __builtin_amdgcn_rsqf(x); }
__device__ __forceinline__ float fexp2(float x) { return __builtin_amdgcn_exp2f(x); }
__device__ __forceinline__ float flog2(float x) { return __builtin_amdgcn_logf(x); }
__device__ __forceinline__ float ftanh(float x) {
  float e = fexp2(x * 2.88539008f);
  return 1.0f - 2.0f * frcp(e + 1.0f);
}
__device__ __forceinline__ float fatanh(float x) {
  return 0.34657359f * flog2((1.0f + x) * frcp(1.0f - x));
}
__device__ __forceinline__ float fsig(float x) {
  return frcp(1.0f + fexp2(-1.44269504f * x));
}
#define DOT4(a, b) ((a).x*(b).x + (a).y*(b).y + (a).z*(b).z + (a).w*(b).w)

// ---- bf16 split helpers (x = hi + lo, each bf16; rel err ~2^-18) ----------
__device__ __forceinline__ unsigned bfh(float x) {
  unsigned u = __float_as_uint(x);
  return (u + 0x7FFFu + ((u >> 16) & 1u)) >> 16;    // RNE to bf16 bits
}
__device__ __forceinline__ void splitpack(float4 q0, float4 q1,
                                          uint4& hi, uint4& lo) {
  unsigned h0=bfh(q0.x),h1=bfh(q0.y),h2=bfh(q0.z),h3=bfh(q0.w);
  unsigned h4=bfh(q1.x),h5=bfh(q1.y),h6=bfh(q1.z),h7=bfh(q1.w);
  float r0=q0.x-__uint_as_float(h0<<16), r1=q0.y-__uint_as_float(h1<<16);
  float r2=q0.z-__uint_as_float(h2<<16), r3=q0.w-__uint_as_float(h3<<16);
  float r4=q1.x-__uint_as_float(h4<<16), r5=q1.y-__uint_as_float(h5<<16);
  float r6=q1.z-__uint_as_float(h6<<16), r7=q1.w-__uint_as_float(h7<<16);
  hi = make_uint4(h0|(h1<<16), h2|(h3<<16), h4|(h5<<16), h6|(h7<<16));
  lo = make_uint4(bfh(r0)|(bfh(r1)<<16), bfh(r2)|(bfh(r3)<<16),
                  bfh(r4)|(bfh(r5)<<16), bfh(r6)|(bfh(r7)<<16));
}
typedef __attribute__((ext_vector_type(8))) short bf16x8;
typedef __attribute__((ext_vector_type(4))) float f32x4;
__device__ __forceinline__ bf16x8 asfrag(uint4 u) {
  union { uint4 u; bf16x8 f; } c; c.u = u; return c.f;
}

// -------- Kernel B0: U matrices -> bf16 hi/lo fragment-linear layout -------
__global__ __launch_bounds__(256) void k_convB(const float* __restrict__ uz,
    const float* __restrict__ ur, const float* __restrict__ uh,
    uint4* __restrict__ Bh, uint4* __restrict__ Bl) {
  int tid = threadIdx.x;
  int l = tid & 63;
  int s = blockIdx.x * 4 + (tid >> 6);     // 0..575
  int kt = s / 24, nt = s % 24;
  int n = nt * 16 + (l & 15);
  const float* U = (n < 128) ? uz : (n < 256 ? ur : uh);
  int i = n & 127;
  int k = kt * 32 + (l >> 4) * 8;
  float4 q0 = *reinterpret_cast<const float4*>(U + (size_t)i * 768 + k);
  float4 q1 = *reinterpret_cast<const float4*>(U + (size_t)i * 768 + k + 4);
  uint4 hi, lo;
  splitpack(q0, q1, hi, lo);
  Bh[(size_t)(kt * 24 + nt) * 64 + l] = hi;
  Bl[(size_t)(kt * 24 + nt) * 64 + l] = lo;
}

// -------- Kernel B: fused MFMA GEMM + expmap0 stats + mobius_matvec NL -----
__global__ __launch_bounds__(256, 1) void k_gemm_fused(
    const float* __restrict__ A, const uint4* __restrict__ Bh,
    const uint4* __restrict__ Bl,
    const float* __restrict__ bzp, const float* __restrict__ brp,
    const float* __restrict__ bhp,
    float* __restrict__ mx, float* __restrict__ yn, float* __restrict__ ub) {
  int tid = threadIdx.x;
  int l = tid & 63;
  int wid = blockIdx.x * 4 + (tid >> 6);   // 0..1023
  int mt0 = wid * 2;
  int mrow = l & 15;
  int koff = (l >> 4) * 8;
  f32x4 acc[2][24];
  #pragma unroll
  for (int m = 0; m < 2; ++m)
    #pragma unroll
    for (int n = 0; n < 24; ++n) acc[m][n] = (f32x4){0.f, 0.f, 0.f, 0.f};
  float ssA0 = 0.f, ssA1 = 0.f;
  #pragma unroll 1
  for (int kt = 0; kt < 24; ++kt) {
    const float* a0p = A + (size_t)(mt0 * 16 + mrow) * 768 + kt * 32 + koff;
    const float* a1p = a0p + 16 * 768;
    float4 q0 = *reinterpret_cast<const float4*>(a0p);
    float4 q1 = *reinterpret_cast<const float4*>(a0p + 4);
    float4 q2 = *reinterpret_cast<const float4*>(a1p);
    float4 q3 = *reinterpret_cast<const float4*>(a1p + 4);
    ssA0 += DOT4(q0, q0) + DOT4(q1, q1);
    ssA1 += DOT4(q2, q2) + DOT4(q3, q3);
    uint4 ah0u, al0u, ah1u, al1u;
    splitpack(q0, q1, ah0u, al0u);
    splitpack(q2, q3, ah1u, al1u);
    bf16x8 ah0 = asfrag(ah0u), al0 = asfrag(al0u);
    bf16x8 ah1 = asfrag(ah1u), al1 = asfrag(al1u);
    const uint4* bhp4 = Bh + (size_t)(kt * 24) * 64 + l;
    const uint4* blp4 = Bl + (size_t)(kt * 24) * 64 + l;
    #pragma unroll
    for (int nt = 0; nt < 24; ++nt) {
      bf16x8 bh = asfrag(bhp4[nt * 64]);
      bf16x8 bl = asfrag(blp4[nt * 64]);
      acc[0][nt] = __builtin_amdgcn_mfma_f32_16x16x32_bf16(ah0, bh, acc[0][nt], 0, 0, 0);
      acc[0][nt] = __builtin_amdgcn_mfma_f32_16x16x32_bf16(ah0, bl, acc[0][nt], 0, 0, 0);
      acc[0][nt] = __builtin_amdgcn_mfma_f32_16x16x32_bf16(al0, bh, acc[0][nt], 0, 0, 0);
      acc[0][nt] = __builtin_amdgcn_mfma_f32_16x16x32_bf16(al0, bl, acc[0][nt], 0, 0, 0);
      acc[1][nt] = __builtin_amdgcn_mfma_f32_16x16x32_bf16(ah1, bh, acc[1][nt], 0, 0, 0);
      acc[1][nt] = __builtin_amdgcn_mfma_f32_16x16x32_bf16(ah1, bl, acc[1][nt], 0, 0, 0);
      acc[1][nt] = __builtin_amdgcn_mfma_f32_16x16x32_bf16(al1, bh, acc[1][nt], 0, 0, 0);
      acc[1][nt] = __builtin_amdgcn_mfma_f32_16x16x32_bf16(al1, bl, acc[1][nt], 0, 0, 0);
    }
  }
  // ---- seq row stats (A layout: lane covers koff-quarter of row mrow) ----
  ssA0 += __shfl_xor(ssA0, 16); ssA0 += __shfl_xor(ssA0, 32);
  ssA1 += __shfl_xor(ssA1, 16); ssA1 += __shfl_xor(ssA1, 32);
  float aA[2], rxA[2];
  {
    float un0 = sqrtf(ssA0), unc0 = fmaxf(un0, MINN);
    float a0 = tanhf(unc0) / unc0;
    float xn0 = fmaxf(a0 * un0, MINN);
    aA[0] = a0; rxA[0] = atanhf(clampart(xn0)) / xn0;
    float un1 = sqrtf(ssA1), unc1 = fmaxf(un1, MINN);
    float a1 = tanhf(unc1) / unc1;
    float xn1 = fmaxf(a1 * un1, MINN);
    aA[1] = a1; rxA[1] = atanhf(clampart(xn1)) / xn1;
  }
  // ---- remap stats to C-layout rows (row = r0 + j) ----
  int r0 = (l >> 4) * 4;
  float aC[2][4], rxC[2][4];
  #pragma unroll
  for (int m = 0; m < 2; ++m)
    #pragma unroll
    for (int j = 0; j < 4; ++j) {
      aC[m][j]  = __shfl(aA[m],  r0 + j);
      rxC[m][j] = __shfl(rxA[m], r0 + j);
    }
  // ---- bias values for ub dots: b_g[col], col = nt*16 + mrow ----
  float bv0[8], bv1[8], bv2[8];
  #pragma unroll
  for (int i = 0; i < 8; ++i) {
    bv0[i] = bzp[i * 16 + mrow];
    bv1[i] = brp[i * 16 + mrow];
    bv2[i] = bhp[i * 16 + mrow];
  }
#define GATE_EPI(m, g, bvarr)                                                 \
  {                                                                           \
    float ss0=0.f,ss1=0.f,ss2=0.f,ss3=0.f,sb0=0.f,sb1=0.f,sb2=0.f,sb3=0.f;    \
    _Pragma("unroll")                                                         \
    for (int ntg = 0; ntg < 8; ++ntg) {                                       \
      f32x4 v = acc[m][(g)*8 + ntg];                                          \
      float bb = bvarr[ntg];                                                  \
      ss0 += v[0]*v[0]; sb0 += v[0]*bb;                                       \
      ss1 += v[1]*v[1]; sb1 += v[1]*bb;                                       \
      ss2 += v[2]*v[2]; sb2 += v[2]*bb;                                       \
      ss3 += v[3]*v[3]; sb3 += v[3]*bb;                                       \
    }                                                                         \
    _Pragma("unroll")                                                         \
    for (int mk = 1; mk <= 8; mk <<= 1) {                                     \
      ss0 += __shfl_xor(ss0, mk); sb0 += __shfl_xor(sb0, mk);                 \
      ss1 += __shfl_xor(ss1, mk); sb1 += __shfl_xor(sb1, mk);                 \
      ss2 += __shfl_xor(ss2, mk); sb2 += __shfl_xor(sb2, mk);                 \
      ss3 += __shfl_xor(ss3, mk); sb3 += __shfl_xor(sb3, mk);                 \
    }                                                                         \
    float ssv[4] = {ss0, ss1, ss2, ss3};                                      \
    float sbv[4] = {sb0, sb1, sb2, sb3};                                      \
    float scale[4];                                                           \
    _Pragma("unroll")                                                         \
    for (int j = 0; j < 4; ++j) {                                             \
      float mxn = fmaxf(aC[m][j] * sqrtf(ssv[j]), MINN);                      \
      float tt = tanhf(mxn * rxC[m][j]);                                      \
      float sc = tt / mxn;                                                    \
      scale[j] = aC[m][j] * sc;                                               \
      if (mrow == 0) {                                                        \
        size_t row = (size_t)(mt0 + (m)) * 16 + r0 + j;                       \
        yn[row * 4 + (g)] = tt;                                               \
        ub[row * 4 + (g)] = scale[j] * sbv[j];                                \
      }                                                                       \
    }                                                                         \
    _Pragma("unroll")                                                         \
    for (int ntg = 0; ntg < 8; ++ntg) {                                       \
      int col = ((g)*8 + ntg) * 16 + mrow;                                    \
      f32x4 v = acc[m][(g)*8 + ntg];                                          \
      size_t rbase = (size_t)(mt0 + (m)) * 16 + r0;                           \
      _Pragma("unroll")                                                       \
      for (int j = 0; j < 4; ++j)                                             \
        mx[(rbase + j) * 384 + col] = v[j] * scale[j];                        \
    }                                                                         \
  }
  GATE_EPI(0, 0, bv0) GATE_EPI(0, 1, bv1) GATE_EPI(0, 2, bv2)
  GATE_EPI(1, 0, bv0) GATE_EPI(1, 1, bv1) GATE_EPI(1, 2, bv2)
#undef GATE_EPI
}

// ---------------- Kernel C: hyperbolic GRU scan, 4 waves per chain --------
// Weights in VGPRs (static); full input prefetch rotation; rsq-folded chain.
__global__ __launch_bounds__(256, 1) void k_scan(
    const float* __restrict__ ux, const float* __restrict__ yn,
    const float* __restrict__ ub,
    const float* __restrict__ wz, const float* __restrict__ wr, const float* __restrict__ wh,
    const float* __restrict__ bzp, const float* __restrict__ brp, const float* __restrict__ bhp,
    const float* __restrict__ mask1, const float* __restrict__ mask2,
    float* __restrict__ uarr, float* __restrict__ varr) {
  __shared__ __align__(16) float hs[128];
  __shared__ __align__(16) float ps[128];
  __shared__ __align__(16) float part[72];
  float4* hs4   = (float4*)hs;
  float4* ps4   = (float4*)ps;
  float4* part4 = (float4*)part;

  int b = blockIdx.x;
  int tid = threadIdx.x;
  int w = tid >> 6;          // wave 0..3
  int l = tid & 63;          // lane
  int l31 = l & 31;
  int kh = l >> 5;           // k-half 0/1
  int o = w * 32 + l31;      // owned output/elem index

  const float4* wzg = (const float4*)wz;
  const float4* wrg = (const float4*)wr;
  const float4* whg = (const float4*)wh;
  float4 wzr[16], wrr[16], whr[16];
  #pragma unroll
  for (int i = 0; i < 16; ++i) {
    wzr[i] = wzg[o * 32 + kh * 16 + i];
    wrr[i] = wrg[o * 32 + kh * 16 + i];
    whr[i] = whg[o * 32 + kh * 16 + i];
  }

  float bzv = bzp[o], brv = brp[o], bhv = bhp[o];
  {
    float v0 = redsum32(bzv * bzv);
    float v1 = redsum32(brv * brv);
    float v2 = redsum32(bhv * bhv);
    if (l == 0) { part[15*4 + w] = v0; part[16*4 + w] = v1; part[17*4 + w] = v2; }
  }
  __syncthreads();
  float b2z, b2r, b2h;
  { float4 q;
    q = part4[15]; b2z = q.x + q.y + q.z + q.w;
    q = part4[16]; b2r = q.x + q.y + q.z + q.w;
    q = part4[17]; b2h = q.x + q.y + q.z + q.w; }

  float h = 0.f, hn2 = 0.f, au = 0.f, av = 0.f;
  const float*  uxb  = ux + (size_t)b * 128 * 384;
  const float4* ynb4 = (const float4*)yn + (size_t)b * 128;
  const float4* ubb4 = (const float4*)ub + (size_t)b * 128;
  const float*  m1p  = mask1 + b * 128;
  const float*  m2p  = mask2 + b * 128;

  // prefetch t=0 inputs
  float cuz = uxb[o], cur = uxb[128 + o], cuh = uxb[256 + o];
  float4 cyn = ynb4[0];
  float4 cub = ubb4[0];
  float cm1 = m1p[0], cm2 = m2p[0];

  #pragma unroll 1
  for (int t = 0; t < 128; ++t) {
    if (l < 32) hs[o] = h;
    __syncthreads();                      // (1) h visible
    // issue ALL t+1 prefetches (hidden under this step's compute)
    int tn = (t + 1 < 128) ? t + 1 : 127;
    const float* uxn = uxb + tn * 384;
    float nuz = uxn[o], nur = uxn[128 + o], nuh = uxn[256 + o];
    float4 nyn = ynb4[tn];
    float4 nub = ubb4[tn];
    float nm1 = m1p[tn], nm2 = m2p[tn];
    float uz = cuz, ur = cur, uh = cuh;
    float ynz = cyn.x, ynr = cyn.y, ynh = cyn.z;
    float ubz = cub.x, ubr = cub.y, ubh = cub.z;
    float m1 = cm1, m2 = cm2;

    // wave-uniform pre-chain (independent of this step's reductions)
    float rqh  = frsq(fmaxf(hn2, 1e-30f));      // 1/||h||
    float xnh  = fmaxf(hn2, 1e-30f) * rqh;      // ||h|| (>= 1e-15)
    float arth = fatanh(fminf(xnh, ONE_EPS));
    float axr  = arth * rqh;

    // ---- z/r matvec: register weights x LDS-broadcast h ----
    float mzp = 0.f, mrp = 0.f;
    #pragma unroll
    for (int i = 0; i < 16; ++i) {
      float4 hv = hs4[kh * 16 + i];
      mzp += DOT4(wzr[i], hv);
      mrp += DOT4(wrr[i], hv);
    }
    float mz = mzp + __shfl_xor(mzp, 32);
    float mr = mrp + __shfl_xor(mrp, 32);

    // ---- window A: 6 reductions ----
    {
      float pA0 = redsum32(mz * mz);
      float pA1 = redsum32(mr * mr);
      float pA2 = redsum32(mz * uz);
      float pA3 = redsum32(mr * ur);
      float pA4 = redsum32(mz * bzv);
      float pA5 = redsum32(mr * brv);
      if (l == 0) {
        part[0*4 + w] = pA0; part[1*4 + w] = pA1; part[2*4 + w] = pA2;
        part[3*4 + w] = pA3; part[4*4 + w] = pA4; part[5*4 + w] = pA5;
      }
    }
    __syncthreads();                      // (2) window A partials
    float sMz2, sMr2, sMzUz, sMrUr, sMzBz, sMrBr;
    { float4 q;
      q = part4[0]; sMz2  = q.x + q.y + q.z + q.w;
      q = part4[1]; sMr2  = q.x + q.y + q.z + q.w;
      q = part4[2]; sMzUz = q.x + q.y + q.z + q.w;
      q = part4[3]; sMrUr = q.x + q.y + q.z + q.w;
      q = part4[4]; sMzBz = q.x + q.y + q.z + q.w;
      q = part4[5]; sMrBr = q.x + q.y + q.z + q.w; }

    // ---- z chain (rsq-folded) ----
    float rqz = frsq(fmaxf(sMz2, 1e-30f));
    float mzn = fmaxf(sMz2, 1e-30f) * rqz;
    float tz  = ftanh(mzn * axr);
    float szs = tz * rqz;
    float xyz = szs * sMzUz;
    float y2z = ynz * ynz, x2z = tz * tz;
    float c1z = 1.f + 2.f * xyz + y2z, c2z = 1.f - x2z;
    float idnz = frcp(fmaxf(1.f + 2.f * xyz + x2z * y2z, MINN));
    float az  = (c1z * szs * mz + c2z * uz) * idnz;
    float az2 = fmaxf(idnz * idnz * (c1z * c1z * x2z + 2.f * c1z * c2z * xyz + c2z * c2z * y2z), 0.f);
    float azb = idnz * (c1z * szs * sMzBz + c2z * ubz);
    float c1zb = 1.f + 2.f * azb + b2z, c2zb = 1.f - az2;
    float idnzb = frcp(fmaxf(1.f + 2.f * azb + az2 * b2z, MINN));
    float cz = (c1zb * az + c2zb * bzv) * idnzb;
    float cn2z = fmaxf(idnzb * idnzb * (c1zb * c1zb * az2 + 2.f * c1zb * c2zb * azb + c2zb * c2zb * b2z), 0.f);
    float rqcz = frsq(fmaxf(cn2z, 1e-30f));
    float cnz = fmaxf(cn2z, 1e-30f) * rqcz;
    float lsz = fatanh(fminf(cnz, ONE_EPS)) * rqcz;
    float zg = fsig(lsz * cz);

    // ---- r chain ----
    float rqr = frsq(fmaxf(sMr2, 1e-30f));
    float mrn = fmaxf(sMr2, 1e-30f) * rqr;
    float trr = ftanh(mrn * axr);
    float srs = trr * rqr;
    float xyr = srs * sMrUr;
    float y2r = ynr * ynr, x2r = trr * trr;
    float c1r = 1.f + 2.f * xyr + y2r, c2r = 1.f - x2r;
    float idnr = frcp(fmaxf(1.f + 2.f * xyr + x2r * y2r, MINN));
    float ar  = (c1r * srs * mr + c2r * ur) * idnr;
    float ar2 = fmaxf(idnr * idnr * (c1r * c1r * x2r + 2.f * c1r * c2r * xyr + c2r * c2r * y2r), 0.f);
    float arb = idnr * (c1r * srs * sMrBr + c2r * ubr);
    float c1rb = 1.f + 2.f * arb + b2r, c2rb = 1.f - ar2;
    float idnrb = frcp(fmaxf(1.f + 2.f * arb + ar2 * b2r, MINN));
    float cr = (c1rb * ar + c2rb * brv) * idnrb;
    float cn2r = fmaxf(idnrb * idnrb * (c1rb * c1rb * ar2 + 2.f * c1rb * c2rb * arb + c2rb * c2rb * b2r), 0.f);
    float rqcr = frsq(fmaxf(cn2r, 1e-30f));
    float cnr = fmaxf(cn2r, 1e-30f) * rqcr;
    float lsr = fatanh(fminf(cnr, ONE_EPS)) * rqcr;
    float rg = fsig(lsr * cr);

    // ---- rh = h o r (unscaled p) ----
    float p = h * rg;
    if (l < 32) ps[o] = p;
    __syncthreads();                      // (3) p visible

    // ---- h matvec from regs x ps broadcast ----
    float mhp = 0.f;
    #pragma unroll
    for (int i = 0; i < 16; ++i) {
      float4 pv = ps4[kh * 16 + i];
      mhp += DOT4(whr[i], pv);
    }
    float mh = mhp + __shfl_xor(mhp, 32);

    // ---- window B: 7 reductions ----
    {
      float pB0 = redsum32(p * p);
      float pB1 = redsum32(mh * mh);
      float pB2 = redsum32(mh * uh);
      float pB3 = redsum32(mh * bhv);
      float pB4 = redsum32(h * mh);
      float pB5 = redsum32(h * uh);
      float pB6 = redsum32(h * bhv);
      if (l == 0) {
        part[6*4 + w] = pB0; part[7*4 + w] = pB1; part[8*4 + w] = pB2;
        part[9*4 + w] = pB3; part[10*4 + w] = pB4; part[11*4 + w] = pB5;
        part[12*4 + w] = pB6;
      }
    }
    __syncthreads();                      // (4) window B partials
    float pn2, sMh2r, sMhUhr, sMhBhr, sHMhr, sHUh, sHBh;
    { float4 q;
      q = part4[6];  pn2    = q.x + q.y + q.z + q.w;
      q = part4[7];  sMh2r  = q.x + q.y + q.z + q.w;
      q = part4[8];  sMhUhr = q.x + q.y + q.z + q.w;
      q = part4[9];  sMhBhr = q.x + q.y + q.z + q.w;
      q = part4[10]; sHMhr  = q.x + q.y + q.z + q.w;
      q = part4[11]; sHUh   = q.x + q.y + q.z + q.w;
      q = part4[12]; sHBh   = q.x + q.y + q.z + q.w; }

    // ---- rh scaling + h~ chain (rsq-folded, srt folded) ----
    float rqp = frsq(fmaxf(pn2, 1e-30f));
    float pn  = fmaxf(pn2, 1e-30f) * rqp;
    float trh = ftanh(pn * axr);
    float srt = trh * rqp;
    float xnp  = fmaxf(trh, MINN);
    float artp = fatanh(fminf(xnp, ONE_EPS));
    float sqh  = fmaxf(sMh2r, 1e-30f) * frsq(fmaxf(sMh2r, 1e-30f));  // sqrt
    float mhn  = fmaxf(srt * sqh, MINN);
    float th   = ftanh(mhn * artp * frcp(xnp));
    float g    = th * frcp(mhn) * srt;
    float xyh  = g * sMhUhr;
    float y2h = ynh * ynh, x2h = th * th;
    float c1h = 1.f + 2.f * xyh + y2h, c2h = 1.f - x2h;
    float idnh = frcp(fmaxf(1.f + 2.f * xyh + x2h * y2h, MINN));
    float ah  = (c1h * g * mh + c2h * uh) * idnh;
    float ah2 = fmaxf(idnh * idnh * (c1h * c1h * x2h + 2.f * c1h * c2h * xyh + c2h * c2h * y2h), 0.f);
    float ahb = idnh * (c1h * g * sMhBhr + c2h * ubh);
    float hah = idnh * (c1h * g * sHMhr + c2h * sHUh);
    float c1hb = 1.f + 2.f * ahb + b2h, c2hb = 1.f - ah2;
    float idnhb = frcp(fmaxf(1.f + 2.f * ahb + ah2 * b2h, MINN));
    float ct  = (c1hb * ah + c2hb * bhv) * idnhb;
    float ct2 = fmaxf(idnhb * idnhb * (c1hb * c1hb * ah2 + 2.f * c1hb * c2hb * ahb + c2hb * c2hb * b2h), 0.f);
    float hct = idnhb * (c1hb * hah + c2hb * sHBh);

    // ---- delta = mobius_add(-h, h_tilde) ----
    float c1d = 1.f - 2.f * hct + ct2, c2d = 1.f - hn2;
    float idnd = frcp(fmaxf(1.f - 2.f * hct + hn2 * ct2, MINN));
    float dl = (c2d * ct - c1d * h) * idnd;
    float dn2 = fmaxf(idnd * idnd * (c1d * c1d * hn2 - 2.f * c1d * c2d * hct + c2d * c2d * ct2), 0.f);
    float wv = dl * zg;

    // ---- window C: 2 reductions ----
    {
      float pC0 = redsum32(wv * wv);
      float pC1 = redsum32(h * wv);
      if (l == 0) { part[13*4 + w] = pC0; part[14*4 + w] = pC1; }
    }
    __syncthreads();                      // (5) window C partials
    float wn2, hw;
    { float4 q;
      q = part4[13]; wn2 = q.x + q.y + q.z + q.w;
      q = part4[14]; hw  = q.x + q.y + q.z + q.w; }

    float rqd = frsq(fmaxf(dn2, 1e-30f));
    float dnv = fmaxf(dn2, 1e-30f) * rqd;
    float rqw = frsq(fmaxf(wn2, 1e-30f));
    float wnv = fmaxf(wn2, 1e-30f) * rqw;
    float tdd = ftanh(wnv * rqd * fatanh(fminf(dnv, ONE_EPS)));
    float szd = tdd * rqw;
    float zd = wv * szd;
    float hzd = hw * szd;
    float t2v = tdd * tdd;
    float c1f = 1.f + 2.f * hzd + t2v, c2f = 1.f - hn2;
    float idnf = frcp(fmaxf(1.f + 2.f * hzd + hn2 * t2v, MINN));
    float nh = (c1f * h + c2f * zd) * idnf;
    hn2 = fmaxf(idnf * idnf * (c1f * c1f * hn2 + 2.f * c1f * c2f * hzd + c2f * c2f * t2v), 0.f);
    h = nh;
    au += m1 * h; av += m2 * h;
    cuz = nuz; cur = nur; cuh = nuh;
    cyn = nyn; cub = nub; cm1 = nm1; cm2 = nm2;
  }
  if (l < 32) {
    uarr[b * 128 + o] = au;
    varr[b * 128 + o] = av;
  }
}

// ---------------- Kernel D: dist + mobius FF + hyperbolic MLR, 1 wave/b ----
__global__ __launch_bounds__(64) void k_final(
    const float* __restrict__ uarr, const float* __restrict__ varr,
    const float* __restrict__ wfu, const float* __restrict__ wfv,
    const float* __restrict__ bff, const float* __restrict__ bffd,
    const float* __restrict__ wfc, const float* __restrict__ pmlr,
    const float* __restrict__ amlr, const int* __restrict__ cids,
    const float* __restrict__ csemb, float* __restrict__ out) {
  int b = blockIdx.x;
  int l = threadIdx.x;
  __shared__ float us[128], vs[128], cbuf[64];
  float q0 = uarr[b * 128 + l], q1 = uarr[b * 128 + 64 + l];
  float r0 = varr[b * 128 + l], r1 = varr[b * 128 + 64 + l];
  us[l] = q0; us[l + 64] = q1; vs[l] = r0; vs[l + 64] = r1;
  __syncthreads();
  float u2 = redsum(q0 * q0 + q1 * q1);
  float v2 = redsum(r0 * r0 + r1 * r1);
  float uv = redsum(q0 * r0 + q1 * r1);
  float dsq;
  { float x2 = u2, y2 = v2, xy = -uv;
    float c1 = 1.f + 2.f * xy + y2, c2 = 1.f - x2;
    float idn = 1.f / fmaxf(1.f + 2.f * xy + x2 * y2, MINN);
    float d0 = (c1 * (-q0) + c2 * r0) * idn, d1 = (c1 * (-q1) + c2 * r1) * idn;
    float dn2 = redsum(d0 * d0 + d1 * d1);
    dsq = 2.f * atanhf(clampart(sqrtf(dn2))); }
  float mxu = 0.f, mxv = 0.f;
  #pragma unroll 4
  for (int jc = 0; jc < 128; jc += 4) {
    float4 uu = *reinterpret_cast<const float4*>(&us[jc]);
    float4 vv = *reinterpret_cast<const float4*>(&vs[jc]);
    float4 wu4 = *reinterpret_cast<const float4*>(wfu + (size_t)l * 128 + jc);
    float4 wv4 = *reinterpret_cast<const float4*>(wfv + (size_t)l * 128 + jc);
    mxu += DOT4(wu4, uu); mxv += DOT4(wv4, vv);
  }
  float xnu = fmaxf(sqrtf(u2), MINN);
  float xnv = fmaxf(sqrtf(v2), MINN);
  float mun = fmaxf(sqrtf(redsum(mxu * mxu)), MINN);
  float mvn = fmaxf(sqrtf(redsum(mxv * mxv)), MINN);
  float tu = tanhf(mun / xnu * atanhf(clampart(xnu)));
  float tv = tanhf(mvn / xnv * atanhf(clampart(xnv)));
  float fu = mxu * (tu / mun), fv = mxv * (tv / mvn);
  float o1;
  { float x2 = tu * tu, y2 = tv * tv, xy = redsum(fu * fv);
    float c1 = 1.f + 2.f * xy + y2, c2 = 1.f - x2;
    float idn = 1.f / fmaxf(1.f + 2.f * xy + x2 * y2, MINN);
    o1 = (c1 * fu + c2 * fv) * idn; }
  float bffl = bff[l];
  float bf2 = redsum(bffl * bffl);
  float o2;
  { float x2 = redsum(o1 * o1), y2 = bf2, xy = redsum(o1 * bffl);
    float c1 = 1.f + 2.f * xy + y2, c2 = 1.f - x2;
    float idn = 1.f / fmaxf(1.f + 2.f * xy + x2 * y2, MINN);
    o2 = (c1 * o1 + c2 * bffl) * idn; }
  float bdl = bffd[l];
  float bdn = fmaxf(sqrtf(redsum(bdl * bdl)), MINN);
  float tsm = tanhf(dsq * atanhf(clampart(bdn)));
  float sm = bdl * (tsm / bdn);
  float o3;
  { float x2 = redsum(o2 * o2), y2 = tsm * tsm, xy = redsum(o2 * sm);
    float c1 = 1.f + 2.f * xy + y2, c2 = 1.f - x2;
    float idn = 1.f / fmaxf(1.f + 2.f * xy + x2 * y2, MINN);
    o3 = (c1 * o2 + c2 * sm) * idn; }
  int cid = cids[b];
  float ce = csemb[(size_t)cid * 64 + l];
  cbuf[l] = ce;
  __syncthreads();
  float ce2 = redsum(ce * ce);
  float mxc = 0.f;
  #pragma unroll 4
  for (int jc = 0; jc < 64; jc += 4) {
    float4 cc = *reinterpret_cast<const float4*>(&cbuf[jc]);
    float4 wc4 = *reinterpret_cast<const float4*>(wfc + (size_t)l * 64 + jc);
    mxc += DOT4(wc4, cc);
  }
  float xnc = fmaxf(sqrtf(ce2), MINN);
  float mcn = fmaxf(sqrtf(redsum(mxc * mxc)), MINN);
  float tc = tanhf(mcn / xnc * atanhf(clampart(xnc)));
  float fc = mxc * (tc / mcn);
  float o4;
  { float x2 = redsum(o3 * o3), y2 = tc * tc, xy = redsum(o3 * fc);
    float c1 = 1.f + 2.f * xy + y2, c2 = 1.f - x2;
    float idn = 1.f / fmaxf(1.f + 2.f * xy + x2 * y2, MINN);
    o4 = (c1 * o3 + c2 * fc) * idn; }
  float on = fmaxf(sqrtf(redsum(o4 * o4)), MINN);
  float lo = o4 * (atanhf(clampart(on)) / on);
  float un = fmaxf(sqrtf(redsum(lo * lo)), MINN);
  float eo = lo * (tanhf(un) / un);
  float eo2 = redsum(eo * eo);
  for (int c = 0; c < 4; ++c) {
    float pc = pmlr[c * 64 + l];
    float ac = amlr[c * 64 + l];
    float p2 = redsum(pc * pc);
    float pe = redsum(pc * eo);
    float x2 = p2, y2 = eo2, xy = -pe;
    float c1 = 1.f + 2.f * xy + y2, c2 = 1.f - x2;
    float idn = 1.f / fmaxf(1.f + 2.f * xy + x2 * y2, MINN);
    float mp = (c1 * (-pc) + c2 * eo) * idn;
    float mp2 = redsum(mp * mp);
    float lam = 2.f / (1.f - mp2);
    float na = sqrtf(redsum(ac * ac));
    float au = ac / fmaxf(na, 1e-12f);
    float pda = redsum(mp * au);
    if (l == 0) out[b * 4 + c] = 2.f * na * asinhf(pda * lam);
  }
}

extern "C" void kernel_launch(void* const* d_in, const int* in_sizes, int n_in,
                              void* d_out, int out_size, void* d_ws, size_t ws_size,
                              hipStream_t stream) {
  const float* seq   = (const float*)d_in[0];
  const float* mask1 = (const float*)d_in[1];
  const float* mask2 = (const float*)d_in[2];
  const int*   cids  = (const int*)d_in[3];
  const float* csemb = (const float*)d_in[4];
  const float* wz  = (const float*)d_in[5];
  const float* wr  = (const float*)d_in[6];
  const float* wh  = (const float*)d_in[7];
  const float* uz  = (const float*)d_in[8];
  const float* ur  = (const float*)d_in[9];
  const float* uh  = (const float*)d_in[10];
  const float* bz  = (const float*)d_in[11];
  const float* br  = (const float*)d_in[12];
  const float* bh  = (const float*)d_in[13];
  const float* wfu = (const float*)d_in[14];
  const float* wfv = (const float*)d_in[15];
  const float* bff = (const float*)d_in[16];
  const float* bffd= (const float*)d_in[17];
  const float* wfc = (const float*)d_in[18];
  const float* pmlr= (const float*)d_in[19];
  const float* amlr= (const float*)d_in[20];
  float* ws = (float*)d_ws;
  float* mx      = ws;                             // 32768*384
  float* yn      = mx + (size_t)32768 * 384;       // 32768*4
  float* ubp     = yn + (size_t)32768 * 4;         // 32768*4
  float* bhi_f   = ubp + (size_t)32768 * 4;        // 147456 f32
  float* blo_f   = bhi_f + 147456;                 // 147456 f32
  float* uarr    = blo_f + 147456;                 // 256*128
  float* varr    = uarr + 256 * 128;               // 256*128
  uint4* Bh = (uint4*)bhi_f;
  uint4* Bl = (uint4*)blo_f;

  k_convB<<<dim3(144), dim3(256), 0, stream>>>(uz, ur, uh, Bh, Bl);
  k_gemm_fused<<<dim3(256), dim3(256), 0, stream>>>(seq, Bh, Bl, bz, br, bh,
                                                    mx, yn, ubp);
  k_scan<<<dim3(256), dim3(256), 0, stream>>>(mx, yn, ubp, wz, wr, wh,
                                              bz, br, bh, mask1, mask2,
                                              uarr, varr);
  k_final<<<dim3(256), dim3(64), 0, stream>>>(uarr, varr, wfu, wfv, bff, bffd,
                                              wfc, pmlr, amlr, cids, csemb,
                                              (float*)d_out);
}

// Round 10
// 516.735 us; speedup vs baseline: 6.3740x; 1.0304x over previous
//
#include <hip/hip_runtime.h>
#include <math.h>

#define MINN 1e-15f
#define ONE_EPS 0.99999f   // 1 - 1e-5 (artanh clamp)

__device__ __forceinline__ float clampart(float x) {
  return fminf(fmaxf(x, -1.0f + 1e-5f), 1.0f - 1e-5f);
}
__device__ __forceinline__ float redsum(float x) {
  #pragma unroll
  for (int m = 32; m; m >>= 1) x += __shfl_xor(x, m);
  return x;
}
// 5-level butterfly within each 32-lane half
__device__ __forceinline__ float redsum32(float x) {
  #pragma unroll
  for (int m = 16; m; m >>= 1) x += __shfl_xor(x, m);
  return x;
}
__device__ __forceinline__ float frcp(float x) { return __builtin_amdgcn_rcpf(x); }
__device__ __forceinline__ float frsq(float x) { return __builtin_amdgcn_rsqf(x); }
__device__ __forceinline__ float fexp2(float x) { return __builtin_amdgcn_exp2f(x); }
__device__ __forceinline__ float flog2(float x) { return __builtin_amdgcn_logf(x); }
__device__ __forceinline__ float ftanh(float x) {
  float e = fexp2(x * 2.88539008f);
  return 1.0f - 2.0f * frcp(e + 1.0f);
}
__device__ __forceinline__ float fatanh(float x) {
  return 0.34657359f * flog2((1.0f + x) * frcp(1.0f - x));
}
__device__ __forceinline__ float fsig(float x) {
  return frcp(1.0f + fexp2(-1.44269504f * x));
}
#define DOT4(a, b) ((a).x*(b).x + (a).y*(b).y + (a).z*(b).z + (a).w*(b).w)

// ---- bf16 split helpers (x = hi + lo, each bf16; rel err ~2^-18) ----------
__device__ __forceinline__ unsigned bfh(float x) {
  unsigned u = __float_as_uint(x);
  return (u + 0x7FFFu + ((u >> 16) & 1u)) >> 16;    // RNE to bf16 bits
}
__device__ __forceinline__ void splitpack(float4 q0, float4 q1,
                                          uint4& hi, uint4& lo) {
  unsigned h0=bfh(q0.x),h1=bfh(q0.y),h2=bfh(q0.z),h3=bfh(q0.w);
  unsigned h4=bfh(q1.x),h5=bfh(q1.y),h6=bfh(q1.z),h7=bfh(q1.w);
  float r0=q0.x-__uint_as_float(h0<<16), r1=q0.y-__uint_as_float(h1<<16);
  float r2=q0.z-__uint_as_float(h2<<16), r3=q0.w-__uint_as_float(h3<<16);
  float r4=q1.x-__uint_as_float(h4<<16), r5=q1.y-__uint_as_float(h5<<16);
  float r6=q1.z-__uint_as_float(h6<<16), r7=q1.w-__uint_as_float(h7<<16);
  hi = make_uint4(h0|(h1<<16), h2|(h3<<16), h4|(h5<<16), h6|(h7<<16));
  lo = make_uint4(bfh(r0)|(bfh(r1)<<16), bfh(r2)|(bfh(r3)<<16),
                  bfh(r4)|(bfh(r5)<<16), bfh(r6)|(bfh(r7)<<16));
}
typedef __attribute__((ext_vector_type(8))) short bf16x8;
typedef __attribute__((ext_vector_type(4))) float f32x4;
__device__ __forceinline__ bf16x8 asfrag(uint4 u) {
  union { uint4 u; bf16x8 f; } c; c.u = u; return c.f;
}

// -------- Kernel B0: U matrices -> bf16 hi/lo fragment-linear layout -------
__global__ __launch_bounds__(256) void k_convB(const float* __restrict__ uz,
    const float* __restrict__ ur, const float* __restrict__ uh,
    uint4* __restrict__ Bh, uint4* __restrict__ Bl) {
  int tid = threadIdx.x;
  int l = tid & 63;
  int s = blockIdx.x * 4 + (tid >> 6);     // 0..575
  int kt = s / 24, nt = s % 24;
  int n = nt * 16 + (l & 15);
  const float* U = (n < 128) ? uz : (n < 256 ? ur : uh);
  int i = n & 127;
  int k = kt * 32 + (l >> 4) * 8;
  float4 q0 = *reinterpret_cast<const float4*>(U + (size_t)i * 768 + k);
  float4 q1 = *reinterpret_cast<const float4*>(U + (size_t)i * 768 + k + 4);
  uint4 hi, lo;
  splitpack(q0, q1, hi, lo);
  Bh[(size_t)(kt * 24 + nt) * 64 + l] = hi;
  Bl[(size_t)(kt * 24 + nt) * 64 + l] = lo;
}

// -------- Kernel B: fused MFMA GEMM + expmap0 stats + mobius_matvec NL -----
__global__ __launch_bounds__(256, 1) void k_gemm_fused(
    const float* __restrict__ A, const uint4* __restrict__ Bh,
    const uint4* __restrict__ Bl,
    const float* __restrict__ bzp, const float* __restrict__ brp,
    const float* __restrict__ bhp,
    float* __restrict__ mx, float* __restrict__ yn, float* __restrict__ ub) {
  int tid = threadIdx.x;
  int l = tid & 63;
  int wid = blockIdx.x * 4 + (tid >> 6);   // 0..1023
  int mt0 = wid * 2;
  int mrow = l & 15;
  int koff = (l >> 4) * 8;
  f32x4 acc[2][24];
  #pragma unroll
  for (int m = 0; m < 2; ++m)
    #pragma unroll
    for (int n = 0; n < 24; ++n) acc[m][n] = (f32x4){0.f, 0.f, 0.f, 0.f};
  float ssA0 = 0.f, ssA1 = 0.f;
  #pragma unroll 1
  for (int kt = 0; kt < 24; ++kt) {
    const float* a0p = A + (size_t)(mt0 * 16 + mrow) * 768 + kt * 32 + koff;
    const float* a1p = a0p + 16 * 768;
    float4 q0 = *reinterpret_cast<const float4*>(a0p);
    float4 q1 = *reinterpret_cast<const float4*>(a0p + 4);
    float4 q2 = *reinterpret_cast<const float4*>(a1p);
    float4 q3 = *reinterpret_cast<const float4*>(a1p + 4);
    ssA0 += DOT4(q0, q0) + DOT4(q1, q1);
    ssA1 += DOT4(q2, q2) + DOT4(q3, q3);
    uint4 ah0u, al0u, ah1u, al1u;
    splitpack(q0, q1, ah0u, al0u);
    splitpack(q2, q3, ah1u, al1u);
    bf16x8 ah0 = asfrag(ah0u), al0 = asfrag(al0u);
    bf16x8 ah1 = asfrag(ah1u), al1 = asfrag(al1u);
    const uint4* bhp4 = Bh + (size_t)(kt * 24) * 64 + l;
    const uint4* blp4 = Bl + (size_t)(kt * 24) * 64 + l;
    #pragma unroll
    for (int nt = 0; nt < 24; ++nt) {
      bf16x8 bh = asfrag(bhp4[nt * 64]);
      bf16x8 bl = asfrag(blp4[nt * 64]);
      acc[0][nt] = __builtin_amdgcn_mfma_f32_16x16x32_bf16(ah0, bh, acc[0][nt], 0, 0, 0);
      acc[0][nt] = __builtin_amdgcn_mfma_f32_16x16x32_bf16(ah0, bl, acc[0][nt], 0, 0, 0);
      acc[0][nt] = __builtin_amdgcn_mfma_f32_16x16x32_bf16(al0, bh, acc[0][nt], 0, 0, 0);
      acc[0][nt] = __builtin_amdgcn_mfma_f32_16x16x32_bf16(al0, bl, acc[0][nt], 0, 0, 0);
      acc[1][nt] = __builtin_amdgcn_mfma_f32_16x16x32_bf16(ah1, bh, acc[1][nt], 0, 0, 0);
      acc[1][nt] = __builtin_amdgcn_mfma_f32_16x16x32_bf16(ah1, bl, acc[1][nt], 0, 0, 0);
      acc[1][nt] = __builtin_amdgcn_mfma_f32_16x16x32_bf16(al1, bh, acc[1][nt], 0, 0, 0);
      acc[1][nt] = __builtin_amdgcn_mfma_f32_16x16x32_bf16(al1, bl, acc[1][nt], 0, 0, 0);
    }
  }
  // ---- seq row stats (A layout: lane covers koff-quarter of row mrow) ----
  ssA0 += __shfl_xor(ssA0, 16); ssA0 += __shfl_xor(ssA0, 32);
  ssA1 += __shfl_xor(ssA1, 16); ssA1 += __shfl_xor(ssA1, 32);
  float aA[2], rxA[2];
  {
    float un0 = sqrtf(ssA0), unc0 = fmaxf(un0, MINN);
    float a0 = tanhf(unc0) / unc0;
    float xn0 = fmaxf(a0 * un0, MINN);
    aA[0] = a0; rxA[0] = atanhf(clampart(xn0)) / xn0;
    float un1 = sqrtf(ssA1), unc1 = fmaxf(un1, MINN);
    float a1 = tanhf(unc1) / unc1;
    float xn1 = fmaxf(a1 * un1, MINN);
    aA[1] = a1; rxA[1] = atanhf(clampart(xn1)) / xn1;
  }
  // ---- remap stats to C-layout rows (row = r0 + j) ----
  int r0 = (l >> 4) * 4;
  float aC[2][4], rxC[2][4];
  #pragma unroll
  for (int m = 0; m < 2; ++m)
    #pragma unroll
    for (int j = 0; j < 4; ++j) {
      aC[m][j]  = __shfl(aA[m],  r0 + j);
      rxC[m][j] = __shfl(rxA[m], r0 + j);
    }
  // ---- bias values for ub dots: b_g[col], col = nt*16 + mrow ----
  float bv0[8], bv1[8], bv2[8];
  #pragma unroll
  for (int i = 0; i < 8; ++i) {
    bv0[i] = bzp[i * 16 + mrow];
    bv1[i] = brp[i * 16 + mrow];
    bv2[i] = bhp[i * 16 + mrow];
  }
#define GATE_EPI(m, g, bvarr)                                                 \
  {                                                                           \
    float ss0=0.f,ss1=0.f,ss2=0.f,ss3=0.f,sb0=0.f,sb1=0.f,sb2=0.f,sb3=0.f;    \
    _Pragma("unroll")                                                         \
    for (int ntg = 0; ntg < 8; ++ntg) {                                       \
      f32x4 v = acc[m][(g)*8 + ntg];                                          \
      float bb = bvarr[ntg];                                                  \
      ss0 += v[0]*v[0]; sb0 += v[0]*bb;                                       \
      ss1 += v[1]*v[1]; sb1 += v[1]*bb;                                       \
      ss2 += v[2]*v[2]; sb2 += v[2]*bb;                                       \
      ss3 += v[3]*v[3]; sb3 += v[3]*bb;                                       \
    }                                                                         \
    _Pragma("unroll")                                                         \
    for (int mk = 1; mk <= 8; mk <<= 1) {                                     \
      ss0 += __shfl_xor(ss0, mk); sb0 += __shfl_xor(sb0, mk);                 \
      ss1 += __shfl_xor(ss1, mk); sb1 += __shfl_xor(sb1, mk);                 \
      ss2 += __shfl_xor(ss2, mk); sb2 += __shfl_xor(sb2, mk);                 \
      ss3 += __shfl_xor(ss3, mk); sb3 += __shfl_xor(sb3, mk);                 \
    }                                                                         \
    float ssv[4] = {ss0, ss1, ss2, ss3};                                      \
    float sbv[4] = {sb0, sb1, sb2, sb3};                                      \
    float scale[4];                                                           \
    _Pragma("unroll")                                                         \
    for (int j = 0; j < 4; ++j) {                                             \
      float mxn = fmaxf(aC[m][j] * sqrtf(ssv[j]), MINN);                      \
      float tt = tanhf(mxn * rxC[m][j]);                                      \
      float sc = tt / mxn;                                                    \
      scale[j] = aC[m][j] * sc;                                               \
      if (mrow == 0) {                                                        \
        size_t row = (size_t)(mt0 + (m)) * 16 + r0 + j;                       \
        yn[row * 4 + (g)] = tt;                                               \
        ub[row * 4 + (g)] = scale[j] * sbv[j];                                \
      }                                                                       \
    }                                                                         \
    _Pragma("unroll")                                                         \
    for (int ntg = 0; ntg < 8; ++ntg) {                                       \
      int col = ((g)*8 + ntg) * 16 + mrow;                                    \
      f32x4 v = acc[m][(g)*8 + ntg];                                          \
      size_t rbase = (size_t)(mt0 + (m)) * 16 + r0;                           \
      _Pragma("unroll")                                                       \
      for (int j = 0; j < 4; ++j)                                             \
        mx[(rbase + j) * 384 + col] = v[j] * scale[j];                        \
    }                                                                         \
  }
  GATE_EPI(0, 0, bv0) GATE_EPI(0, 1, bv1) GATE_EPI(0, 2, bv2)
  GATE_EPI(1, 0, bv0) GATE_EPI(1, 1, bv1) GATE_EPI(1, 2, bv2)
#undef GATE_EPI
}

// ---------------- Kernel C: hyperbolic GRU scan, 4 waves per chain --------
// Weights in VGPRs; full input prefetch; rsq-folded chain; SPLIT-HALF
// reductions: the two 32-lane halves of each wave hold identical per-o
// values, so each half reduces a DIFFERENT subset (A:3+3, B:4+3, C:1+1)
// -> per-wave butterfly count 15 -> 8, bit-identical sums.
__global__ __launch_bounds__(256, 1) void k_scan(
    const float* __restrict__ ux, const float* __restrict__ yn,
    const float* __restrict__ ub,
    const float* __restrict__ wz, const float* __restrict__ wr, const float* __restrict__ wh,
    const float* __restrict__ bzp, const float* __restrict__ brp, const float* __restrict__ bhp,
    const float* __restrict__ mask1, const float* __restrict__ mask2,
    float* __restrict__ uarr, float* __restrict__ varr) {
  __shared__ __align__(16) float hs[128];
  __shared__ __align__(16) float ps[128];
  __shared__ __align__(16) float part[72];
  float4* hs4   = (float4*)hs;
  float4* ps4   = (float4*)ps;
  float4* part4 = (float4*)part;

  int b = blockIdx.x;
  int tid = threadIdx.x;
  int w = tid >> 6;          // wave 0..3
  int l = tid & 63;          // lane
  int l31 = l & 31;
  int kh = l >> 5;           // k-half 0/1 (also reduction-subset selector)
  int o = w * 32 + l31;      // owned output/elem index

  const float4* wzg = (const float4*)wz;
  const float4* wrg = (const float4*)wr;
  const float4* whg = (const float4*)wh;
  float4 wzr[16], wrr[16], whr[16];
  #pragma unroll
  for (int i = 0; i < 16; ++i) {
    wzr[i] = wzg[o * 32 + kh * 16 + i];
    wrr[i] = wrg[o * 32 + kh * 16 + i];
    whr[i] = whg[o * 32 + kh * 16 + i];
  }

  float bzv = bzp[o], brv = brp[o], bhv = bhp[o];
  {
    float v0 = redsum32(bzv * bzv);
    float v1 = redsum32(brv * brv);
    float v2 = redsum32(bhv * bhv);
    if (l == 0) { part[15*4 + w] = v0; part[16*4 + w] = v1; part[17*4 + w] = v2; }
  }
  __syncthreads();
  float b2z, b2r, b2h;
  { float4 q;
    q = part4[15]; b2z = q.x + q.y + q.z + q.w;
    q = part4[16]; b2r = q.x + q.y + q.z + q.w;
    q = part4[17]; b2h = q.x + q.y + q.z + q.w; }

  float h = 0.f, hn2 = 0.f, au = 0.f, av = 0.f;
  const float*  uxb  = ux + (size_t)b * 128 * 384;
  const float4* ynb4 = (const float4*)yn + (size_t)b * 128;
  const float4* ubb4 = (const float4*)ub + (size_t)b * 128;
  const float*  m1p  = mask1 + b * 128;
  const float*  m2p  = mask2 + b * 128;

  // prefetch t=0 inputs
  float cuz = uxb[o], cur = uxb[128 + o], cuh = uxb[256 + o];
  float4 cyn = ynb4[0];
  float4 cub = ubb4[0];
  float cm1 = m1p[0], cm2 = m2p[0];

  #pragma unroll 1
  for (int t = 0; t < 128; ++t) {
    if (l < 32) hs[o] = h;
    __syncthreads();                      // (1) h visible
    // issue ALL t+1 prefetches
    int tn = (t + 1 < 128) ? t + 1 : 127;
    const float* uxn = uxb + tn * 384;
    float nuz = uxn[o], nur = uxn[128 + o], nuh = uxn[256 + o];
    float4 nyn = ynb4[tn];
    float4 nub = ubb4[tn];
    float nm1 = m1p[tn], nm2 = m2p[tn];
    float uz = cuz, ur = cur, uh = cuh;
    float ynz = cyn.x, ynr = cyn.y, ynh = cyn.z;
    float ubz = cub.x, ubr = cub.y, ubh = cub.z;
    float m1 = cm1, m2 = cm2;

    // wave-uniform pre-chain
    float rqh  = frsq(fmaxf(hn2, 1e-30f));
    float xnh  = fmaxf(hn2, 1e-30f) * rqh;
    float arth = fatanh(fminf(xnh, ONE_EPS));
    float axr  = arth * rqh;

    // ---- z/r matvec: register weights x LDS-broadcast h ----
    float mzp = 0.f, mrp = 0.f;
    #pragma unroll
    for (int i = 0; i < 16; ++i) {
      float4 hv = hs4[kh * 16 + i];
      mzp += DOT4(wzr[i], hv);
      mrp += DOT4(wrr[i], hv);
    }
    float mz = mzp + __shfl_xor(mzp, 32);
    float mr = mrp + __shfl_xor(mrp, 32);

    // ---- window A: 6 reductions, split 3/3 across halves ----
    {
      float v0 = kh ? mr * mr  : mz * mz;
      float v1 = kh ? mr * ur  : mz * uz;
      float v2 = kh ? mr * brv : mz * bzv;
      v0 = redsum32(v0); v1 = redsum32(v1); v2 = redsum32(v2);
      if (l31 == 0) {
        int base = kh * 3;
        part[(base + 0) * 4 + w] = v0;
        part[(base + 1) * 4 + w] = v1;
        part[(base + 2) * 4 + w] = v2;
      }
    }
    __syncthreads();                      // (2) window A partials
    float sMz2, sMzUz, sMzBz, sMr2, sMrUr, sMrBr;
    { float4 q;
      q = part4[0]; sMz2  = q.x + q.y + q.z + q.w;
      q = part4[1]; sMzUz = q.x + q.y + q.z + q.w;
      q = part4[2]; sMzBz = q.x + q.y + q.z + q.w;
      q = part4[3]; sMr2  = q.x + q.y + q.z + q.w;
      q = part4[4]; sMrUr = q.x + q.y + q.z + q.w;
      q = part4[5]; sMrBr = q.x + q.y + q.z + q.w; }

    // ---- z chain (rsq-folded) ----
    float rqz = frsq(fmaxf(sMz2, 1e-30f));
    float mzn = fmaxf(sMz2, 1e-30f) * rqz;
    float tz  = ftanh(mzn * axr);
    float szs = tz * rqz;
    float xyz = szs * sMzUz;
    float y2z = ynz * ynz, x2z = tz * tz;
    float c1z = 1.f + 2.f * xyz + y2z, c2z = 1.f - x2z;
    float idnz = frcp(fmaxf(1.f + 2.f * xyz + x2z * y2z, MINN));
    float az  = (c1z * szs * mz + c2z * uz) * idnz;
    float az2 = fmaxf(idnz * idnz * (c1z * c1z * x2z + 2.f * c1z * c2z * xyz + c2z * c2z * y2z), 0.f);
    float azb = idnz * (c1z * szs * sMzBz + c2z * ubz);
    float c1zb = 1.f + 2.f * azb + b2z, c2zb = 1.f - az2;
    float idnzb = frcp(fmaxf(1.f + 2.f * azb + az2 * b2z, MINN));
    float cz = (c1zb * az + c2zb * bzv) * idnzb;
    float cn2z = fmaxf(idnzb * idnzb * (c1zb * c1zb * az2 + 2.f * c1zb * c2zb * azb + c2zb * c2zb * b2z), 0.f);
    float rqcz = frsq(fmaxf(cn2z, 1e-30f));
    float cnz = fmaxf(cn2z, 1e-30f) * rqcz;
    float lsz = fatanh(fminf(cnz, ONE_EPS)) * rqcz;
    float zg = fsig(lsz * cz);

    // ---- r chain ----
    float rqr = frsq(fmaxf(sMr2, 1e-30f));
    float mrn = fmaxf(sMr2, 1e-30f) * rqr;
    float trr = ftanh(mrn * axr);
    float srs = trr * rqr;
    float xyr = srs * sMrUr;
    float y2r = ynr * ynr, x2r = trr * trr;
    float c1r = 1.f + 2.f * xyr + y2r, c2r = 1.f - x2r;
    float idnr = frcp(fmaxf(1.f + 2.f * xyr + x2r * y2r, MINN));
    float ar  = (c1r * srs * mr + c2r * ur) * idnr;
    float ar2 = fmaxf(idnr * idnr * (c1r * c1r * x2r + 2.f * c1r * c2r * xyr + c2r * c2r * y2r), 0.f);
    float arb = idnr * (c1r * srs * sMrBr + c2r * ubr);
    float c1rb = 1.f + 2.f * arb + b2r, c2rb = 1.f - ar2;
    float idnrb = frcp(fmaxf(1.f + 2.f * arb + ar2 * b2r, MINN));
    float cr = (c1rb * ar + c2rb * brv) * idnrb;
    float cn2r = fmaxf(idnrb * idnrb * (c1rb * c1rb * ar2 + 2.f * c1rb * c2rb * arb + c2rb * c2rb * b2r), 0.f);
    float rqcr = frsq(fmaxf(cn2r, 1e-30f));
    float cnr = fmaxf(cn2r, 1e-30f) * rqcr;
    float lsr = fatanh(fminf(cnr, ONE_EPS)) * rqcr;
    float rg = fsig(lsr * cr);

    // ---- rh = h o r (unscaled p) ----
    float p = h * rg;
    if (l < 32) ps[o] = p;
    __syncthreads();                      // (3) p visible

    // ---- h matvec from regs x ps broadcast ----
    float mhp = 0.f;
    #pragma unroll
    for (int i = 0; i < 16; ++i) {
      float4 pv = ps4[kh * 16 + i];
      mhp += DOT4(whr[i], pv);
    }
    float mh = mhp + __shfl_xor(mhp, 32);

    // ---- window B: 7 reductions, split 4/3 across halves ----
    {
      float v0 = kh ? (h * mh)  : (p * p);
      float v1 = kh ? (h * uh)  : (mh * mh);
      float v2 = kh ? (h * bhv) : (mh * uh);
      float v3 = kh ? 0.f       : (mh * bhv);
      v0 = redsum32(v0); v1 = redsum32(v1); v2 = redsum32(v2); v3 = redsum32(v3);
      if (l31 == 0) {
        if (kh) {
          part[10*4 + w] = v0; part[11*4 + w] = v1; part[12*4 + w] = v2;
        } else {
          part[6*4 + w] = v0; part[7*4 + w] = v1;
          part[8*4 + w] = v2; part[9*4 + w] = v3;
        }
      }
    }
    __syncthreads();                      // (4) window B partials
    float pn2, sMh2r, sMhUhr, sMhBhr, sHMhr, sHUh, sHBh;
    { float4 q;
      q = part4[6];  pn2    = q.x + q.y + q.z + q.w;
      q = part4[7];  sMh2r  = q.x + q.y + q.z + q.w;
      q = part4[8];  sMhUhr = q.x + q.y + q.z + q.w;
      q = part4[9];  sMhBhr = q.x + q.y + q.z + q.w;
      q = part4[10]; sHMhr  = q.x + q.y + q.z + q.w;
      q = part4[11]; sHUh   = q.x + q.y + q.z + q.w;
      q = part4[12]; sHBh   = q.x + q.y + q.z + q.w; }

    // ---- rh scaling + h~ chain (rsq-folded, srt folded) ----
    float rqp = frsq(fmaxf(pn2, 1e-30f));
    float pn  = fmaxf(pn2, 1e-30f) * rqp;
    float trh = ftanh(pn * axr);
    float srt = trh * rqp;
    float xnp  = fmaxf(trh, MINN);
    float artp = fatanh(fminf(xnp, ONE_EPS));
    float sqh  = fmaxf(sMh2r, 1e-30f) * frsq(fmaxf(sMh2r, 1e-30f));  // sqrt
    float mhn  = fmaxf(srt * sqh, MINN);
    float th   = ftanh(mhn * artp * frcp(xnp));
    float g    = th * frcp(mhn) * srt;
    float xyh  = g * sMhUhr;
    float y2h = ynh * ynh, x2h = th * th;
    float c1h = 1.f + 2.f * xyh + y2h, c2h = 1.f - x2h;
    float idnh = frcp(fmaxf(1.f + 2.f * xyh + x2h * y2h, MINN));
    float ah  = (c1h * g * mh + c2h * uh) * idnh;
    float ah2 = fmaxf(idnh * idnh * (c1h * c1h * x2h + 2.f * c1h * c2h * xyh + c2h * c2h * y2h), 0.f);
    float ahb = idnh * (c1h * g * sMhBhr + c2h * ubh);
    float hah = idnh * (c1h * g * sHMhr + c2h * sHUh);
    float c1hb = 1.f + 2.f * ahb + b2h, c2hb = 1.f - ah2;
    float idnhb = frcp(fmaxf(1.f + 2.f * ahb + ah2 * b2h, MINN));
    float ct  = (c1hb * ah + c2hb * bhv) * idnhb;
    float ct2 = fmaxf(idnhb * idnhb * (c1hb * c1hb * ah2 + 2.f * c1hb * c2hb * ahb + c2hb * c2hb * b2h), 0.f);
    float hct = idnhb * (c1hb * hah + c2hb * sHBh);

    // ---- delta = mobius_add(-h, h_tilde) ----
    float c1d = 1.f - 2.f * hct + ct2, c2d = 1.f - hn2;
    float idnd = frcp(fmaxf(1.f - 2.f * hct + hn2 * ct2, MINN));
    float dl = (c2d * ct - c1d * h) * idnd;
    float dn2 = fmaxf(idnd * idnd * (c1d * c1d * hn2 - 2.f * c1d * c2d * hct + c2d * c2d * ct2), 0.f);
    float wv = dl * zg;

    // ---- window C: 2 reductions, split 1/1 across halves ----
    {
      float vC = kh ? (h * wv) : (wv * wv);
      vC = redsum32(vC);
      if (l31 == 0) part[(13 + kh) * 4 + w] = vC;
    }
    __syncthreads();                      // (5) window C partials
    float wn2, hw;
    { float4 q;
      q = part4[13]; wn2 = q.x + q.y + q.z + q.w;
      q = part4[14]; hw  = q.x + q.y + q.z + q.w; }

    float rqd = frsq(fmaxf(dn2, 1e-30f));
    float dnv = fmaxf(dn2, 1e-30f) * rqd;
    float rqw = frsq(fmaxf(wn2, 1e-30f));
    float wnv = fmaxf(wn2, 1e-30f) * rqw;
    float tdd = ftanh(wnv * rqd * fatanh(fminf(dnv, ONE_EPS)));
    float szd = tdd * rqw;
    float zd = wv * szd;
    float hzd = hw * szd;
    float t2v = tdd * tdd;
    float c1f = 1.f + 2.f * hzd + t2v, c2f = 1.f - hn2;
    float idnf = frcp(fmaxf(1.f + 2.f * hzd + hn2 * t2v, MINN));
    float nh = (c1f * h + c2f * zd) * idnf;
    hn2 = fmaxf(idnf * idnf * (c1f * c1f * hn2 + 2.f * c1f * c2f * hzd + c2f * c2f * t2v), 0.f);
    h = nh;
    au += m1 * h; av += m2 * h;
    cuz = nuz; cur = nur; cuh = nuh;
    cyn = nyn; cub = nub; cm1 = nm1; cm2 = nm2;
  }
  if (l < 32) {
    uarr[b * 128 + o] = au;
    varr[b * 128 + o] = av;
  }
}

// ---------------- Kernel D: dist + mobius FF + hyperbolic MLR, 1 wave/b ----
__global__ __launch_bounds__(64) void k_final(
    const float* __restrict__ uarr, const float* __restrict__ varr,
    const float* __restrict__ wfu, const float* __restrict__ wfv,
    const float* __restrict__ bff, const float* __restrict__ bffd,
    const float* __restrict__ wfc, const float* __restrict__ pmlr,
    const float* __restrict__ amlr, const int* __restrict__ cids,
    const float* __restrict__ csemb, float* __restrict__ out) {
  int b = blockIdx.x;
  int l = threadIdx.x;
  __shared__ float us[128], vs[128], cbuf[64];
  float q0 = uarr[b * 128 + l], q1 = uarr[b * 128 + 64 + l];
  float r0 = varr[b * 128 + l], r1 = varr[b * 128 + 64 + l];
  us[l] = q0; us[l + 64] = q1; vs[l] = r0; vs[l + 64] = r1;
  __syncthreads();
  float u2 = redsum(q0 * q0 + q1 * q1);
  float v2 = redsum(r0 * r0 + r1 * r1);
  float uv = redsum(q0 * r0 + q1 * r1);
  float dsq;
  { float x2 = u2, y2 = v2, xy = -uv;
    float c1 = 1.f + 2.f * xy + y2, c2 = 1.f - x2;
    float idn = 1.f / fmaxf(1.f + 2.f * xy + x2 * y2, MINN);
    float d0 = (c1 * (-q0) + c2 * r0) * idn, d1 = (c1 * (-q1) + c2 * r1) * idn;
    float dn2 = redsum(d0 * d0 + d1 * d1);
    dsq = 2.f * atanhf(clampart(sqrtf(dn2))); }
  float mxu = 0.f, mxv = 0.f;
  #pragma unroll 4
  for (int jc = 0; jc < 128; jc += 4) {
    float4 uu = *reinterpret_cast<const float4*>(&us[jc]);
    float4 vv = *reinterpret_cast<const float4*>(&vs[jc]);
    float4 wu4 = *reinterpret_cast<const float4*>(wfu + (size_t)l * 128 + jc);
    float4 wv4 = *reinterpret_cast<const float4*>(wfv + (size_t)l * 128 + jc);
    mxu += DOT4(wu4, uu); mxv += DOT4(wv4, vv);
  }
  float xnu = fmaxf(sqrtf(u2), MINN);
  float xnv = fmaxf(sqrtf(v2), MINN);
  float mun = fmaxf(sqrtf(redsum(mxu * mxu)), MINN);
  float mvn = fmaxf(sqrtf(redsum(mxv * mxv)), MINN);
  float tu = tanhf(mun / xnu * atanhf(clampart(xnu)));
  float tv = tanhf(mvn / xnv * atanhf(clampart(xnv)));
  float fu = mxu * (tu / mun), fv = mxv * (tv / mvn);
  float o1;
  { float x2 = tu * tu, y2 = tv * tv, xy = redsum(fu * fv);
    float c1 = 1.f + 2.f * xy + y2, c2 = 1.f - x2;
    float idn = 1.f / fmaxf(1.f + 2.f * xy + x2 * y2, MINN);
    o1 = (c1 * fu + c2 * fv) * idn; }
  float bffl = bff[l];
  float bf2 = redsum(bffl * bffl);
  float o2;
  { float x2 = redsum(o1 * o1), y2 = bf2, xy = redsum(o1 * bffl);
    float c1 = 1.f + 2.f * xy + y2, c2 = 1.f - x2;
    float idn = 1.f / fmaxf(1.f + 2.f * xy + x2 * y2, MINN);
    o2 = (c1 * o1 + c2 * bffl) * idn; }
  float bdl = bffd[l];
  float bdn = fmaxf(sqrtf(redsum(bdl * bdl)), MINN);
  float tsm = tanhf(dsq * atanhf(clampart(bdn)));
  float sm = bdl * (tsm / bdn);
  float o3;
  { float x2 = redsum(o2 * o2), y2 = tsm * tsm, xy = redsum(o2 * sm);
    float c1 = 1.f + 2.f * xy + y2, c2 = 1.f - x2;
    float idn = 1.f / fmaxf(1.f + 2.f * xy + x2 * y2, MINN);
    o3 = (c1 * o2 + c2 * sm) * idn; }
  int cid = cids[b];
  float ce = csemb[(size_t)cid * 64 + l];
  cbuf[l] = ce;
  __syncthreads();
  float ce2 = redsum(ce * ce);
  float mxc = 0.f;
  #pragma unroll 4
  for (int jc = 0; jc < 64; jc += 4) {
    float4 cc = *reinterpret_cast<const float4*>(&cbuf[jc]);
    float4 wc4 = *reinterpret_cast<const float4*>(wfc + (size_t)l * 64 + jc);
    mxc += DOT4(wc4, cc);
  }
  float xnc = fmaxf(sqrtf(ce2), MINN);
  float mcn = fmaxf(sqrtf(redsum(mxc * mxc)), MINN);
  float tc = tanhf(mcn / xnc * atanhf(clampart(xnc)));
  float fc = mxc * (tc / mcn);
  float o4;
  { float x2 = redsum(o3 * o3), y2 = tc * tc, xy = redsum(o3 * fc);
    float c1 = 1.f + 2.f * xy + y2, c2 = 1.f - x2;
    float idn = 1.f / fmaxf(1.f + 2.f * xy + x2 * y2, MINN);
    o4 = (c1 * o3 + c2 * fc) * idn; }
  float on = fmaxf(sqrtf(redsum(o4 * o4)), MINN);
  float lo = o4 * (atanhf(clampart(on)) / on);
  float un = fmaxf(sqrtf(redsum(lo * lo)), MINN);
  float eo = lo * (tanhf(un) / un);
  float eo2 = redsum(eo * eo);
  for (int c = 0; c < 4; ++c) {
    float pc = pmlr[c * 64 + l];
    float ac = amlr[c * 64 + l];
    float p2 = redsum(pc * pc);
    float pe = redsum(pc * eo);
    float x2 = p2, y2 = eo2, xy = -pe;
    float c1 = 1.f + 2.f * xy + y2, c2 = 1.f - x2;
    float idn = 1.f / fmaxf(1.f + 2.f * xy + x2 * y2, MINN);
    float mp = (c1 * (-pc) + c2 * eo) * idn;
    float mp2 = redsum(mp * mp);
    float lam = 2.f / (1.f - mp2);
    float na = sqrtf(redsum(ac * ac));
    float au = ac / fmaxf(na, 1e-12f);
    float pda = redsum(mp * au);
    if (l == 0) out[b * 4 + c] = 2.f * na * asinhf(pda * lam);
  }
}

extern "C" void kernel_launch(void* const* d_in, const int* in_sizes, int n_in,
                              void* d_out, int out_size, void* d_ws, size_t ws_size,
                              hipStream_t stream) {
  const float* seq   = (const float*)d_in[0];
  const float* mask1 = (const float*)d_in[1];
  const float* mask2 = (const float*)d_in[2];
  const int*   cids  = (const int*)d_in[3];
  const float* csemb = (const float*)d_in[4];
  const float* wz  = (const float*)d_in[5];
  const float* wr  = (const float*)d_in[6];
  const float* wh  = (const float*)d_in[7];
  const float* uz  = (const float*)d_in[8];
  const float* ur  = (const float*)d_in[9];
  const float* uh  = (const float*)d_in[10];
  const float* bz  = (const float*)d_in[11];
  const float* br  = (const float*)d_in[12];
  const float* bh  = (const float*)d_in[13];
  const float* wfu = (const float*)d_in[14];
  const float* wfv = (const float*)d_in[15];
  const float* bff = (const float*)d_in[16];
  const float* bffd= (const float*)d_in[17];
  const float* wfc = (const float*)d_in[18];
  const float* pmlr= (const float*)d_in[19];
  const float* amlr= (const float*)d_in[20];
  float* ws = (float*)d_ws;
  float* mx      = ws;                             // 32768*384
  float* yn      = mx + (size_t)32768 * 384;       // 32768*4
  float* ubp     = yn + (size_t)32768 * 4;         // 32768*4
  float* bhi_f   = ubp + (size_t)32768 * 4;        // 147456 f32
  float* blo_f   = bhi_f + 147456;                 // 147456 f32
  float* uarr    = blo_f + 147456;                 // 256*128
  float* varr    = uarr + 256 * 128;               // 256*128
  uint4* Bh = (uint4*)bhi_f;
  uint4* Bl = (uint4*)blo_f;

  k_convB<<<dim3(144), dim3(256), 0, stream>>>(uz, ur, uh, Bh, Bl);
  k_gemm_fused<<<dim3(256), dim3(256), 0, stream>>>(seq, Bh, Bl, bz, br, bh,
                                                    mx, yn, ubp);
  k_scan<<<dim3(256), dim3(256), 0, stream>>>(mx, yn, ubp, wz, wr, wh,
                                              bz, br, bh, mask1, mask2,
                                              uarr, varr);
  k_final<<<dim3(256), dim3(64), 0, stream>>>(uarr, varr, wfu, wfv, bff, bffd,
                                              wfc, pmlr, amlr, cids, csemb,
                                              (float*)d_out);
}

// Round 11
// 499.689 us; speedup vs baseline: 6.5915x; 1.0341x over previous
//
#include <hip/hip_runtime.h>
#include <math.h>

#define MINN 1e-15f
#define ONE_EPS 0.99999f   // 1 - 1e-5 (artanh clamp)

__device__ __forceinline__ float clampart(float x) {
  return fminf(fmaxf(x, -1.0f + 1e-5f), 1.0f - 1e-5f);
}
__device__ __forceinline__ float redsum(float x) {
  #pragma unroll
  for (int m = 32; m; m >>= 1) x += __shfl_xor(x, m);
  return x;
}
// 5-level butterfly within each 32-lane half
__device__ __forceinline__ float redsum32(float x) {
  #pragma unroll
  for (int m = 16; m; m >>= 1) x += __shfl_xor(x, m);
  return x;
}
__device__ __forceinline__ float frcp(float x) { return __builtin_amdgcn_rcpf(x); }
__device__ __forceinline__ float frsq(float x) { return __builtin_amdgcn_rsqf(x); }
__device__ __forceinline__ float fexp2(float x) { return __builtin_amdgcn_exp2f(x); }
__device__ __forceinline__ float flog2(float x) { return __builtin_amdgcn_logf(x); }
__device__ __forceinline__ float ftanh(float x) {
  float e = fexp2(x * 2.88539008f);
  return 1.0f - 2.0f * frcp(e + 1.0f);
}
__device__ __forceinline__ float fatanh(float x) {
  return 0.34657359f * flog2((1.0f + x) * frcp(1.0f - x));
}
__device__ __forceinline__ float fsig(float x) {
  return frcp(1.0f + fexp2(-1.44269504f * x));
}
#define DOT4(a, b) ((a).x*(b).x + (a).y*(b).y + (a).z*(b).z + (a).w*(b).w)

// ---- bf16 split helpers (x = hi + lo, each bf16; rel err ~2^-18) ----------
__device__ __forceinline__ unsigned bfh(float x) {
  unsigned u = __float_as_uint(x);
  return (u + 0x7FFFu + ((u >> 16) & 1u)) >> 16;    // RNE to bf16 bits
}
__device__ __forceinline__ void splitpack(float4 q0, float4 q1,
                                          uint4& hi, uint4& lo) {
  unsigned h0=bfh(q0.x),h1=bfh(q0.y),h2=bfh(q0.z),h3=bfh(q0.w);
  unsigned h4=bfh(q1.x),h5=bfh(q1.y),h6=bfh(q1.z),h7=bfh(q1.w);
  float r0=q0.x-__uint_as_float(h0<<16), r1=q0.y-__uint_as_float(h1<<16);
  float r2=q0.z-__uint_as_float(h2<<16), r3=q0.w-__uint_as_float(h3<<16);
  float r4=q1.x-__uint_as_float(h4<<16), r5=q1.y-__uint_as_float(h5<<16);
  float r6=q1.z-__uint_as_float(h6<<16), r7=q1.w-__uint_as_float(h7<<16);
  hi = make_uint4(h0|(h1<<16), h2|(h3<<16), h4|(h5<<16), h6|(h7<<16));
  lo = make_uint4(bfh(r0)|(bfh(r1)<<16), bfh(r2)|(bfh(r3)<<16),
                  bfh(r4)|(bfh(r5)<<16), bfh(r6)|(bfh(r7)<<16));
}
typedef __attribute__((ext_vector_type(8))) short bf16x8;
typedef __attribute__((ext_vector_type(4))) float f32x4;
__device__ __forceinline__ bf16x8 asfrag(uint4 u) {
  union { uint4 u; bf16x8 f; } c; c.u = u; return c.f;
}

// -------- Kernel B0: U matrices -> bf16 hi/lo fragment-linear layout -------
__global__ __launch_bounds__(256) void k_convB(const float* __restrict__ uz,
    const float* __restrict__ ur, const float* __restrict__ uh,
    uint4* __restrict__ Bh, uint4* __restrict__ Bl) {
  int tid = threadIdx.x;
  int l = tid & 63;
  int s = blockIdx.x * 4 + (tid >> 6);     // 0..575
  int kt = s / 24, nt = s % 24;
  int n = nt * 16 + (l & 15);
  const float* U = (n < 128) ? uz : (n < 256 ? ur : uh);
  int i = n & 127;
  int k = kt * 32 + (l >> 4) * 8;
  float4 q0 = *reinterpret_cast<const float4*>(U + (size_t)i * 768 + k);
  float4 q1 = *reinterpret_cast<const float4*>(U + (size_t)i * 768 + k + 4);
  uint4 hi, lo;
  splitpack(q0, q1, hi, lo);
  Bh[(size_t)(kt * 24 + nt) * 64 + l] = hi;
  Bl[(size_t)(kt * 24 + nt) * 64 + l] = lo;
}

// -------- Kernel B: fused MFMA GEMM + expmap0 stats + mobius_matvec NL -----
// B staged per-kt in double-buffered LDS (48KB/buf): each B element enters
// the CU once (was 4x, one per wave) -> GEMM leaves the L2-delivery bound.
__global__ __launch_bounds__(256, 1) void k_gemm_fused(
    const float* __restrict__ A, const uint4* __restrict__ Bh,
    const uint4* __restrict__ Bl,
    const float* __restrict__ bzp, const float* __restrict__ brp,
    const float* __restrict__ bhp,
    float* __restrict__ mx, float* __restrict__ yn, float* __restrict__ ub) {
  __shared__ uint4 bstage[2][3072];        // [buf][Bh:0..1535 | Bl:1536..3071]
  int tid = threadIdx.x;
  int l = tid & 63;
  int wv = tid >> 6;                       // wave 0..3
  int wid = blockIdx.x * 4 + wv;           // 0..1023
  int mt0 = wid * 2;
  int mrow = l & 15;
  int koff = (l >> 4) * 8;
  int sbase = wv * 384 + l;                // staging slot base (6 chunks of 64)

  f32x4 acc[2][24];
  #pragma unroll
  for (int m = 0; m < 2; ++m)
    #pragma unroll
    for (int n = 0; n < 24; ++n) acc[m][n] = (f32x4){0.f, 0.f, 0.f, 0.f};
  float ssA0 = 0.f, ssA1 = 0.f;

  // prologue: stage kt=0 into buf 0
  {
    const uint4* sH = Bh;                  // kt=0
    const uint4* sL = Bl;
    #pragma unroll
    for (int j = 0; j < 6; ++j) {
      bstage[0][sbase + j * 64]        = sH[sbase + j * 64];
      bstage[0][1536 + sbase + j * 64] = sL[sbase + j * 64];
    }
  }
  __syncthreads();

  #pragma unroll 1
  for (int kt = 0; kt < 24; ++kt) {
    int cb = kt & 1;
    // stage kt+1 into the other buffer (loads overlap this kt's MFMA)
    if (kt + 1 < 24) {
      const uint4* sH = Bh + (size_t)(kt + 1) * 1536;
      const uint4* sL = Bl + (size_t)(kt + 1) * 1536;
      #pragma unroll
      for (int j = 0; j < 6; ++j) {
        bstage[cb ^ 1][sbase + j * 64]        = sH[sbase + j * 64];
        bstage[cb ^ 1][1536 + sbase + j * 64] = sL[sbase + j * 64];
      }
    }
    const float* a0p = A + (size_t)(mt0 * 16 + mrow) * 768 + kt * 32 + koff;
    const float* a1p = a0p + 16 * 768;
    float4 q0 = *reinterpret_cast<const float4*>(a0p);
    float4 q1 = *reinterpret_cast<const float4*>(a0p + 4);
    float4 q2 = *reinterpret_cast<const float4*>(a1p);
    float4 q3 = *reinterpret_cast<const float4*>(a1p + 4);
    ssA0 += DOT4(q0, q0) + DOT4(q1, q1);
    ssA1 += DOT4(q2, q2) + DOT4(q3, q3);
    uint4 ah0u, al0u, ah1u, al1u;
    splitpack(q0, q1, ah0u, al0u);
    splitpack(q2, q3, ah1u, al1u);
    bf16x8 ah0 = asfrag(ah0u), al0 = asfrag(al0u);
    bf16x8 ah1 = asfrag(ah1u), al1 = asfrag(al1u);
    const uint4* bhp4 = &bstage[cb][l];
    const uint4* blp4 = &bstage[cb][1536 + l];
    #pragma unroll
    for (int nt = 0; nt < 24; ++nt) {
      bf16x8 bh = asfrag(bhp4[nt * 64]);
      bf16x8 bl = asfrag(blp4[nt * 64]);
      acc[0][nt] = __builtin_amdgcn_mfma_f32_16x16x32_bf16(ah0, bh, acc[0][nt], 0, 0, 0);
      acc[0][nt] = __builtin_amdgcn_mfma_f32_16x16x32_bf16(ah0, bl, acc[0][nt], 0, 0, 0);
      acc[0][nt] = __builtin_amdgcn_mfma_f32_16x16x32_bf16(al0, bh, acc[0][nt], 0, 0, 0);
      acc[0][nt] = __builtin_amdgcn_mfma_f32_16x16x32_bf16(al0, bl, acc[0][nt], 0, 0, 0);
      acc[1][nt] = __builtin_amdgcn_mfma_f32_16x16x32_bf16(ah1, bh, acc[1][nt], 0, 0, 0);
      acc[1][nt] = __builtin_amdgcn_mfma_f32_16x16x32_bf16(ah1, bl, acc[1][nt], 0, 0, 0);
      acc[1][nt] = __builtin_amdgcn_mfma_f32_16x16x32_bf16(al1, bh, acc[1][nt], 0, 0, 0);
      acc[1][nt] = __builtin_amdgcn_mfma_f32_16x16x32_bf16(al1, bl, acc[1][nt], 0, 0, 0);
    }
    __syncthreads();   // staging complete + all waves done reading buf cb
  }
  // ---- seq row stats (A layout: lane covers koff-quarter of row mrow) ----
  ssA0 += __shfl_xor(ssA0, 16); ssA0 += __shfl_xor(ssA0, 32);
  ssA1 += __shfl_xor(ssA1, 16); ssA1 += __shfl_xor(ssA1, 32);
  float aA[2], rxA[2];
  {
    float un0 = sqrtf(ssA0), unc0 = fmaxf(un0, MINN);
    float a0 = tanhf(unc0) / unc0;
    float xn0 = fmaxf(a0 * un0, MINN);
    aA[0] = a0; rxA[0] = atanhf(clampart(xn0)) / xn0;
    float un1 = sqrtf(ssA1), unc1 = fmaxf(un1, MINN);
    float a1 = tanhf(unc1) / unc1;
    float xn1 = fmaxf(a1 * un1, MINN);
    aA[1] = a1; rxA[1] = atanhf(clampart(xn1)) / xn1;
  }
  // ---- remap stats to C-layout rows (row = r0 + j) ----
  int r0 = (l >> 4) * 4;
  float aC[2][4], rxC[2][4];
  #pragma unroll
  for (int m = 0; m < 2; ++m)
    #pragma unroll
    for (int j = 0; j < 4; ++j) {
      aC[m][j]  = __shfl(aA[m],  r0 + j);
      rxC[m][j] = __shfl(rxA[m], r0 + j);
    }
  // ---- bias values for ub dots: b_g[col], col = nt*16 + mrow ----
  float bv0[8], bv1[8], bv2[8];
  #pragma unroll
  for (int i = 0; i < 8; ++i) {
    bv0[i] = bzp[i * 16 + mrow];
    bv1[i] = brp[i * 16 + mrow];
    bv2[i] = bhp[i * 16 + mrow];
  }
#define GATE_EPI(m, g, bvarr)                                                 \
  {                                                                           \
    float ss0=0.f,ss1=0.f,ss2=0.f,ss3=0.f,sb0=0.f,sb1=0.f,sb2=0.f,sb3=0.f;    \
    _Pragma("unroll")                                                         \
    for (int ntg = 0; ntg < 8; ++ntg) {                                       \
      f32x4 v = acc[m][(g)*8 + ntg];                                          \
      float bb = bvarr[ntg];                                                  \
      ss0 += v[0]*v[0]; sb0 += v[0]*bb;                                       \
      ss1 += v[1]*v[1]; sb1 += v[1]*bb;                                       \
      ss2 += v[2]*v[2]; sb2 += v[2]*bb;                                       \
      ss3 += v[3]*v[3]; sb3 += v[3]*bb;                                       \
    }                                                                         \
    _Pragma("unroll")                                                         \
    for (int mk = 1; mk <= 8; mk <<= 1) {                                     \
      ss0 += __shfl_xor(ss0, mk); sb0 += __shfl_xor(sb0, mk);                 \
      ss1 += __shfl_xor(ss1, mk); sb1 += __shfl_xor(sb1, mk);                 \
      ss2 += __shfl_xor(ss2, mk); sb2 += __shfl_xor(sb2, mk);                 \
      ss3 += __shfl_xor(ss3, mk); sb3 += __shfl_xor(sb3, mk);                 \
    }                                                                         \
    float ssv[4] = {ss0, ss1, ss2, ss3};                                      \
    float sbv[4] = {sb0, sb1, sb2, sb3};                                      \
    float scale[4];                                                           \
    _Pragma("unroll")                                                         \
    for (int j = 0; j < 4; ++j) {                                             \
      float mxn = fmaxf(aC[m][j] * sqrtf(ssv[j]), MINN);                      \
      float tt = tanhf(mxn * rxC[m][j]);                                      \
      float sc = tt / mxn;                                                    \
      scale[j] = aC[m][j] * sc;                                               \
      if (mrow == 0) {                                                        \
        size_t row = (size_t)(mt0 + (m)) * 16 + r0 + j;                       \
        yn[row * 4 + (g)] = tt;                                               \
        ub[row * 4 + (g)] = scale[j] * sbv[j];                                \
      }                                                                       \
    }                                                                         \
    _Pragma("unroll")                                                         \
    for (int ntg = 0; ntg < 8; ++ntg) {                                       \
      int col = ((g)*8 + ntg) * 16 + mrow;                                    \
      f32x4 v = acc[m][(g)*8 + ntg];                                          \
      size_t rbase = (size_t)(mt0 + (m)) * 16 + r0;                           \
      _Pragma("unroll")                                                       \
      for (int j = 0; j < 4; ++j)                                             \
        mx[(rbase + j) * 384 + col] = v[j] * scale[j];                        \
    }                                                                         \
  }
  GATE_EPI(0, 0, bv0) GATE_EPI(0, 1, bv1) GATE_EPI(0, 2, bv2)
  GATE_EPI(1, 0, bv0) GATE_EPI(1, 1, bv1) GATE_EPI(1, 2, bv2)
#undef GATE_EPI
}

// ---------------- Kernel C: hyperbolic GRU scan, 4 waves per chain --------
// Weights in VGPRs; full input prefetch; rsq-folded chain; split-half
// reductions (A:3+3, B:4+3, C:1+1). hs/ps written by both halves
// (identical values; 2-way same-address LDS write is free).
__global__ __launch_bounds__(256, 1) void k_scan(
    const float* __restrict__ ux, const float* __restrict__ yn,
    const float* __restrict__ ub,
    const float* __restrict__ wz, const float* __restrict__ wr, const float* __restrict__ wh,
    const float* __restrict__ bzp, const float* __restrict__ brp, const float* __restrict__ bhp,
    const float* __restrict__ mask1, const float* __restrict__ mask2,
    float* __restrict__ uarr, float* __restrict__ varr) {
  __shared__ __align__(16) float hs[128];
  __shared__ __align__(16) float ps[128];
  __shared__ __align__(16) float part[72];
  float4* hs4   = (float4*)hs;
  float4* ps4   = (float4*)ps;
  float4* part4 = (float4*)part;

  int b = blockIdx.x;
  int tid = threadIdx.x;
  int w = tid >> 6;          // wave 0..3
  int l = tid & 63;          // lane
  int l31 = l & 31;
  int kh = l >> 5;           // k-half 0/1 (also reduction-subset selector)
  int o = w * 32 + l31;      // owned output/elem index

  const float4* wzg = (const float4*)wz;
  const float4* wrg = (const float4*)wr;
  const float4* whg = (const float4*)wh;
  float4 wzr[16], wrr[16], whr[16];
  #pragma unroll
  for (int i = 0; i < 16; ++i) {
    wzr[i] = wzg[o * 32 + kh * 16 + i];
    wrr[i] = wrg[o * 32 + kh * 16 + i];
    whr[i] = whg[o * 32 + kh * 16 + i];
  }

  float bzv = bzp[o], brv = brp[o], bhv = bhp[o];
  {
    float v0 = redsum32(bzv * bzv);
    float v1 = redsum32(brv * brv);
    float v2 = redsum32(bhv * bhv);
    if (l == 0) { part[15*4 + w] = v0; part[16*4 + w] = v1; part[17*4 + w] = v2; }
  }
  __syncthreads();
  float b2z, b2r, b2h;
  { float4 q;
    q = part4[15]; b2z = q.x + q.y + q.z + q.w;
    q = part4[16]; b2r = q.x + q.y + q.z + q.w;
    q = part4[17]; b2h = q.x + q.y + q.z + q.w; }

  float h = 0.f, hn2 = 0.f, au = 0.f, av = 0.f;
  const float*  uxb  = ux + (size_t)b * 128 * 384;
  const float4* ynb4 = (const float4*)yn + (size_t)b * 128;
  const float4* ubb4 = (const float4*)ub + (size_t)b * 128;
  const float*  m1p  = mask1 + b * 128;
  const float*  m2p  = mask2 + b * 128;

  // prefetch t=0 inputs
  float cuz = uxb[o], cur = uxb[128 + o], cuh = uxb[256 + o];
  float4 cyn = ynb4[0];
  float4 cub = ubb4[0];
  float cm1 = m1p[0], cm2 = m2p[0];

  #pragma unroll 1
  for (int t = 0; t < 128; ++t) {
    hs[o] = h;                            // both halves write identical value
    __syncthreads();                      // (1) h visible
    // issue ALL t+1 prefetches
    int tn = (t < 127) ? t + 1 : 127;
    const float* uxn = uxb + tn * 384;
    float nuz = uxn[o], nur = uxn[128 + o], nuh = uxn[256 + o];
    float4 nyn = ynb4[tn];
    float4 nub = ubb4[tn];
    float nm1 = m1p[tn], nm2 = m2p[tn];
    float uz = cuz, ur = cur, uh = cuh;
    float ynz = cyn.x, ynr = cyn.y, ynh = cyn.z;
    float ubz = cub.x, ubr = cub.y, ubh = cub.z;
    float m1 = cm1, m2 = cm2;

    // wave-uniform pre-chain
    float rqh  = frsq(fmaxf(hn2, 1e-30f));
    float xnh  = fmaxf(hn2, 1e-30f) * rqh;
    float arth = fatanh(fminf(xnh, ONE_EPS));
    float axr  = arth * rqh;

    // ---- z/r matvec: register weights x LDS-broadcast h ----
    float mzp = 0.f, mrp = 0.f;
    #pragma unroll
    for (int i = 0; i < 16; ++i) {
      float4 hv = hs4[kh * 16 + i];
      mzp += DOT4(wzr[i], hv);
      mrp += DOT4(wrr[i], hv);
    }
    float mz = mzp + __shfl_xor(mzp, 32);
    float mr = mrp + __shfl_xor(mrp, 32);

    // ---- window A: 6 reductions, split 3/3 across halves ----
    {
      float v0 = kh ? mr * mr  : mz * mz;
      float v1 = kh ? mr * ur  : mz * uz;
      float v2 = kh ? mr * brv : mz * bzv;
      v0 = redsum32(v0); v1 = redsum32(v1); v2 = redsum32(v2);
      if (l31 == 0) {
        int base = kh * 3;
        part[(base + 0) * 4 + w] = v0;
        part[(base + 1) * 4 + w] = v1;
        part[(base + 2) * 4 + w] = v2;
      }
    }
    __syncthreads();                      // (2) window A partials
    float sMz2, sMzUz, sMzBz, sMr2, sMrUr, sMrBr;
    { float4 q;
      q = part4[0]; sMz2  = q.x + q.y + q.z + q.w;
      q = part4[1]; sMzUz = q.x + q.y + q.z + q.w;
      q = part4[2]; sMzBz = q.x + q.y + q.z + q.w;
      q = part4[3]; sMr2  = q.x + q.y + q.z + q.w;
      q = part4[4]; sMrUr = q.x + q.y + q.z + q.w;
      q = part4[5]; sMrBr = q.x + q.y + q.z + q.w; }

    // ---- z chain (rsq-folded) ----
    float rqz = frsq(fmaxf(sMz2, 1e-30f));
    float mzn = fmaxf(sMz2, 1e-30f) * rqz;
    float tz  = ftanh(mzn * axr);
    float szs = tz * rqz;
    float xyz = szs * sMzUz;
    float y2z = ynz * ynz, x2z = tz * tz;
    float c1z = 1.f + 2.f * xyz + y2z, c2z = 1.f - x2z;
    float idnz = frcp(fmaxf(1.f + 2.f * xyz + x2z * y2z, MINN));
    float az  = (c1z * szs * mz + c2z * uz) * idnz;
    float az2 = fmaxf(idnz * idnz * (c1z * c1z * x2z + 2.f * c1z * c2z * xyz + c2z * c2z * y2z), 0.f);
    float azb = idnz * (c1z * szs * sMzBz + c2z * ubz);
    float c1zb = 1.f + 2.f * azb + b2z, c2zb = 1.f - az2;
    float idnzb = frcp(fmaxf(1.f + 2.f * azb + az2 * b2z, MINN));
    float cz = (c1zb * az + c2zb * bzv) * idnzb;
    float cn2z = fmaxf(idnzb * idnzb * (c1zb * c1zb * az2 + 2.f * c1zb * c2zb * azb + c2zb * c2zb * b2z), 0.f);
    float rqcz = frsq(fmaxf(cn2z, 1e-30f));
    float cnz = fmaxf(cn2z, 1e-30f) * rqcz;
    float lsz = fatanh(fminf(cnz, ONE_EPS)) * rqcz;
    float zg = fsig(lsz * cz);

    // ---- r chain ----
    float rqr = frsq(fmaxf(sMr2, 1e-30f));
    float mrn = fmaxf(sMr2, 1e-30f) * rqr;
    float trr = ftanh(mrn * axr);
    float srs = trr * rqr;
    float xyr = srs * sMrUr;
    float y2r = ynr * ynr, x2r = trr * trr;
    float c1r = 1.f + 2.f * xyr + y2r, c2r = 1.f - x2r;
    float idnr = frcp(fmaxf(1.f + 2.f * xyr + x2r * y2r, MINN));
    float ar  = (c1r * srs * mr + c2r * ur) * idnr;
    float ar2 = fmaxf(idnr * idnr * (c1r * c1r * x2r + 2.f * c1r * c2r * xyr + c2r * c2r * y2r), 0.f);
    float arb = idnr * (c1r * srs * sMrBr + c2r * ubr);
    float c1rb = 1.f + 2.f * arb + b2r, c2rb = 1.f - ar2;
    float idnrb = frcp(fmaxf(1.f + 2.f * arb + ar2 * b2r, MINN));
    float cr = (c1rb * ar + c2rb * brv) * idnrb;
    float cn2r = fmaxf(idnrb * idnrb * (c1rb * c1rb * ar2 + 2.f * c1rb * c2rb * arb + c2rb * c2rb * b2r), 0.f);
    float rqcr = frsq(fmaxf(cn2r, 1e-30f));
    float cnr = fmaxf(cn2r, 1e-30f) * rqcr;
    float lsr = fatanh(fminf(cnr, ONE_EPS)) * rqcr;
    float rg = fsig(lsr * cr);

    // ---- rh = h o r (unscaled p) ----
    float p = h * rg;
    ps[o] = p;                            // both halves, identical value
    __syncthreads();                      // (3) p visible

    // ---- h matvec from regs x ps broadcast ----
    float mhp = 0.f;
    #pragma unroll
    for (int i = 0; i < 16; ++i) {
      float4 pv = ps4[kh * 16 + i];
      mhp += DOT4(whr[i], pv);
    }
    float mh = mhp + __shfl_xor(mhp, 32);

    // ---- window B: 7 reductions, split 4/3 across halves ----
    {
      float v0 = kh ? (h * mh)  : (p * p);
      float v1 = kh ? (h * uh)  : (mh * mh);
      float v2 = kh ? (h * bhv) : (mh * uh);
      float v3 = kh ? 0.f       : (mh * bhv);
      v0 = redsum32(v0); v1 = redsum32(v1); v2 = redsum32(v2); v3 = redsum32(v3);
      if (l31 == 0) {
        if (kh) {
          part[10*4 + w] = v0; part[11*4 + w] = v1; part[12*4 + w] = v2;
        } else {
          part[6*4 + w] = v0; part[7*4 + w] = v1;
          part[8*4 + w] = v2; part[9*4 + w] = v3;
        }
      }
    }
    __syncthreads();                      // (4) window B partials
    float pn2, sMh2r, sMhUhr, sMhBhr, sHMhr, sHUh, sHBh;
    { float4 q;
      q = part4[6];  pn2    = q.x + q.y + q.z + q.w;
      q = part4[7];  sMh2r  = q.x + q.y + q.z + q.w;
      q = part4[8];  sMhUhr = q.x + q.y + q.z + q.w;
      q = part4[9];  sMhBhr = q.x + q.y + q.z + q.w;
      q = part4[10]; sHMhr  = q.x + q.y + q.z + q.w;
      q = part4[11]; sHUh   = q.x + q.y + q.z + q.w;
      q = part4[12]; sHBh   = q.x + q.y + q.z + q.w; }

    // ---- rh scaling + h~ chain (rsq-folded, srt folded) ----
    float rqp = frsq(fmaxf(pn2, 1e-30f));
    float pn  = fmaxf(pn2, 1e-30f) * rqp;
    float trh = ftanh(pn * axr);
    float srt = trh * rqp;
    float xnp  = fmaxf(trh, MINN);
    float artp = fatanh(fminf(xnp, ONE_EPS));
    float sqh  = fmaxf(sMh2r, 1e-30f) * frsq(fmaxf(sMh2r, 1e-30f));  // sqrt
    float mhn  = fmaxf(srt * sqh, MINN);
    float th   = ftanh(mhn * artp * frcp(xnp));
    float g    = th * frcp(mhn) * srt;
    float xyh  = g * sMhUhr;
    float y2h = ynh * ynh, x2h = th * th;
    float c1h = 1.f + 2.f * xyh + y2h, c2h = 1.f - x2h;
    float idnh = frcp(fmaxf(1.f + 2.f * xyh + x2h * y2h, MINN));
    float ah  = (c1h * g * mh + c2h * uh) * idnh;
    float ah2 = fmaxf(idnh * idnh * (c1h * c1h * x2h + 2.f * c1h * c2h * xyh + c2h * c2h * y2h), 0.f);
    float ahb = idnh * (c1h * g * sMhBhr + c2h * ubh);
    float hah = idnh * (c1h * g * sHMhr + c2h * sHUh);
    float c1hb = 1.f + 2.f * ahb + b2h, c2hb = 1.f - ah2;
    float idnhb = frcp(fmaxf(1.f + 2.f * ahb + ah2 * b2h, MINN));
    float ct  = (c1hb * ah + c2hb * bhv) * idnhb;
    float ct2 = fmaxf(idnhb * idnhb * (c1hb * c1hb * ah2 + 2.f * c1hb * c2hb * ahb + c2hb * c2hb * b2h), 0.f);
    float hct = idnhb * (c1hb * hah + c2hb * sHBh);

    // ---- delta = mobius_add(-h, h_tilde) ----
    float c1d = 1.f - 2.f * hct + ct2, c2d = 1.f - hn2;
    float idnd = frcp(fmaxf(1.f - 2.f * hct + hn2 * ct2, MINN));
    float dl = (c2d * ct - c1d * h) * idnd;
    float dn2 = fmaxf(idnd * idnd * (c1d * c1d * hn2 - 2.f * c1d * c2d * hct + c2d * c2d * ct2), 0.f);
    float wv = dl * zg;

    // ---- window C: 2 reductions, split 1/1 across halves ----
    {
      float vC = kh ? (h * wv) : (wv * wv);
      vC = redsum32(vC);
      if (l31 == 0) part[(13 + kh) * 4 + w] = vC;
    }
    __syncthreads();                      // (5) window C partials
    float wn2, hw;
    { float4 q;
      q = part4[13]; wn2 = q.x + q.y + q.z + q.w;
      q = part4[14]; hw  = q.x + q.y + q.z + q.w; }

    float rqd = frsq(fmaxf(dn2, 1e-30f));
    float dnv = fmaxf(dn2, 1e-30f) * rqd;
    float rqw = frsq(fmaxf(wn2, 1e-30f));
    float wnv = fmaxf(wn2, 1e-30f) * rqw;
    float tdd = ftanh(wnv * rqd * fatanh(fminf(dnv, ONE_EPS)));
    float szd = tdd * rqw;
    float zd = wv * szd;
    float hzd = hw * szd;
    float t2v = tdd * tdd;
    float c1f = 1.f + 2.f * hzd + t2v, c2f = 1.f - hn2;
    float idnf = frcp(fmaxf(1.f + 2.f * hzd + hn2 * t2v, MINN));
    float nh = (c1f * h + c2f * zd) * idnf;
    hn2 = fmaxf(idnf * idnf * (c1f * c1f * hn2 + 2.f * c1f * c2f * hzd + c2f * c2f * t2v), 0.f);
    h = nh;
    au += m1 * h; av += m2 * h;
    cuz = nuz; cur = nur; cuh = nuh;
    cyn = nyn; cub = nub; cm1 = nm1; cm2 = nm2;
  }
  if (l < 32) {
    uarr[b * 128 + o] = au;
    varr[b * 128 + o] = av;
  }
}

// ---------------- Kernel D: dist + mobius FF + hyperbolic MLR, 1 wave/b ----
__global__ __launch_bounds__(64) void k_final(
    const float* __restrict__ uarr, const float* __restrict__ varr,
    const float* __restrict__ wfu, const float* __restrict__ wfv,
    const float* __restrict__ bff, const float* __restrict__ bffd,
    const float* __restrict__ wfc, const float* __restrict__ pmlr,
    const float* __restrict__ amlr, const int* __restrict__ cids,
    const float* __restrict__ csemb, float* __restrict__ out) {
  int b = blockIdx.x;
  int l = threadIdx.x;
  __shared__ float us[128], vs[128], cbuf[64];
  float q0 = uarr[b * 128 + l], q1 = uarr[b * 128 + 64 + l];
  float r0 = varr[b * 128 + l], r1 = varr[b * 128 + 64 + l];
  us[l] = q0; us[l + 64] = q1; vs[l] = r0; vs[l + 64] = r1;
  __syncthreads();
  float u2 = redsum(q0 * q0 + q1 * q1);
  float v2 = redsum(r0 * r0 + r1 * r1);
  float uv = redsum(q0 * r0 + q1 * r1);
  float dsq;
  { float x2 = u2, y2 = v2, xy = -uv;
    float c1 = 1.f + 2.f * xy + y2, c2 = 1.f - x2;
    float idn = 1.f / fmaxf(1.f + 2.f * xy + x2 * y2, MINN);
    float d0 = (c1 * (-q0) + c2 * r0) * idn, d1 = (c1 * (-q1) + c2 * r1) * idn;
    float dn2 = redsum(d0 * d0 + d1 * d1);
    dsq = 2.f * atanhf(clampart(sqrtf(dn2))); }
  float mxu = 0.f, mxv = 0.f;
  #pragma unroll 4
  for (int jc = 0; jc < 128; jc += 4) {
    float4 uu = *reinterpret_cast<const float4*>(&us[jc]);
    float4 vv = *reinterpret_cast<const float4*>(&vs[jc]);
    float4 wu4 = *reinterpret_cast<const float4*>(wfu + (size_t)l * 128 + jc);
    float4 wv4 = *reinterpret_cast<const float4*>(wfv + (size_t)l * 128 + jc);
    mxu += DOT4(wu4, uu); mxv += DOT4(wv4, vv);
  }
  float xnu = fmaxf(sqrtf(u2), MINN);
  float xnv = fmaxf(sqrtf(v2), MINN);
  float mun = fmaxf(sqrtf(redsum(mxu * mxu)), MINN);
  float mvn = fmaxf(sqrtf(redsum(mxv * mxv)), MINN);
  float tu = tanhf(mun / xnu * atanhf(clampart(xnu)));
  float tv = tanhf(mvn / xnv * atanhf(clampart(xnv)));
  float fu = mxu * (tu / mun), fv = mxv * (tv / mvn);
  float o1;
  { float x2 = tu * tu, y2 = tv * tv, xy = redsum(fu * fv);
    float c1 = 1.f + 2.f * xy + y2, c2 = 1.f - x2;
    float idn = 1.f / fmaxf(1.f + 2.f * xy + x2 * y2, MINN);
    o1 = (c1 * fu + c2 * fv) * idn; }
  float bffl = bff[l];
  float bf2 = redsum(bffl * bffl);
  float o2;
  { float x2 = redsum(o1 * o1), y2 = bf2, xy = redsum(o1 * bffl);
    float c1 = 1.f + 2.f * xy + y2, c2 = 1.f - x2;
    float idn = 1.f / fmaxf(1.f + 2.f * xy + x2 * y2, MINN);
    o2 = (c1 * o1 + c2 * bffl) * idn; }
  float bdl = bffd[l];
  float bdn = fmaxf(sqrtf(redsum(bdl * bdl)), MINN);
  float tsm = tanhf(dsq * atanhf(clampart(bdn)));
  float sm = bdl * (tsm / bdn);
  float o3;
  { float x2 = redsum(o2 * o2), y2 = tsm * tsm, xy = redsum(o2 * sm);
    float c1 = 1.f + 2.f * xy + y2, c2 = 1.f - x2;
    float idn = 1.f / fmaxf(1.f + 2.f * xy + x2 * y2, MINN);
    o3 = (c1 * o2 + c2 * sm) * idn; }
  int cid = cids[b];
  float ce = csemb[(size_t)cid * 64 + l];
  cbuf[l] = ce;
  __syncthreads();
  float ce2 = redsum(ce * ce);
  float mxc = 0.f;
  #pragma unroll 4
  for (int jc = 0; jc < 64; jc += 4) {
    float4 cc = *reinterpret_cast<const float4*>(&cbuf[jc]);
    float4 wc4 = *reinterpret_cast<const float4*>(wfc + (size_t)l * 64 + jc);
    mxc += DOT4(wc4, cc);
  }
  float xnc = fmaxf(sqrtf(ce2), MINN);
  float mcn = fmaxf(sqrtf(redsum(mxc * mxc)), MINN);
  float tc = tanhf(mcn / xnc * atanhf(clampart(xnc)));
  float fc = mxc * (tc / mcn);
  float o4;
  { float x2 = redsum(o3 * o3), y2 = tc * tc, xy = redsum(o3 * fc);
    float c1 = 1.f + 2.f * xy + y2, c2 = 1.f - x2;
    float idn = 1.f / fmaxf(1.f + 2.f * xy + x2 * y2, MINN);
    o4 = (c1 * o3 + c2 * fc) * idn; }
  float on = fmaxf(sqrtf(redsum(o4 * o4)), MINN);
  float lo = o4 * (atanhf(clampart(on)) / on);
  float un = fmaxf(sqrtf(redsum(lo * lo)), MINN);
  float eo = lo * (tanhf(un) / un);
  float eo2 = redsum(eo * eo);
  for (int c = 0; c < 4; ++c) {
    float pc = pmlr[c * 64 + l];
    float ac = amlr[c * 64 + l];
    float p2 = redsum(pc * pc);
    float pe = redsum(pc * eo);
    float x2 = p2, y2 = eo2, xy = -pe;
    float c1 = 1.f + 2.f * xy + y2, c2 = 1.f - x2;
    float idn = 1.f / fmaxf(1.f + 2.f * xy + x2 * y2, MINN);
    float mp = (c1 * (-pc) + c2 * eo) * idn;
    float mp2 = redsum(mp * mp);
    float lam = 2.f / (1.f - mp2);
    float na = sqrtf(redsum(ac * ac));
    float au = ac / fmaxf(na, 1e-12f);
    float pda = redsum(mp * au);
    if (l == 0) out[b * 4 + c] = 2.f * na * asinhf(pda * lam);
  }
}

extern "C" void kernel_launch(void* const* d_in, const int* in_sizes, int n_in,
                              void* d_out, int out_size, void* d_ws, size_t ws_size,
                              hipStream_t stream) {
  const float* seq   = (const float*)d_in[0];
  const float* mask1 = (const float*)d_in[1];
  const float* mask2 = (const float*)d_in[2];
  const int*   cids  = (const int*)d_in[3];
  const float* csemb = (const float*)d_in[4];
  const float* wz  = (const float*)d_in[5];
  const float* wr  = (const float*)d_in[6];
  const float* wh  = (const float*)d_in[7];
  const float* uz  = (const float*)d_in[8];
  const float* ur  = (const float*)d_in[9];
  const float* uh  = (const float*)d_in[10];
  const float* bz  = (const float*)d_in[11];
  const float* br  = (const float*)d_in[12];
  const float* bh  = (const float*)d_in[13];
  const float* wfu = (const float*)d_in[14];
  const float* wfv = (const float*)d_in[15];
  const float* bff = (const float*)d_in[16];
  const float* bffd= (const float*)d_in[17];
  const float* wfc = (const float*)d_in[18];
  const float* pmlr= (const float*)d_in[19];
  const float* amlr= (const float*)d_in[20];
  float* ws = (float*)d_ws;
  float* mx      = ws;                             // 32768*384
  float* yn      = mx + (size_t)32768 * 384;       // 32768*4
  float* ubp     = yn + (size_t)32768 * 4;         // 32768*4
  float* bhi_f   = ubp + (size_t)32768 * 4;        // 147456 f32
  float* blo_f   = bhi_f + 147456;                 // 147456 f32
  float* uarr    = blo_f + 147456;                 // 256*128
  float* varr    = uarr + 256 * 128;               // 256*128
  uint4* Bh = (uint4*)bhi_f;
  uint4* Bl = (uint4*)blo_f;

  k_convB<<<dim3(144), dim3(256), 0, stream>>>(uz, ur, uh, Bh, Bl);
  k_gemm_fused<<<dim3(256), dim3(256), 0, stream>>>(seq, Bh, Bl, bz, br, bh,
                                                    mx, yn, ubp);
  k_scan<<<dim3(256), dim3(256), 0, stream>>>(mx, yn, ubp, wz, wr, wh,
                                              bz, br, bh, mask1, mask2,
                                              uarr, varr);
  k_final<<<dim3(256), dim3(64), 0, stream>>>(uarr, varr, wfu, wfv, bff, bffd,
                                              wfc, pmlr, amlr, cids, csemb,
                                              (float*)d_out);
}